// Round 5
// baseline (1687.579 us; speedup 1.0000x reference)
//
#include <hip/hip_runtime.h>

typedef unsigned short u16;
typedef __bf16 bf16x8 __attribute__((ext_vector_type(8)));
typedef float f32x4 __attribute__((ext_vector_type(4)));

typedef __attribute__((address_space(3))) u16 lds_u16_t;
typedef __attribute__((address_space(1))) const u16 glb_u16_t;

__device__ __forceinline__ u16 f2bf(float f) {
    union { float f; unsigned u; } v; v.f = f;
    unsigned r = v.u + 0x7FFFu + ((v.u >> 16) & 1u);   // RNE
    return (u16)(r >> 16);
}
__device__ __forceinline__ float bf2f(u16 h) {
    union { unsigned u; float f; } v; v.u = ((unsigned)h) << 16; return v.f;
}

// ---------------- f32 -> bf16 cast (n % 4 == 0) ----------------
__global__ void cast_f32_bf16(const float* __restrict__ src, u16* __restrict__ dst, long n4) {
    long i = (long)blockIdx.x * blockDim.x + threadIdx.x;
    long stride = (long)gridDim.x * blockDim.x;
    for (; i < n4; i += stride) {
        float4 f = reinterpret_cast<const float4*>(src)[i];
        ushort4 o;
        o.x = f2bf(f.x); o.y = f2bf(f.y); o.z = f2bf(f.z); o.w = f2bf(f.w);
        reinterpret_cast<ushort4*>(dst)[i] = o;
    }
}

// ---------------- token + positional embedding (wave-per-row, bf16 out) ----------------
__global__ __launch_bounds__(256) void embed_kernel(
    const int* __restrict__ labels, const float* __restrict__ tok_emb,
    const float* __restrict__ pos_emb, u16* __restrict__ xb)
{
    int wid = threadIdx.x >> 6, lane = threadIdx.x & 63;
    int r = blockIdx.x * 4 + wid;       // 0..8191 = b*512+t
    int b = r >> 9, t = r & 511;
    int tok = labels[b * 513 + t];      // labels[:, :-1]
    const float* te = tok_emb + (long)tok * 768;
    const float* pe = pos_emb + (long)t * 768;
    u16* xo = xb + (long)r * 768;
    int base = lane * 12;
#pragma unroll
    for (int c = 0; c < 3; c++) {
        float4 a = *reinterpret_cast<const float4*>(te + base + c * 4);
        float4 p = *reinterpret_cast<const float4*>(pe + base + c * 4);
        ushort4 o;
        o.x = f2bf(a.x + p.x); o.y = f2bf(a.y + p.y);
        o.z = f2bf(a.z + p.z); o.w = f2bf(a.w + p.w);
        *reinterpret_cast<ushort4*>(xo + base + c * 4) = o;
    }
}

// ================= 128x128 MFMA GEMM, 3-buffer depth-2 prefetch, counted vmcnt (T4) ============
// C = A[M,K] * W[N,K]^T + bias. 4 waves (2x2), each wave 64x64 = 4x4 16x16x32 frags.
// Tile t staged at iter t-2; vmcnt(8) at iter t waits only tile t (loads span ~2 iterations).
// Raw s_barrier (no implicit vmcnt drain). LDS 48 KB -> 3 blocks/CU. K % 32 == 0, K/32 >= 2.
template<int OB, int RELU>
__global__ __launch_bounds__(256) void gemm128(
    const u16* __restrict__ A, int lda,
    const u16* __restrict__ W, int ldw,
    const float* __restrict__ bias,
    void* __restrict__ C, int ldc,
    int M, int N, int K)
{
    __shared__ __align__(16) u16 As[3][128 * 32];
    __shared__ __align__(16) u16 Bs[3][128 * 32];

    // ---- bijective XCD swizzle (m204) ----
    int nwg = (int)(gridDim.x * gridDim.y);
    int orig = (int)(blockIdx.y * gridDim.x + blockIdx.x);
    int q = nwg >> 3, r = nwg & 7;
    int xcd = orig & 7, loc = orig >> 3;
    int wg = (xcd < r ? xcd * (q + 1) : r * (q + 1) + (xcd - r) * q) + loc;
    int bx = wg % (int)gridDim.x, by = wg / (int)gridDim.x;

    int m0 = by * 128, n0 = bx * 128;
    int tid = threadIdx.x, wid = tid >> 6, lane = tid & 63;
    int wr = (wid >> 1) * 64, wc = (wid & 1) * 64;
    int fr = lane & 15, fk = (lane >> 4) * 8;

    // staging geometry: 8 KB per matrix-tile = 512 x 16B; thread li stages chunks (li, li+256)
    int li0 = wid * 64 + lane;
    int li1 = li0 + 256;
    int r0 = li0 >> 2, c0 = (li0 & 3) * 8;
    int r1 = li1 >> 2, c1 = (li1 & 3) * 8;
    long aoff0 = (long)min(m0 + r0, M - 1) * lda + c0;
    long aoff1 = (long)min(m0 + r1, M - 1) * lda + c1;
    long woff0 = (long)min(n0 + r0, N - 1) * ldw + c0;
    long woff1 = (long)min(n0 + r1, N - 1) * ldw + c1;

    // rotating buffer pointers (explicit vars, no runtime-indexed arrays)
    char* sA0 = (char*)As[0] + wid * 1024;
    char* sA1 = (char*)As[1] + wid * 1024;
    char* sA2 = (char*)As[2] + wid * 1024;
    char* sB0 = (char*)Bs[0] + wid * 1024;
    char* sB1 = (char*)Bs[1] + wid * 1024;
    char* sB2 = (char*)Bs[2] + wid * 1024;
    const u16* cA0 = As[0]; const u16* cA1 = As[1]; const u16* cA2 = As[2];
    const u16* cB0 = Bs[0]; const u16* cB1 = Bs[1]; const u16* cB2 = Bs[2];

    f32x4 acc[4][4] = {};

    auto STAGE = [&](char* ab, char* bb, int kt) {
        int k0 = kt * 32;
        __builtin_amdgcn_global_load_lds((glb_u16_t*)(A + aoff0 + k0), (lds_u16_t*)ab, 16, 0, 0);
        __builtin_amdgcn_global_load_lds((glb_u16_t*)(A + aoff1 + k0), (lds_u16_t*)(ab + 4096), 16, 0, 0);
        __builtin_amdgcn_global_load_lds((glb_u16_t*)(W + woff0 + k0), (lds_u16_t*)bb, 16, 0, 0);
        __builtin_amdgcn_global_load_lds((glb_u16_t*)(W + woff1 + k0), (lds_u16_t*)(bb + 4096), 16, 0, 0);
    };
    auto COMPUTE = [&](const u16* as, const u16* bs) {
        bf16x8 af[4], bw[4];
#pragma unroll
        for (int m = 0; m < 4; m++)
            af[m] = *reinterpret_cast<const bf16x8*>(&as[(wr + m * 16 + fr) * 32 + fk]);
#pragma unroll
        for (int n = 0; n < 4; n++)
            bw[n] = *reinterpret_cast<const bf16x8*>(&bs[(wc + n * 16 + fr) * 32 + fk]);
#pragma unroll
        for (int m = 0; m < 4; m++)
#pragma unroll
            for (int n = 0; n < 4; n++)
                acc[m][n] = __builtin_amdgcn_mfma_f32_16x16x32_bf16(af[m], bw[n], acc[m][n], 0, 0, 0);
    };

    int nt = K >> 5;
    STAGE(sA0, sB0, 0);
    STAGE(sA1, sB1, 1);
    for (int t = 0; t < nt; ++t) {
        bool s2 = (t + 2 < nt);
        if (s2) STAGE(sA2, sB2, t + 2);
        // counted drain: wait only tile t's 4 loads (oldest); deeper loads stay in flight
        if (s2)               asm volatile("s_waitcnt vmcnt(8)" ::: "memory");
        else if (t + 1 < nt)  asm volatile("s_waitcnt vmcnt(4)" ::: "memory");
        else                  asm volatile("s_waitcnt vmcnt(0)" ::: "memory");
        __builtin_amdgcn_s_barrier();            // all waves' tile-t chunks visible
        __builtin_amdgcn_sched_barrier(0);       // rule #18: no ds_read hoist above the wait
        COMPUTE(cA0, cB0);
        __builtin_amdgcn_sched_barrier(0);       // keep reads/MFMAs before the WAR barrier
        __builtin_amdgcn_s_barrier();            // all reads of buf done -> re-stage is safe
        { char* tmp = sA0; sA0 = sA1; sA1 = sA2; sA2 = tmp; }
        { char* tmp = sB0; sB0 = sB1; sB1 = sB2; sB2 = tmp; }
        { const u16* tmp = cA0; cA0 = cA1; cA1 = cA2; cA2 = tmp; }
        { const u16* tmp = cB0; cB0 = cB1; cB1 = cB2; cB2 = tmp; }
    }

    // C/D layout: col = lane&15, row = (lane>>4)*4 + reg
    int crow = (lane >> 4) * 4;
#pragma unroll
    for (int m = 0; m < 4; m++) {
#pragma unroll
        for (int n = 0; n < 4; n++) {
            int col = n0 + wc + n * 16 + fr;
            if (col >= N) continue;
            float bv = bias ? bias[col] : 0.f;
            int rbase = m0 + wr + m * 16 + crow;
#pragma unroll
            for (int rr = 0; rr < 4; rr++) {
                int row = rbase + rr;
                if (row >= M) continue;
                float v = acc[m][n][rr] + bv;
                if (RELU) v = fmaxf(v, 0.f);
                long idx = (long)row * ldc + col;
                if (OB) ((u16*)C)[idx] = f2bf(v);
                else    ((float*)C)[idx] = v;
            }
        }
    }
}

// ---------------- bf16 MFMA GEMM 64x64 (batched, for attention): C = A * W^T + bias ----------------
template<int OB, int RELU>
__global__ __launch_bounds__(256) void gemm_bt(
    const u16* __restrict__ A, int lda, long sAb, long sAh,
    const u16* __restrict__ W, int ldw, long sWb, long sWh,
    const float* __restrict__ bias,
    void* __restrict__ C, int ldc, long sCb, long sCh,
    int M, int N, int K, int NH)
{
    __shared__ __align__(16) u16 As[64][40];   // +8 pad: breaks pow2 bank stride
    __shared__ __align__(16) u16 Bs[64][40];
    int z = blockIdx.z, zb = z / NH, zh = z % NH;
    const u16* Ap = A + (long)zb * sAb + (long)zh * sAh;
    const u16* Wp = W + (long)zb * sWb + (long)zh * sWh;
    long coff = (long)zb * sCb + (long)zh * sCh;
    int m0 = blockIdx.y * 64, n0 = blockIdx.x * 64;
    int tid = threadIdx.x;
    int lrow = tid >> 2;              // 0..63
    int lcb = (tid & 3) * 8;          // 0,8,16,24
    int wid = tid >> 6, lane = tid & 63;
    int wr = (wid >> 1) * 32, wc = (wid & 1) * 32;
    int fr = lane & 15, fk = (lane >> 4) * 8;

    f32x4 zero4 = {0.f, 0.f, 0.f, 0.f};
    f32x4 acc00 = zero4, acc01 = zero4, acc10 = zero4, acc11 = zero4;

    int aRow = m0 + lrow; bool aOK = aRow < M;
    int wRow = n0 + lrow; bool wOK = wRow < N;
    const u16* aP = Ap + (long)aRow * lda + lcb;
    const u16* wP = Wp + (long)wRow * ldw + lcb;
    uint4 zz = {0u, 0u, 0u, 0u};

    for (int k0 = 0; k0 < K; k0 += 32) {
        uint4 av = zz, wv = zz;
        if (aOK) av = *reinterpret_cast<const uint4*>(aP + k0);
        if (wOK) wv = *reinterpret_cast<const uint4*>(wP + k0);
        __syncthreads();
        *reinterpret_cast<uint4*>(&As[lrow][lcb]) = av;
        *reinterpret_cast<uint4*>(&Bs[lrow][lcb]) = wv;
        __syncthreads();
        bf16x8 a0 = *reinterpret_cast<const bf16x8*>(&As[wr + fr][fk]);
        bf16x8 a1 = *reinterpret_cast<const bf16x8*>(&As[wr + 16 + fr][fk]);
        bf16x8 b0 = *reinterpret_cast<const bf16x8*>(&Bs[wc + fr][fk]);
        bf16x8 b1 = *reinterpret_cast<const bf16x8*>(&Bs[wc + 16 + fr][fk]);
        acc00 = __builtin_amdgcn_mfma_f32_16x16x32_bf16(a0, b0, acc00, 0, 0, 0);
        acc01 = __builtin_amdgcn_mfma_f32_16x16x32_bf16(a0, b1, acc01, 0, 0, 0);
        acc10 = __builtin_amdgcn_mfma_f32_16x16x32_bf16(a1, b0, acc10, 0, 0, 0);
        acc11 = __builtin_amdgcn_mfma_f32_16x16x32_bf16(a1, b1, acc11, 0, 0, 0);
    }

    int crow = (lane >> 4) * 4;
    f32x4 accs[2][2] = {{acc00, acc01}, {acc10, acc11}};
#pragma unroll
    for (int fm = 0; fm < 2; fm++) {
#pragma unroll
        for (int fn = 0; fn < 2; fn++) {
            int col = n0 + wc + fn * 16 + fr;
            if (col >= N) continue;
            float bv = bias ? bias[col] : 0.f;
#pragma unroll
            for (int rr = 0; rr < 4; rr++) {
                int row = m0 + wr + fm * 16 + crow + rr;
                if (row >= M) continue;
                float v = accs[fm][fn][rr] + bv;
                if (RELU) v = fmaxf(v, 0.f);
                long idx = coff + (long)row * ldc + col;
                if (OB) ((u16*)C)[idx] = f2bf(v);
                else    ((float*)C)[idx] = v;
            }
        }
    }
}

// ---------------- V transpose with zero-pad: VT[z][d][k] = V[k][d], k>=rowsIn -> 0 ----------------
__global__ __launch_bounds__(256) void transpose_pad(
    const u16* __restrict__ V, long sVb, long sVh, int ldv, int NH,
    u16* __restrict__ VT, long sVT, int rowsIn, int Kp)
{
    __shared__ u16 tile[32][33];
    int z = blockIdx.z, zb = z / NH, zh = z % NH;
    const u16* Vp = V + (long)zb * sVb + (long)zh * sVh;
    int k0 = blockIdx.x * 32, d0 = blockIdx.y * 32;
#pragma unroll
    for (int i = 0; i < 4; i++) {
        int k = k0 + threadIdx.y + i * 8;
        int d = d0 + threadIdx.x;
        tile[threadIdx.y + i * 8][threadIdx.x] = (k < rowsIn) ? Vp[(long)k * ldv + d] : (u16)0;
    }
    __syncthreads();
    u16* Op = VT + (long)z * sVT;
#pragma unroll
    for (int i = 0; i < 4; i++) {
        int d = d0 + threadIdx.y + i * 8;
        int k = k0 + threadIdx.x;
        Op[(long)d * Kp + k] = tile[threadIdx.x][threadIdx.y + i * 8];
    }
}

// ---------------- row softmax (optionally causal), bf16 scores -> bf16 probs, zero-pad to ld_out ----------------
__global__ __launch_bounds__(256) void softmax_kernel(
    const u16* __restrict__ S, u16* __restrict__ P,
    int qrows, int cols_in, int ld_out, float scale, int causal)
{
    __shared__ float red[4];
    int r = blockIdx.x;
    int q = r % qrows;
    const u16* srow = S + (long)r * cols_in;
    u16* prow = P + (long)r * ld_out;
    int valid = causal ? (q + 1) : cols_in;
    int tid = threadIdx.x, lane = tid & 63, wid = tid >> 6;
    int c0 = tid, c1 = tid + 256;
    float v0 = -3e38f, v1 = -3e38f;
    if (c0 < valid) v0 = bf2f(srow[c0]) * scale;
    if (c1 < valid) v1 = bf2f(srow[c1]) * scale;
    float mx = fmaxf(v0, v1);
#pragma unroll
    for (int o = 32; o; o >>= 1) mx = fmaxf(mx, __shfl_down(mx, o, 64));
    if (lane == 0) red[wid] = mx;
    __syncthreads();
    mx = fmaxf(fmaxf(red[0], red[1]), fmaxf(red[2], red[3]));
    __syncthreads();
    float e0 = (c0 < valid) ? __expf(v0 - mx) : 0.f;
    float e1 = (c1 < valid) ? __expf(v1 - mx) : 0.f;
    float s = e0 + e1;
#pragma unroll
    for (int o = 32; o; o >>= 1) s += __shfl_down(s, o, 64);
    if (lane == 0) red[wid] = s;
    __syncthreads();
    s = red[0] + red[1] + red[2] + red[3];
    float inv = 1.f / s;
    if (c0 < ld_out) prow[c0] = f2bf(e0 * inv);
    if (c1 < ld_out) prow[c1] = f2bf(e1 * inv);
}

// ---------------- fused residual add + LayerNorm (bf16 in/out, wave-per-row) ----------------
__global__ __launch_bounds__(256) void ln_kernel(
    const u16* __restrict__ xin, const u16* __restrict__ subb,
    const float* __restrict__ g, const float* __restrict__ bta,
    u16* __restrict__ xout)
{
    int wid = threadIdx.x >> 6, lane = threadIdx.x & 63;
    long r = (long)blockIdx.x * 4 + wid;
    const u16* a = xin + r * 768;
    const u16* s = subb + r * 768;
    int base = lane * 12;
    float v[12];
    float sum = 0.f;
#pragma unroll
    for (int c = 0; c < 3; c++) {
        ushort4 av = *reinterpret_cast<const ushort4*>(a + base + c * 4);
        ushort4 sv = *reinterpret_cast<const ushort4*>(s + base + c * 4);
        v[c*4+0] = bf2f(av.x) + bf2f(sv.x);
        v[c*4+1] = bf2f(av.y) + bf2f(sv.y);
        v[c*4+2] = bf2f(av.z) + bf2f(sv.z);
        v[c*4+3] = bf2f(av.w) + bf2f(sv.w);
        sum += v[c*4+0] + v[c*4+1] + v[c*4+2] + v[c*4+3];
    }
#pragma unroll
    for (int o = 32; o; o >>= 1) sum += __shfl_xor(sum, o, 64);
    float mean = sum * (1.f / 768.f);
    float vs = 0.f;
#pragma unroll
    for (int j = 0; j < 12; j++) { float t = v[j] - mean; vs += t * t; }
#pragma unroll
    for (int o = 32; o; o >>= 1) vs += __shfl_xor(vs, o, 64);
    float rstd = rsqrtf(vs * (1.f / 768.f) + 1e-5f);
    u16* xo = xout + r * 768;
#pragma unroll
    for (int c = 0; c < 3; c++) {
        float4 gv = *reinterpret_cast<const float4*>(g + base + c * 4);
        float4 bv = *reinterpret_cast<const float4*>(bta + base + c * 4);
        ushort4 o;
        o.x = f2bf((v[c*4+0] - mean) * rstd * gv.x + bv.x);
        o.y = f2bf((v[c*4+1] - mean) * rstd * gv.y + bv.y);
        o.z = f2bf((v[c*4+2] - mean) * rstd * gv.z + bv.z);
        o.w = f2bf((v[c*4+3] - mean) * rstd * gv.w + bv.w);
        *reinterpret_cast<ushort4*>(xo + base + c * 4) = o;
    }
}

// ---------------- second output: labels[:, 1:] as FLOAT32 (d_out is float*) ----------------
__global__ void labels_out_kernel(const int* __restrict__ labels, float* __restrict__ out) {
    int i = blockIdx.x * 256 + threadIdx.x;
    if (i >= 8192) return;
    int b = i >> 9, t = i & 511;
    out[i] = (float)labels[b * 513 + t + 1];
}

// ---------------- host helpers ----------------
static void gemm_launch(hipStream_t st, bool outbf, bool relu,
    const u16* A, int lda, long sAb, long sAh,
    const u16* W, int ldw, long sWb, long sWh,
    const float* bias, void* C, int ldc, long sCb, long sCh,
    int M, int N, int K, int Z, int NH)
{
    dim3 g((N + 63) / 64, (M + 63) / 64, Z), b(256, 1, 1);
    if (outbf) {
        if (relu) gemm_bt<1,1><<<g,b,0,st>>>(A,lda,sAb,sAh,W,ldw,sWb,sWh,bias,C,ldc,sCb,sCh,M,N,K,NH);
        else      gemm_bt<1,0><<<g,b,0,st>>>(A,lda,sAb,sAh,W,ldw,sWb,sWh,bias,C,ldc,sCb,sCh,M,N,K,NH);
    } else {
        if (relu) gemm_bt<0,1><<<g,b,0,st>>>(A,lda,sAb,sAh,W,ldw,sWb,sWh,bias,C,ldc,sCb,sCh,M,N,K,NH);
        else      gemm_bt<0,0><<<g,b,0,st>>>(A,lda,sAb,sAh,W,ldw,sWb,sWh,bias,C,ldc,sCb,sCh,M,N,K,NH);
    }
}

static void gemm128_launch(hipStream_t st, bool outbf, bool relu,
    const u16* A, int lda, const u16* W, int ldw,
    const float* bias, void* C, int ldc, int M, int N, int K)
{
    dim3 g((N + 127) / 128, (M + 127) / 128, 1), b(256, 1, 1);
    if (outbf) {
        if (relu) gemm128<1,1><<<g,b,0,st>>>(A,lda,W,ldw,bias,C,ldc,M,N,K);
        else      gemm128<1,0><<<g,b,0,st>>>(A,lda,W,ldw,bias,C,ldc,M,N,K);
    } else {
        gemm128<0,0><<<g,b,0,st>>>(A,lda,W,ldw,bias,C,ldc,M,N,K);
    }
}

extern "C" void kernel_launch(void* const* d_in, const int* in_sizes, int n_in,
                              void* d_out, int out_size, void* d_ws, size_t ws_size,
                              hipStream_t stream)
{
    const int*   labels = (const int*)  d_in[0];
    const float* vision = (const float*)d_in[1];
    const float* vpw    = (const float*)d_in[2];
    const float* vpb    = (const float*)d_in[3];
    const float* temb   = (const float*)d_in[4];
    const float* pemb   = (const float*)d_in[5];
    const float* saw    = (const float*)d_in[6];
    const float* sab    = (const float*)d_in[7];
    const float* saow   = (const float*)d_in[8];
    const float* saob   = (const float*)d_in[9];
    const float* caw    = (const float*)d_in[10];
    const float* cab    = (const float*)d_in[11];
    const float* caow   = (const float*)d_in[12];
    const float* caob   = (const float*)d_in[13];
    const float* ln1g   = (const float*)d_in[14];
    const float* ln1b   = (const float*)d_in[15];
    const float* ln2g   = (const float*)d_in[16];
    const float* ln2b   = (const float*)d_in[17];
    const float* ln3g   = (const float*)d_in[18];
    const float* ln3b   = (const float*)d_in[19];
    const float* f1w    = (const float*)d_in[20];
    const float* f1b    = (const float*)d_in[21];
    const float* f2w    = (const float*)d_in[22];
    const float* f2b    = (const float*)d_in[23];
    const float* ow     = (const float*)d_in[24];
    const float* ob     = (const float*)d_in[25];
    (void)in_sizes; (void)n_in; (void)out_size;

    // ---- workspace layout ----
    char* p = (char*)d_ws;
    auto alloc = [&](long elems, int esz) -> char* {
        char* r = p; p += ((long)elems * esz + 255) & ~255L; return r;
    };
    u16* wb_vp  = (u16*)alloc(768L*768, 2);
    u16* wb_sa  = (u16*)alloc(3L*2304*768, 2);
    u16* wb_sao = (u16*)alloc(3L*768*768, 2);
    u16* wb_ca  = (u16*)alloc(3L*2304*768, 2);
    u16* wb_cao = (u16*)alloc(3L*768*768, 2);
    u16* wb_f1  = (u16*)alloc(3L*1024*768, 2);
    u16* wb_f2  = (u16*)alloc(3L*768*1024, 2);
    u16* wb_ow  = (u16*)alloc(10000L*768, 2);
    u16* vis_b  = (u16*)alloc(3152L*768, 2);
    u16* mem_b  = (u16*)alloc(3152L*768, 2);
    u16* xb     = (u16*)alloc(8192L*768, 2);
    u16* qkv    = (u16*)alloc(8192L*2304, 2);   // reused: {qkv} | {q_bf,kv_bf} | {h_bf}
    u16* q_bf   = qkv;
    u16* kv_bf  = qkv + 8192L*768;
    u16* h_bf   = qkv;
    u16* scb    = (u16*)alloc(64L*512*512, 2);  // bf16 scores
    u16* pr     = (u16*)alloc(64L*512*512, 2);
    u16* vt     = (u16*)alloc(64L*192*512, 2);
    u16* attn   = (u16*)alloc(8192L*768, 2);
    u16* subb   = (u16*)alloc(8192L*768, 2);
    if ((size_t)(p - (char*)d_ws) > ws_size) return;   // clean fail if ws too small

    auto cast = [&](const float* s, u16* d, long n) {
        long n4 = n >> 2;
        int blocks = (int)((n4 + 255) / 256); if (blocks > 4096) blocks = 4096;
        cast_f32_bf16<<<dim3(blocks), dim3(256), 0, stream>>>(s, d, n4);
    };
    cast(vpw,  wb_vp,  768L*768);
    cast(saw,  wb_sa,  3L*2304*768);
    cast(saow, wb_sao, 3L*768*768);
    cast(caw,  wb_ca,  3L*2304*768);
    cast(caow, wb_cao, 3L*768*768);
    cast(f1w,  wb_f1,  3L*1024*768);
    cast(f2w,  wb_f2,  3L*768*1024);
    cast(ow,   wb_ow,  10000L*768);
    cast(vision, vis_b, 3152L*768);

    embed_kernel<<<dim3(2048), dim3(256), 0, stream>>>(labels, temb, pemb, xb);

    // mem = vision @ vis_proj_w^T + b   (16*197=3152 rows)
    gemm128_launch(stream, true, false, vis_b, 768, wb_vp, 768, vpb, mem_b, 768, 3152, 768, 768);

    const float scale = 0.07216878364870323f;  // 1/sqrt(192)

    for (int l = 0; l < 3; l++) {
        // ======== self-attention ========
        const u16* Wsa = wb_sa + (long)l*2304*768;
        gemm128_launch(stream, true, false, xb, 768, Wsa, 768, sab + l*2304,
                       qkv, 2304, 8192, 2304, 768);
        transpose_pad<<<dim3(16,6,64), dim3(32,8), 0, stream>>>(
            qkv + 1536, 512L*2304, 192L, 2304, 4, vt, 192L*512, 512, 512);
        // scores = Q K^T  (bf16 out; batched over b,h: z = b*4+h)
        gemm_launch(stream, true, false, qkv, 2304, 512L*2304, 192, qkv + 768, 2304, 512L*2304, 192,
                    nullptr, scb, 512, 4L*512*512, 512L*512, 512, 512, 192, 64, 4);
        softmax_kernel<<<dim3(64*512), dim3(256), 0, stream>>>(scb, pr, 512, 512, 512, scale, 1);
        // O = P @ V  (W = V^T)
        gemm_launch(stream, true, false, pr, 512, 4L*512*512, 512L*512, vt, 512, 4L*192*512, 192L*512,
                    nullptr, attn, 768, 512L*768, 192, 512, 192, 512, 64, 4);
        gemm128_launch(stream, true, false, attn, 768, wb_sao + (long)l*768*768, 768,
                       saob + l*768, subb, 768, 8192, 768, 768);
        ln_kernel<<<dim3(2048), dim3(256), 0, stream>>>(xb, subb, ln1g + l*768, ln1b + l*768, xb);

        // ======== cross-attention ========
        const u16* Wca = wb_ca + (long)l*2304*768;
        gemm128_launch(stream, true, false, xb, 768, Wca, 768, cab + l*2304,
                       q_bf, 768, 8192, 768, 768);
        gemm128_launch(stream, true, false, mem_b, 768, Wca + 768L*768, 768, cab + l*2304 + 768,
                       kv_bf, 1536, 3152, 1536, 768);
        transpose_pad<<<dim3(7,6,64), dim3(32,8), 0, stream>>>(
            kv_bf + 768, 197L*1536, 192L, 1536, 4, vt, 192L*224, 197, 224);
        gemm_launch(stream, true, false, q_bf, 768, 512L*768, 192, kv_bf, 1536, 197L*1536, 192,
                    nullptr, scb, 197, 4L*512*197, 512L*197, 512, 197, 192, 64, 4);
        softmax_kernel<<<dim3(64*512), dim3(256), 0, stream>>>(scb, pr, 512, 197, 224, scale, 0);
        gemm_launch(stream, true, false, pr, 224, 4L*512*224, 512L*224, vt, 224, 4L*192*224, 192L*224,
                    nullptr, attn, 768, 512L*768, 192, 512, 192, 224, 64, 4);
        gemm128_launch(stream, true, false, attn, 768, wb_cao + (long)l*768*768, 768,
                       caob + l*768, subb, 768, 8192, 768, 768);
        ln_kernel<<<dim3(2048), dim3(256), 0, stream>>>(xb, subb, ln2g + l*768, ln2b + l*768, xb);

        // ======== feed-forward ========
        gemm128_launch(stream, true, true, xb, 768, wb_f1 + (long)l*1024*768, 768,
                       f1b + l*1024, h_bf, 1024, 8192, 1024, 768);
        gemm128_launch(stream, true, false, h_bf, 1024, wb_f2 + (long)l*768*1024, 1024,
                       f2b + l*768, subb, 768, 8192, 768, 1024);
        ln_kernel<<<dim3(2048), dim3(256), 0, stream>>>(xb, subb, ln3g + l*768, ln3b + l*768, xb);
    }

    // vocab head -> d_out (FLOAT32 logits — d_out is float*)
    gemm128_launch(stream, false, false, xb, 768, wb_ow, 768, ob,
                   (float*)d_out, 10000, 8192, 10000, 768);
    // second output: labels[:, 1:] as float32
    labels_out_kernel<<<dim3(32), dim3(256), 0, stream>>>(labels, (float*)d_out + 81920000L);
}

// Round 6
// 1473.528 us; speedup vs baseline: 1.1453x; 1.1453x over previous
//
#include <hip/hip_runtime.h>

typedef unsigned short u16;
typedef __bf16 bf16x8 __attribute__((ext_vector_type(8)));
typedef float f32x4 __attribute__((ext_vector_type(4)));

typedef __attribute__((address_space(3))) u16 lds_u16_t;
typedef __attribute__((address_space(1))) const u16 glb_u16_t;

__device__ __forceinline__ u16 f2bf(float f) {
    union { float f; unsigned u; } v; v.f = f;
    unsigned r = v.u + 0x7FFFu + ((v.u >> 16) & 1u);   // RNE
    return (u16)(r >> 16);
}
__device__ __forceinline__ float bf2f(u16 h) {
    union { unsigned u; float f; } v; v.u = ((unsigned)h) << 16; return v.f;
}

// ---------------- merged f32 -> bf16 cast: 9 segments in ONE launch ----------------
struct Cast9 { const float* s[9]; u16* d[9]; long n4[9]; };
__global__ __launch_bounds__(256) void cast9_kernel(Cast9 a) {
    int seg = blockIdx.z;
    const float* s = a.s[seg];
    u16* d = a.d[seg];
    long n4 = a.n4[seg];
    long i = (long)blockIdx.x * 256 + threadIdx.x;
    long stride = (long)gridDim.x * 256;
    for (; i < n4; i += stride) {
        float4 f = reinterpret_cast<const float4*>(s)[i];
        ushort4 o;
        o.x = f2bf(f.x); o.y = f2bf(f.y); o.z = f2bf(f.z); o.w = f2bf(f.w);
        reinterpret_cast<ushort4*>(d)[i] = o;
    }
}

// ---------------- token + positional embedding (wave-per-row) + labels[:,1:] out ----------------
__global__ __launch_bounds__(256) void embed_kernel(
    const int* __restrict__ labels, const float* __restrict__ tok_emb,
    const float* __restrict__ pos_emb, u16* __restrict__ xb, float* __restrict__ lab_out)
{
    int wid = threadIdx.x >> 6, lane = threadIdx.x & 63;
    int r = blockIdx.x * 4 + wid;       // 0..8191 = b*512+t
    int b = r >> 9, t = r & 511;
    int tok = labels[b * 513 + t];      // labels[:, :-1]
    if (lane == 0) lab_out[r] = (float)labels[b * 513 + t + 1];   // second output
    const float* te = tok_emb + (long)tok * 768;
    const float* pe = pos_emb + (long)t * 768;
    u16* xo = xb + (long)r * 768;
    int base = lane * 12;
#pragma unroll
    for (int c = 0; c < 3; c++) {
        float4 a = *reinterpret_cast<const float4*>(te + base + c * 4);
        float4 p = *reinterpret_cast<const float4*>(pe + base + c * 4);
        ushort4 o;
        o.x = f2bf(a.x + p.x); o.y = f2bf(a.y + p.y);
        o.z = f2bf(a.z + p.z); o.w = f2bf(a.w + p.w);
        *reinterpret_cast<ushort4*>(xo + base + c * 4) = o;
    }
}

// ================= BMx128 MFMA GEMM, 2-phase double-buffered (round-4 proven structure) =========
// C = A[M,K] * W[N,K]^T + bias.  BM=128: 4 waves 2x2, wave tile 64x64 (4x4 frags).
//                                BM=64 : 4 waves 1x4, wave tile 64x32 (4x2 frags) - for small-N fills.
// global_load_lds width=16, linear LDS [BM][32]/[128][32]; stage(t+1) before compute(t);
// one __syncthreads per K-step. XCD-bijective swizzle (m204) + 8-col supertiles for L2.
// MW = min waves/EU (launch_bounds). Row-clamped edges; K % 64 == 0.
template<int OB, int RELU, int BM, int MW>
__global__ __launch_bounds__(256, MW) void gemmT(
    const u16* __restrict__ A, int lda,
    const u16* __restrict__ W, int ldw,
    const float* __restrict__ bias,
    void* __restrict__ C, int ldc,
    int M, int N, int K)
{
    constexpr int MREP = 4;
    constexpr int NREP = (BM == 128) ? 4 : 2;
    __shared__ __align__(16) u16 As0[BM * 32];
    __shared__ __align__(16) u16 As1[BM * 32];
    __shared__ __align__(16) u16 Bs0[128 * 32];
    __shared__ __align__(16) u16 Bs1[128 * 32];

    // ---- bijective XCD swizzle (m204) ----
    int gx = (int)gridDim.x, gy = (int)gridDim.y;
    int nwg = gx * gy;
    int orig = (int)(blockIdx.y * gridDim.x + blockIdx.x);
    int q = nwg >> 3, r = nwg & 7;
    int xcd = orig & 7, loc = orig >> 3;
    int wg = (xcd < r ? xcd * (q + 1) : r * (q + 1) + (xcd - r) * q) + loc;
    // ---- 8-column supertiles within the XCD chunk (L2: 8 W-panels + streamed A) ----
    int full = 8 * gy;
    int nsc = (gx + 7) >> 3;
    int sc = wg / full; if (sc > nsc - 1) sc = nsc - 1;
    int rem = wg - sc * full;
    int wdt = gx - sc * 8; if (wdt > 8) wdt = 8;
    int by = rem / wdt, bx = sc * 8 + rem % wdt;

    int m0 = by * BM, n0 = bx * 128;
    int tid = threadIdx.x, wid = tid >> 6, lane = tid & 63;
    int wr = (BM == 128) ? (wid >> 1) * 64 : 0;
    int wc = (BM == 128) ? (wid & 1) * 64 : wid * 32;
    int fr = lane & 15, fk = (lane >> 4) * 8;

    // staging geometry: chunk = 16B; A has BM*4 chunks, W has 512 chunks; thread li0 (+li1)
    int li0 = wid * 64 + lane;
    int li1 = li0 + 256;
    int r0 = li0 >> 2, c0 = (li0 & 3) * 8;
    int r1 = li1 >> 2, c1 = (li1 & 3) * 8;
    long aoff0 = (long)min(m0 + r0, M - 1) * lda + c0;
    long aoff1 = (BM == 128) ? ((long)min(m0 + r1, M - 1) * lda + c1) : 0;
    long woff0 = (long)min(n0 + r0, N - 1) * ldw + c0;
    long woff1 = (long)min(n0 + r1, N - 1) * ldw + c1;
    char* a0base = (char*)As0 + wid * 1024;
    char* a1base = (char*)As1 + wid * 1024;
    char* b0base = (char*)Bs0 + wid * 1024;
    char* b1base = (char*)Bs1 + wid * 1024;

    f32x4 acc[MREP][NREP] = {};

    auto stage = [&](char* ab, char* bb, int kt) {
        int k0 = kt * 32;
        __builtin_amdgcn_global_load_lds((glb_u16_t*)(A + aoff0 + k0), (lds_u16_t*)ab, 16, 0, 0);
        if (BM == 128)
            __builtin_amdgcn_global_load_lds((glb_u16_t*)(A + aoff1 + k0), (lds_u16_t*)(ab + 4096), 16, 0, 0);
        __builtin_amdgcn_global_load_lds((glb_u16_t*)(W + woff0 + k0), (lds_u16_t*)bb, 16, 0, 0);
        __builtin_amdgcn_global_load_lds((glb_u16_t*)(W + woff1 + k0), (lds_u16_t*)(bb + 4096), 16, 0, 0);
    };
    auto compute = [&](const u16* as, const u16* bs) {
        bf16x8 af[MREP], bw[NREP];
#pragma unroll
        for (int m = 0; m < MREP; m++)
            af[m] = *reinterpret_cast<const bf16x8*>(&as[(wr + m * 16 + fr) * 32 + fk]);
#pragma unroll
        for (int n = 0; n < NREP; n++)
            bw[n] = *reinterpret_cast<const bf16x8*>(&bs[(wc + n * 16 + fr) * 32 + fk]);
#pragma unroll
        for (int m = 0; m < MREP; m++)
#pragma unroll
            for (int n = 0; n < NREP; n++)
                acc[m][n] = __builtin_amdgcn_mfma_f32_16x16x32_bf16(af[m], bw[n], acc[m][n], 0, 0, 0);
    };

    int nt = K >> 5;                       // even for K in {768, 1024}
    stage((char*)As0 + wid * 1024, (char*)Bs0 + wid * 1024, 0);
    __syncthreads();                       // buf0 ready
    for (int t = 0; t < nt; t += 2) {
        stage(a1base, b1base, t + 1);                          // prefetch into buf1
        compute(As0, Bs0);
        __syncthreads();                   // buf1 ready; buf0 reads retired
        if (t + 2 < nt) stage(a0base, b0base, t + 2);          // prefetch into buf0
        compute(As1, Bs1);
        __syncthreads();                   // buf0 ready; buf1 reads retired
    }

    // C/D layout: col = lane&15, row = (lane>>4)*4 + reg
    int crow = (lane >> 4) * 4;
#pragma unroll
    for (int m = 0; m < MREP; m++) {
#pragma unroll
        for (int n = 0; n < NREP; n++) {
            int col = n0 + wc + n * 16 + fr;
            if (col >= N) continue;
            float bv = bias ? bias[col] : 0.f;
            int rbase = m0 + wr + m * 16 + crow;
#pragma unroll
            for (int rr = 0; rr < 4; rr++) {
                int row = rbase + rr;
                if (row >= M) continue;
                float v = acc[m][n][rr] + bv;
                if (RELU) v = fmaxf(v, 0.f);
                long idx = (long)row * ldc + col;
                if (OB) ((u16*)C)[idx] = f2bf(v);
                else    ((float*)C)[idx] = v;
            }
        }
    }
}

// ---------------- bf16 MFMA GEMM 64x64 (batched, for attention): C = A * W^T + bias ----------------
template<int OB, int RELU>
__global__ __launch_bounds__(256) void gemm_bt(
    const u16* __restrict__ A, int lda, long sAb, long sAh,
    const u16* __restrict__ W, int ldw, long sWb, long sWh,
    const float* __restrict__ bias,
    void* __restrict__ C, int ldc, long sCb, long sCh,
    int M, int N, int K, int NH)
{
    __shared__ __align__(16) u16 As[64][40];   // +8 pad: breaks pow2 bank stride
    __shared__ __align__(16) u16 Bs[64][40];
    int z = blockIdx.z, zb = z / NH, zh = z % NH;
    const u16* Ap = A + (long)zb * sAb + (long)zh * sAh;
    const u16* Wp = W + (long)zb * sWb + (long)zh * sWh;
    long coff = (long)zb * sCb + (long)zh * sCh;
    int m0 = blockIdx.y * 64, n0 = blockIdx.x * 64;
    int tid = threadIdx.x;
    int lrow = tid >> 2;              // 0..63
    int lcb = (tid & 3) * 8;          // 0,8,16,24
    int wid = tid >> 6, lane = tid & 63;
    int wr = (wid >> 1) * 32, wc = (wid & 1) * 32;
    int fr = lane & 15, fk = (lane >> 4) * 8;

    f32x4 zero4 = {0.f, 0.f, 0.f, 0.f};
    f32x4 acc00 = zero4, acc01 = zero4, acc10 = zero4, acc11 = zero4;

    int aRow = m0 + lrow; bool aOK = aRow < M;
    int wRow = n0 + lrow; bool wOK = wRow < N;
    const u16* aP = Ap + (long)aRow * lda + lcb;
    const u16* wP = Wp + (long)wRow * ldw + lcb;
    uint4 zz = {0u, 0u, 0u, 0u};

    for (int k0 = 0; k0 < K; k0 += 32) {
        uint4 av = zz, wv = zz;
        if (aOK) av = *reinterpret_cast<const uint4*>(aP + k0);
        if (wOK) wv = *reinterpret_cast<const uint4*>(wP + k0);
        __syncthreads();
        *reinterpret_cast<uint4*>(&As[lrow][lcb]) = av;
        *reinterpret_cast<uint4*>(&Bs[lrow][lcb]) = wv;
        __syncthreads();
        bf16x8 a0 = *reinterpret_cast<const bf16x8*>(&As[wr + fr][fk]);
        bf16x8 a1 = *reinterpret_cast<const bf16x8*>(&As[wr + 16 + fr][fk]);
        bf16x8 b0 = *reinterpret_cast<const bf16x8*>(&Bs[wc + fr][fk]);
        bf16x8 b1 = *reinterpret_cast<const bf16x8*>(&Bs[wc + 16 + fr][fk]);
        acc00 = __builtin_amdgcn_mfma_f32_16x16x32_bf16(a0, b0, acc00, 0, 0, 0);
        acc01 = __builtin_amdgcn_mfma_f32_16x16x32_bf16(a0, b1, acc01, 0, 0, 0);
        acc10 = __builtin_amdgcn_mfma_f32_16x16x32_bf16(a1, b0, acc10, 0, 0, 0);
        acc11 = __builtin_amdgcn_mfma_f32_16x16x32_bf16(a1, b1, acc11, 0, 0, 0);
    }

    int crow = (lane >> 4) * 4;
    f32x4 accs[2][2] = {{acc00, acc01}, {acc10, acc11}};
#pragma unroll
    for (int fm = 0; fm < 2; fm++) {
#pragma unroll
        for (int fn = 0; fn < 2; fn++) {
            int col = n0 + wc + fn * 16 + fr;
            if (col >= N) continue;
            float bv = bias ? bias[col] : 0.f;
#pragma unroll
            for (int rr = 0; rr < 4; rr++) {
                int row = m0 + wr + fm * 16 + crow + rr;
                if (row >= M) continue;
                float v = accs[fm][fn][rr] + bv;
                if (RELU) v = fmaxf(v, 0.f);
                long idx = coff + (long)row * ldc + col;
                if (OB) ((u16*)C)[idx] = f2bf(v);
                else    ((float*)C)[idx] = v;
            }
        }
    }
}

// ---------------- V transpose with zero-pad: VT[z][d][k] = V[k][d], k>=rowsIn -> 0 ----------------
__global__ __launch_bounds__(256) void transpose_pad(
    const u16* __restrict__ V, long sVb, long sVh, int ldv, int NH,
    u16* __restrict__ VT, long sVT, int rowsIn, int Kp)
{
    __shared__ u16 tile[32][33];
    int z = blockIdx.z, zb = z / NH, zh = z % NH;
    const u16* Vp = V + (long)zb * sVb + (long)zh * sVh;
    int k0 = blockIdx.x * 32, d0 = blockIdx.y * 32;
#pragma unroll
    for (int i = 0; i < 4; i++) {
        int k = k0 + threadIdx.y + i * 8;
        int d = d0 + threadIdx.x;
        tile[threadIdx.y + i * 8][threadIdx.x] = (k < rowsIn) ? Vp[(long)k * ldv + d] : (u16)0;
    }
    __syncthreads();
    u16* Op = VT + (long)z * sVT;
#pragma unroll
    for (int i = 0; i < 4; i++) {
        int d = d0 + threadIdx.y + i * 8;
        int k = k0 + threadIdx.x;
        Op[(long)d * Kp + k] = tile[threadIdx.x][threadIdx.y + i * 8];
    }
}

// ---------------- row softmax (optionally causal), bf16 scores -> bf16 probs, zero-pad to ld_out ----------------
__global__ __launch_bounds__(256) void softmax_kernel(
    const u16* __restrict__ S, u16* __restrict__ P,
    int qrows, int cols_in, int ld_out, float scale, int causal)
{
    __shared__ float red[4];
    int r = blockIdx.x;
    int q = r % qrows;
    const u16* srow = S + (long)r * cols_in;
    u16* prow = P + (long)r * ld_out;
    int valid = causal ? (q + 1) : cols_in;
    int tid = threadIdx.x, lane = tid & 63, wid = tid >> 6;
    int c0 = tid, c1 = tid + 256;
    float v0 = -3e38f, v1 = -3e38f;
    if (c0 < valid) v0 = bf2f(srow[c0]) * scale;
    if (c1 < valid) v1 = bf2f(srow[c1]) * scale;
    float mx = fmaxf(v0, v1);
#pragma unroll
    for (int o = 32; o; o >>= 1) mx = fmaxf(mx, __shfl_down(mx, o, 64));
    if (lane == 0) red[wid] = mx;
    __syncthreads();
    mx = fmaxf(fmaxf(red[0], red[1]), fmaxf(red[2], red[3]));
    __syncthreads();
    float e0 = (c0 < valid) ? __expf(v0 - mx) : 0.f;
    float e1 = (c1 < valid) ? __expf(v1 - mx) : 0.f;
    float s = e0 + e1;
#pragma unroll
    for (int o = 32; o; o >>= 1) s += __shfl_down(s, o, 64);
    if (lane == 0) red[wid] = s;
    __syncthreads();
    s = red[0] + red[1] + red[2] + red[3];
    float inv = 1.f / s;
    if (c0 < ld_out) prow[c0] = f2bf(e0 * inv);
    if (c1 < ld_out) prow[c1] = f2bf(e1 * inv);
}

// ---------------- fused residual add + LayerNorm (bf16 in/out, wave-per-row) ----------------
__global__ __launch_bounds__(256) void ln_kernel(
    const u16* __restrict__ xin, const u16* __restrict__ subb,
    const float* __restrict__ g, const float* __restrict__ bta,
    u16* __restrict__ xout)
{
    int wid = threadIdx.x >> 6, lane = threadIdx.x & 63;
    long r = (long)blockIdx.x * 4 + wid;
    const u16* a = xin + r * 768;
    const u16* s = subb + r * 768;
    int base = lane * 12;
    float v[12];
    float sum = 0.f;
#pragma unroll
    for (int c = 0; c < 3; c++) {
        ushort4 av = *reinterpret_cast<const ushort4*>(a + base + c * 4);
        ushort4 sv = *reinterpret_cast<const ushort4*>(s + base + c * 4);
        v[c*4+0] = bf2f(av.x) + bf2f(sv.x);
        v[c*4+1] = bf2f(av.y) + bf2f(sv.y);
        v[c*4+2] = bf2f(av.z) + bf2f(sv.z);
        v[c*4+3] = bf2f(av.w) + bf2f(sv.w);
        sum += v[c*4+0] + v[c*4+1] + v[c*4+2] + v[c*4+3];
    }
#pragma unroll
    for (int o = 32; o; o >>= 1) sum += __shfl_xor(sum, o, 64);
    float mean = sum * (1.f / 768.f);
    float vs = 0.f;
#pragma unroll
    for (int j = 0; j < 12; j++) { float t = v[j] - mean; vs += t * t; }
#pragma unroll
    for (int o = 32; o; o >>= 1) vs += __shfl_xor(vs, o, 64);
    float rstd = rsqrtf(vs * (1.f / 768.f) + 1e-5f);
    u16* xo = xout + r * 768;
#pragma unroll
    for (int c = 0; c < 3; c++) {
        float4 gv = *reinterpret_cast<const float4*>(g + base + c * 4);
        float4 bv = *reinterpret_cast<const float4*>(bta + base + c * 4);
        ushort4 o;
        o.x = f2bf((v[c*4+0] - mean) * rstd * gv.x + bv.x);
        o.y = f2bf((v[c*4+1] - mean) * rstd * gv.y + bv.y);
        o.z = f2bf((v[c*4+2] - mean) * rstd * gv.z + bv.z);
        o.w = f2bf((v[c*4+3] - mean) * rstd * gv.w + bv.w);
        *reinterpret_cast<ushort4*>(xo + base + c * 4) = o;
    }
}

// ---------------- host helpers ----------------
static void gemm_launch(hipStream_t st, bool outbf, bool relu,
    const u16* A, int lda, long sAb, long sAh,
    const u16* W, int ldw, long sWb, long sWh,
    const float* bias, void* C, int ldc, long sCb, long sCh,
    int M, int N, int K, int Z, int NH)
{
    dim3 g((N + 63) / 64, (M + 63) / 64, Z), b(256, 1, 1);
    if (outbf) {
        if (relu) gemm_bt<1,1><<<g,b,0,st>>>(A,lda,sAb,sAh,W,ldw,sWb,sWh,bias,C,ldc,sCb,sCh,M,N,K,NH);
        else      gemm_bt<1,0><<<g,b,0,st>>>(A,lda,sAb,sAh,W,ldw,sWb,sWh,bias,C,ldc,sCb,sCh,M,N,K,NH);
    } else {
        if (relu) gemm_bt<0,1><<<g,b,0,st>>>(A,lda,sAb,sAh,W,ldw,sWb,sWh,bias,C,ldc,sCb,sCh,M,N,K,NH);
        else      gemm_bt<0,0><<<g,b,0,st>>>(A,lda,sAb,sAh,W,ldw,sWb,sWh,bias,C,ldc,sCb,sCh,M,N,K,NH);
    }
}

// BM=128, bf16 out
static void g128_bf(hipStream_t st, const u16* A, int lda, const u16* W, int ldw,
                    const float* bias, void* C, int ldc, int M, int N, int K) {
    dim3 g((N + 127) / 128, (M + 127) / 128, 1), b(256, 1, 1);
    gemmT<1,0,128,3><<<g,b,0,st>>>(A,lda,W,ldw,bias,C,ldc,M,N,K);
}
// BM=128, f32 out, MW=4 occupancy experiment (vocab head only)
static void g128_f32_mw4(hipStream_t st, const u16* A, int lda, const u16* W, int ldw,
                         const float* bias, void* C, int ldc, int M, int N, int K) {
    dim3 g((N + 127) / 128, (M + 127) / 128, 1), b(256, 1, 1);
    gemmT<0,0,128,4><<<g,b,0,st>>>(A,lda,W,ldw,bias,C,ldc,M,N,K);
}
// BM=64, bf16 out (small-N GEMMs: fills more CUs)
static void g64_bf(hipStream_t st, bool relu, const u16* A, int lda, const u16* W, int ldw,
                   const float* bias, void* C, int ldc, int M, int N, int K) {
    dim3 g((N + 127) / 128, (M + 63) / 64, 1), b(256, 1, 1);
    if (relu) gemmT<1,1,64,3><<<g,b,0,st>>>(A,lda,W,ldw,bias,C,ldc,M,N,K);
    else      gemmT<1,0,64,3><<<g,b,0,st>>>(A,lda,W,ldw,bias,C,ldc,M,N,K);
}

extern "C" void kernel_launch(void* const* d_in, const int* in_sizes, int n_in,
                              void* d_out, int out_size, void* d_ws, size_t ws_size,
                              hipStream_t stream)
{
    const int*   labels = (const int*)  d_in[0];
    const float* vision = (const float*)d_in[1];
    const float* vpw    = (const float*)d_in[2];
    const float* vpb    = (const float*)d_in[3];
    const float* temb   = (const float*)d_in[4];
    const float* pemb   = (const float*)d_in[5];
    const float* saw    = (const float*)d_in[6];
    const float* sab    = (const float*)d_in[7];
    const float* saow   = (const float*)d_in[8];
    const float* saob   = (const float*)d_in[9];
    const float* caw    = (const float*)d_in[10];
    const float* cab    = (const float*)d_in[11];
    const float* caow   = (const float*)d_in[12];
    const float* caob   = (const float*)d_in[13];
    const float* ln1g   = (const float*)d_in[14];
    const float* ln1b   = (const float*)d_in[15];
    const float* ln2g   = (const float*)d_in[16];
    const float* ln2b   = (const float*)d_in[17];
    const float* ln3g   = (const float*)d_in[18];
    const float* ln3b   = (const float*)d_in[19];
    const float* f1w    = (const float*)d_in[20];
    const float* f1b    = (const float*)d_in[21];
    const float* f2w    = (const float*)d_in[22];
    const float* f2b    = (const float*)d_in[23];
    const float* ow     = (const float*)d_in[24];
    const float* ob     = (const float*)d_in[25];
    (void)in_sizes; (void)n_in; (void)out_size;

    // ---- workspace layout ----
    char* p = (char*)d_ws;
    auto alloc = [&](long elems, int esz) -> char* {
        char* r = p; p += ((long)elems * esz + 255) & ~255L; return r;
    };
    u16* wb_vp  = (u16*)alloc(768L*768, 2);
    u16* wb_sa  = (u16*)alloc(3L*2304*768, 2);
    u16* wb_sao = (u16*)alloc(3L*768*768, 2);
    u16* wb_ca  = (u16*)alloc(3L*2304*768, 2);
    u16* wb_cao = (u16*)alloc(3L*768*768, 2);
    u16* wb_f1  = (u16*)alloc(3L*1024*768, 2);
    u16* wb_f2  = (u16*)alloc(3L*768*1024, 2);
    u16* wb_ow  = (u16*)alloc(10000L*768, 2);
    u16* vis_b  = (u16*)alloc(3152L*768, 2);
    u16* mem_b  = (u16*)alloc(3152L*768, 2);
    u16* xb     = (u16*)alloc(8192L*768, 2);
    u16* qkv    = (u16*)alloc(8192L*2304, 2);   // reused: {qkv} | {q_bf,kv_bf} | {h_bf}
    u16* q_bf   = qkv;
    u16* kv_bf  = qkv + 8192L*768;
    u16* h_bf   = qkv;
    u16* scb    = (u16*)alloc(64L*512*512, 2);  // bf16 scores
    u16* pr     = (u16*)alloc(64L*512*512, 2);
    u16* vt     = (u16*)alloc(64L*192*512, 2);
    u16* attn   = (u16*)alloc(8192L*768, 2);
    u16* subb   = (u16*)alloc(8192L*768, 2);
    if ((size_t)(p - (char*)d_ws) > ws_size) return;   // clean fail if ws too small

    // ---- all f32->bf16 casts in ONE launch ----
    Cast9 c9;
    c9.s[0] = vpw;    c9.d[0] = wb_vp;  c9.n4[0] = 768L*768/4;
    c9.s[1] = saw;    c9.d[1] = wb_sa;  c9.n4[1] = 3L*2304*768/4;
    c9.s[2] = saow;   c9.d[2] = wb_sao; c9.n4[2] = 3L*768*768/4;
    c9.s[3] = caw;    c9.d[3] = wb_ca;  c9.n4[3] = 3L*2304*768/4;
    c9.s[4] = caow;   c9.d[4] = wb_cao; c9.n4[4] = 3L*768*768/4;
    c9.s[5] = f1w;    c9.d[5] = wb_f1;  c9.n4[5] = 3L*1024*768/4;
    c9.s[6] = f2w;    c9.d[6] = wb_f2;  c9.n4[6] = 3L*768*1024/4;
    c9.s[7] = ow;     c9.d[7] = wb_ow;  c9.n4[7] = 10000L*768/4;
    c9.s[8] = vision; c9.d[8] = vis_b;  c9.n4[8] = 3152L*768/4;
    cast9_kernel<<<dim3(512, 1, 9), dim3(256), 0, stream>>>(c9);

    embed_kernel<<<dim3(2048), dim3(256), 0, stream>>>(labels, temb, pemb, xb,
                                                       (float*)d_out + 81920000L);

    // mem = vision @ vis_proj_w^T + b   (16*197=3152 rows)
    g64_bf(stream, false, vis_b, 768, wb_vp, 768, vpb, mem_b, 768, 3152, 768, 768);

    const float scale = 0.07216878364870323f;  // 1/sqrt(192)

    for (int l = 0; l < 3; l++) {
        // ======== self-attention ========
        const u16* Wsa = wb_sa + (long)l*2304*768;
        g128_bf(stream, xb, 768, Wsa, 768, sab + l*2304, qkv, 2304, 8192, 2304, 768);
        transpose_pad<<<dim3(16,6,64), dim3(32,8), 0, stream>>>(
            qkv + 1536, 512L*2304, 192L, 2304, 4, vt, 192L*512, 512, 512);
        // scores = Q K^T  (bf16 out; batched over b,h: z = b*4+h)
        gemm_launch(stream, true, false, qkv, 2304, 512L*2304, 192, qkv + 768, 2304, 512L*2304, 192,
                    nullptr, scb, 512, 4L*512*512, 512L*512, 512, 512, 192, 64, 4);
        softmax_kernel<<<dim3(64*512), dim3(256), 0, stream>>>(scb, pr, 512, 512, 512, scale, 1);
        // O = P @ V  (W = V^T)
        gemm_launch(stream, true, false, pr, 512, 4L*512*512, 512L*512, vt, 512, 4L*192*512, 192L*512,
                    nullptr, attn, 768, 512L*768, 192, 512, 192, 512, 64, 4);
        g64_bf(stream, false, attn, 768, wb_sao + (long)l*768*768, 768,
               saob + l*768, subb, 768, 8192, 768, 768);
        ln_kernel<<<dim3(2048), dim3(256), 0, stream>>>(xb, subb, ln1g + l*768, ln1b + l*768, xb);

        // ======== cross-attention ========
        const u16* Wca = wb_ca + (long)l*2304*768;
        g64_bf(stream, false, xb, 768, Wca, 768, cab + l*2304, q_bf, 768, 8192, 768, 768);
        g64_bf(stream, false, mem_b, 768, Wca + 768L*768, 768, cab + l*2304 + 768,
               kv_bf, 1536, 3152, 1536, 768);
        transpose_pad<<<dim3(7,6,64), dim3(32,8), 0, stream>>>(
            kv_bf + 768, 197L*1536, 192L, 1536, 4, vt, 192L*224, 197, 224);
        gemm_launch(stream, true, false, q_bf, 768, 512L*768, 192, kv_bf, 1536, 197L*1536, 192,
                    nullptr, scb, 197, 4L*512*197, 512L*197, 512, 197, 192, 64, 4);
        softmax_kernel<<<dim3(64*512), dim3(256), 0, stream>>>(scb, pr, 512, 197, 224, scale, 0);
        gemm_launch(stream, true, false, pr, 224, 4L*512*224, 512L*224, vt, 224, 4L*192*224, 192L*224,
                    nullptr, attn, 768, 512L*768, 192, 512, 192, 224, 64, 4);
        g64_bf(stream, false, attn, 768, wb_cao + (long)l*768*768, 768,
               caob + l*768, subb, 768, 8192, 768, 768);
        ln_kernel<<<dim3(2048), dim3(256), 0, stream>>>(xb, subb, ln2g + l*768, ln2b + l*768, xb);

        // ======== feed-forward ========
        g64_bf(stream, true, xb, 768, wb_f1 + (long)l*1024*768, 768,
               f1b + l*1024, h_bf, 1024, 8192, 1024, 768);
        g64_bf(stream, false, h_bf, 1024, wb_f2 + (long)l*768*1024, 1024,
               f2b + l*768, subb, 768, 8192, 768, 1024);
        ln_kernel<<<dim3(2048), dim3(256), 0, stream>>>(xb, subb, ln3g + l*768, ln3b + l*768, xb);
    }

    // vocab head -> d_out (FLOAT32 logits — d_out is float*); MW=4 occupancy experiment
    g128_f32_mw4(stream, xb, 768, wb_ow, 768, ob, (float*)d_out, 10000, 8192, 10000, 768);
}

// Round 7
// 1460.485 us; speedup vs baseline: 1.1555x; 1.0089x over previous
//
#include <hip/hip_runtime.h>

typedef unsigned short u16;
typedef __bf16 bf16x8 __attribute__((ext_vector_type(8)));
typedef float f32x4 __attribute__((ext_vector_type(4)));

typedef __attribute__((address_space(3))) u16 lds_u16_t;
typedef __attribute__((address_space(1))) const u16 glb_u16_t;

__device__ __forceinline__ u16 f2bf(float f) {
    union { float f; unsigned u; } v; v.f = f;
    unsigned r = v.u + 0x7FFFu + ((v.u >> 16) & 1u);   // RNE
    return (u16)(r >> 16);
}
__device__ __forceinline__ float bf2f(u16 h) {
    union { unsigned u; float f; } v; v.u = ((unsigned)h) << 16; return v.f;
}

// ---------------- merged f32 -> bf16 cast: 9 segments in ONE launch ----------------
struct Cast9 { const float* s[9]; u16* d[9]; long n4[9]; };
__global__ __launch_bounds__(256) void cast9_kernel(Cast9 a) {
    int seg = blockIdx.z;
    const float* s = a.s[seg];
    u16* d = a.d[seg];
    long n4 = a.n4[seg];
    long i = (long)blockIdx.x * 256 + threadIdx.x;
    long stride = (long)gridDim.x * 256;
    for (; i < n4; i += stride) {
        float4 f = reinterpret_cast<const float4*>(s)[i];
        ushort4 o;
        o.x = f2bf(f.x); o.y = f2bf(f.y); o.z = f2bf(f.z); o.w = f2bf(f.w);
        reinterpret_cast<ushort4*>(d)[i] = o;
    }
}

// ---------------- token + positional embedding (wave-per-row) + labels[:,1:] out ----------------
__global__ __launch_bounds__(256) void embed_kernel(
    const int* __restrict__ labels, const float* __restrict__ tok_emb,
    const float* __restrict__ pos_emb, u16* __restrict__ xb, float* __restrict__ lab_out)
{
    int wid = threadIdx.x >> 6, lane = threadIdx.x & 63;
    int r = blockIdx.x * 4 + wid;       // 0..8191 = b*512+t
    int b = r >> 9, t = r & 511;
    int tok = labels[b * 513 + t];      // labels[:, :-1]
    if (lane == 0) lab_out[r] = (float)labels[b * 513 + t + 1];   // second output
    const float* te = tok_emb + (long)tok * 768;
    const float* pe = pos_emb + (long)t * 768;
    u16* xo = xb + (long)r * 768;
    int base = lane * 12;
#pragma unroll
    for (int c = 0; c < 3; c++) {
        float4 a = *reinterpret_cast<const float4*>(te + base + c * 4);
        float4 p = *reinterpret_cast<const float4*>(pe + base + c * 4);
        ushort4 o;
        o.x = f2bf(a.x + p.x); o.y = f2bf(a.y + p.y);
        o.z = f2bf(a.z + p.z); o.w = f2bf(a.w + p.w);
        *reinterpret_cast<ushort4*>(xo + base + c * 4) = o;
    }
}

// ================= BMx128 MFMA GEMM, 2-phase double-buffered, BATCHED (z = zb*NH+zh) =========
// C = A[M,K] * W[N,K]^T + bias.  BM=128: 4 waves 2x2, wave 64x64 (4x4 frags).
//                                BM=64 : 4 waves 1x4, wave 64x32 (4x2 frags).
// global_load_lds width=16, linear LDS [BM][32]/[128][32]; stage(t+1) before compute(t);
// one __syncthreads per K-step. XCD-bijective swizzle (m204) + 8-col supertiles for L2.
// Row-clamped M/N edges; K % 64 == 0 (nt even).
template<int OB, int RELU, int BM, int MW>
__global__ __launch_bounds__(256, MW) void gemmT(
    const u16* __restrict__ A, int lda, long sAb, long sAh,
    const u16* __restrict__ W, int ldw, long sWb, long sWh,
    const float* __restrict__ bias,
    void* __restrict__ C, int ldc, long sCb, long sCh,
    int M, int N, int K, int NH)
{
    constexpr int MREP = 4;
    constexpr int NREP = (BM == 128) ? 4 : 2;
    __shared__ __align__(16) u16 As0[BM * 32];
    __shared__ __align__(16) u16 As1[BM * 32];
    __shared__ __align__(16) u16 Bs0[128 * 32];
    __shared__ __align__(16) u16 Bs1[128 * 32];

    int z = blockIdx.z, zb = z / NH, zh = z % NH;
    const u16* Ap = A + (long)zb * sAb + (long)zh * sAh;
    const u16* Wp = W + (long)zb * sWb + (long)zh * sWh;
    long coff = (long)zb * sCb + (long)zh * sCh;

    // ---- bijective XCD swizzle (m204) ----
    int gx = (int)gridDim.x, gy = (int)gridDim.y;
    int nwg = gx * gy;
    int orig = (int)(blockIdx.y * gridDim.x + blockIdx.x);
    int q = nwg >> 3, r = nwg & 7;
    int xcd = orig & 7, loc = orig >> 3;
    int wg = (xcd < r ? xcd * (q + 1) : r * (q + 1) + (xcd - r) * q) + loc;
    // ---- 8-column supertiles within the XCD chunk (L2: 8 W-panels + streamed A) ----
    int full = 8 * gy;
    int nsc = (gx + 7) >> 3;
    int sc = wg / full; if (sc > nsc - 1) sc = nsc - 1;
    int rem = wg - sc * full;
    int wdt = gx - sc * 8; if (wdt > 8) wdt = 8;
    int by = rem / wdt, bx = sc * 8 + rem % wdt;

    int m0 = by * BM, n0 = bx * 128;
    int tid = threadIdx.x, wid = tid >> 6, lane = tid & 63;
    int wr = (BM == 128) ? (wid >> 1) * 64 : 0;
    int wc = (BM == 128) ? (wid & 1) * 64 : wid * 32;
    int fr = lane & 15, fk = (lane >> 4) * 8;

    // staging geometry: chunk = 16B; thread li0 (+li1 for BM=128 A / always W)
    int li0 = wid * 64 + lane;
    int li1 = li0 + 256;
    int r0 = li0 >> 2, c0 = (li0 & 3) * 8;
    int r1 = li1 >> 2, c1 = (li1 & 3) * 8;
    long aoff0 = (long)min(m0 + r0, M - 1) * lda + c0;
    long aoff1 = (BM == 128) ? ((long)min(m0 + r1, M - 1) * lda + c1) : 0;
    long woff0 = (long)min(n0 + r0, N - 1) * ldw + c0;
    long woff1 = (long)min(n0 + r1, N - 1) * ldw + c1;
    char* a0base = (char*)As0 + wid * 1024;
    char* a1base = (char*)As1 + wid * 1024;
    char* b0base = (char*)Bs0 + wid * 1024;
    char* b1base = (char*)Bs1 + wid * 1024;

    f32x4 acc[MREP][NREP] = {};

    auto stage = [&](char* ab, char* bb, int kt) {
        int k0 = kt * 32;
        __builtin_amdgcn_global_load_lds((glb_u16_t*)(Ap + aoff0 + k0), (lds_u16_t*)ab, 16, 0, 0);
        if (BM == 128)
            __builtin_amdgcn_global_load_lds((glb_u16_t*)(Ap + aoff1 + k0), (lds_u16_t*)(ab + 4096), 16, 0, 0);
        __builtin_amdgcn_global_load_lds((glb_u16_t*)(Wp + woff0 + k0), (lds_u16_t*)bb, 16, 0, 0);
        __builtin_amdgcn_global_load_lds((glb_u16_t*)(Wp + woff1 + k0), (lds_u16_t*)(bb + 4096), 16, 0, 0);
    };
    auto compute = [&](const u16* as, const u16* bs) {
        bf16x8 af[MREP], bw[NREP];
#pragma unroll
        for (int m = 0; m < MREP; m++)
            af[m] = *reinterpret_cast<const bf16x8*>(&as[(wr + m * 16 + fr) * 32 + fk]);
#pragma unroll
        for (int n = 0; n < NREP; n++)
            bw[n] = *reinterpret_cast<const bf16x8*>(&bs[(wc + n * 16 + fr) * 32 + fk]);
#pragma unroll
        for (int m = 0; m < MREP; m++)
#pragma unroll
            for (int n = 0; n < NREP; n++)
                acc[m][n] = __builtin_amdgcn_mfma_f32_16x16x32_bf16(af[m], bw[n], acc[m][n], 0, 0, 0);
    };

    int nt = K >> 5;                       // even for all K used (192/256/512/768/1024)
    stage(a0base, b0base, 0);
    __syncthreads();                       // buf0 ready
    for (int t = 0; t < nt; t += 2) {
        stage(a1base, b1base, t + 1);                          // prefetch into buf1
        compute(As0, Bs0);
        __syncthreads();                   // buf1 ready; buf0 reads retired
        if (t + 2 < nt) stage(a0base, b0base, t + 2);          // prefetch into buf0
        compute(As1, Bs1);
        __syncthreads();                   // buf0 ready; buf1 reads retired
    }

    // C/D layout: col = lane&15, row = (lane>>4)*4 + reg
    int crow = (lane >> 4) * 4;
#pragma unroll
    for (int m = 0; m < MREP; m++) {
#pragma unroll
        for (int n = 0; n < NREP; n++) {
            int col = n0 + wc + n * 16 + fr;
            if (col >= N) continue;
            float bv = bias ? bias[col] : 0.f;
            int rbase = m0 + wr + m * 16 + crow;
#pragma unroll
            for (int rr = 0; rr < 4; rr++) {
                int row = rbase + rr;
                if (row >= M) continue;
                float v = acc[m][n][rr] + bv;
                if (RELU) v = fmaxf(v, 0.f);
                long idx = coff + (long)row * ldc + col;
                if (OB) ((u16*)C)[idx] = f2bf(v);
                else    ((float*)C)[idx] = v;
            }
        }
    }
}

// ---------------- V transpose with zero-pad: VT[z][d][k] = V[k][d], k>=rowsIn -> 0 ----------------
__global__ __launch_bounds__(256) void transpose_pad(
    const u16* __restrict__ V, long sVb, long sVh, int ldv, int NH,
    u16* __restrict__ VT, long sVT, int rowsIn, int Kp)
{
    __shared__ u16 tile[32][33];
    int z = blockIdx.z, zb = z / NH, zh = z % NH;
    const u16* Vp = V + (long)zb * sVb + (long)zh * sVh;
    int k0 = blockIdx.x * 32, d0 = blockIdx.y * 32;
#pragma unroll
    for (int i = 0; i < 4; i++) {
        int k = k0 + threadIdx.y + i * 8;
        int d = d0 + threadIdx.x;
        tile[threadIdx.y + i * 8][threadIdx.x] = (k < rowsIn) ? Vp[(long)k * ldv + d] : (u16)0;
    }
    __syncthreads();
    u16* Op = VT + (long)z * sVT;
#pragma unroll
    for (int i = 0; i < 4; i++) {
        int d = d0 + threadIdx.y + i * 8;
        int k = k0 + threadIdx.x;
        Op[(long)d * Kp + k] = tile[threadIdx.x][threadIdx.y + i * 8];
    }
}

// ---------------- row softmax (optionally causal), bf16 scores -> bf16 probs, zero-pad to ld_out ----------------
__global__ __launch_bounds__(256) void softmax_kernel(
    const u16* __restrict__ S, u16* __restrict__ P,
    int qrows, int cols_in, int ld_out, float scale, int causal)
{
    __shared__ float red[4];
    int r = blockIdx.x;
    int q = r % qrows;
    const u16* srow = S + (long)r * cols_in;
    u16* prow = P + (long)r * ld_out;
    int valid = causal ? (q + 1) : cols_in;
    int tid = threadIdx.x, lane = tid & 63, wid = tid >> 6;
    int c0 = tid, c1 = tid + 256;
    float v0 = -3e38f, v1 = -3e38f;
    if (c0 < valid) v0 = bf2f(srow[c0]) * scale;
    if (c1 < valid) v1 = bf2f(srow[c1]) * scale;
    float mx = fmaxf(v0, v1);
#pragma unroll
    for (int o = 32; o; o >>= 1) mx = fmaxf(mx, __shfl_down(mx, o, 64));
    if (lane == 0) red[wid] = mx;
    __syncthreads();
    mx = fmaxf(fmaxf(red[0], red[1]), fmaxf(red[2], red[3]));
    __syncthreads();
    float e0 = (c0 < valid) ? __expf(v0 - mx) : 0.f;
    float e1 = (c1 < valid) ? __expf(v1 - mx) : 0.f;
    float s = e0 + e1;
#pragma unroll
    for (int o = 32; o; o >>= 1) s += __shfl_down(s, o, 64);
    if (lane == 0) red[wid] = s;
    __syncthreads();
    s = red[0] + red[1] + red[2] + red[3];
    float inv = 1.f / s;
    if (c0 < ld_out) prow[c0] = f2bf(e0 * inv);
    if (c1 < ld_out) prow[c1] = f2bf(e1 * inv);
}

// ---------------- fused residual add + LayerNorm (bf16 in/out, wave-per-row) ----------------
__global__ __launch_bounds__(256) void ln_kernel(
    const u16* __restrict__ xin, const u16* __restrict__ subb,
    const float* __restrict__ g, const float* __restrict__ bta,
    u16* __restrict__ xout)
{
    int wid = threadIdx.x >> 6, lane = threadIdx.x & 63;
    long r = (long)blockIdx.x * 4 + wid;
    const u16* a = xin + r * 768;
    const u16* s = subb + r * 768;
    int base = lane * 12;
    float v[12];
    float sum = 0.f;
#pragma unroll
    for (int c = 0; c < 3; c++) {
        ushort4 av = *reinterpret_cast<const ushort4*>(a + base + c * 4);
        ushort4 sv = *reinterpret_cast<const ushort4*>(s + base + c * 4);
        v[c*4+0] = bf2f(av.x) + bf2f(sv.x);
        v[c*4+1] = bf2f(av.y) + bf2f(sv.y);
        v[c*4+2] = bf2f(av.z) + bf2f(sv.z);
        v[c*4+3] = bf2f(av.w) + bf2f(sv.w);
        sum += v[c*4+0] + v[c*4+1] + v[c*4+2] + v[c*4+3];
    }
#pragma unroll
    for (int o = 32; o; o >>= 1) sum += __shfl_xor(sum, o, 64);
    float mean = sum * (1.f / 768.f);
    float vs = 0.f;
#pragma unroll
    for (int j = 0; j < 12; j++) { float t = v[j] - mean; vs += t * t; }
#pragma unroll
    for (int o = 32; o; o >>= 1) vs += __shfl_xor(vs, o, 64);
    float rstd = rsqrtf(vs * (1.f / 768.f) + 1e-5f);
    u16* xo = xout + r * 768;
#pragma unroll
    for (int c = 0; c < 3; c++) {
        float4 gv = *reinterpret_cast<const float4*>(g + base + c * 4);
        float4 bv = *reinterpret_cast<const float4*>(bta + base + c * 4);
        ushort4 o;
        o.x = f2bf((v[c*4+0] - mean) * rstd * gv.x + bv.x);
        o.y = f2bf((v[c*4+1] - mean) * rstd * gv.y + bv.y);
        o.z = f2bf((v[c*4+2] - mean) * rstd * gv.z + bv.z);
        o.w = f2bf((v[c*4+3] - mean) * rstd * gv.w + bv.w);
        *reinterpret_cast<ushort4*>(xo + base + c * 4) = o;
    }
}

// ---------------- host helpers ----------------
// non-batched wrappers
static void g128_bf(hipStream_t st, const u16* A, int lda, const u16* W, int ldw,
                    const float* bias, void* C, int ldc, int M, int N, int K) {
    dim3 g((N + 127) / 128, (M + 127) / 128, 1), b(256, 1, 1);
    gemmT<1,0,128,4><<<g,b,0,st>>>(A,lda,0,0,W,ldw,0,0,bias,C,ldc,0,0,M,N,K,1);
}
static void g128_f32(hipStream_t st, const u16* A, int lda, const u16* W, int ldw,
                     const float* bias, void* C, int ldc, int M, int N, int K) {
    dim3 g((N + 127) / 128, (M + 127) / 128, 1), b(256, 1, 1);
    gemmT<0,0,128,4><<<g,b,0,st>>>(A,lda,0,0,W,ldw,0,0,bias,C,ldc,0,0,M,N,K,1);
}
static void g64_bf(hipStream_t st, bool relu, const u16* A, int lda, const u16* W, int ldw,
                   const float* bias, void* C, int ldc, int M, int N, int K) {
    dim3 g((N + 127) / 128, (M + 63) / 64, 1), b(256, 1, 1);
    if (relu) gemmT<1,1,64,4><<<g,b,0,st>>>(A,lda,0,0,W,ldw,0,0,bias,C,ldc,0,0,M,N,K,1);
    else      gemmT<1,0,64,4><<<g,b,0,st>>>(A,lda,0,0,W,ldw,0,0,bias,C,ldc,0,0,M,N,K,1);
}
// batched (attention): BM=128, bf16 out
static void gbat(hipStream_t st,
    const u16* A, int lda, long sAb, long sAh,
    const u16* W, int ldw, long sWb, long sWh,
    void* C, int ldc, long sCb, long sCh,
    int M, int N, int K, int Z, int NH) {
    dim3 g((N + 127) / 128, (M + 127) / 128, Z), b(256, 1, 1);
    gemmT<1,0,128,4><<<g,b,0,st>>>(A,lda,sAb,sAh,W,ldw,sWb,sWh,nullptr,C,ldc,sCb,sCh,M,N,K,NH);
}

extern "C" void kernel_launch(void* const* d_in, const int* in_sizes, int n_in,
                              void* d_out, int out_size, void* d_ws, size_t ws_size,
                              hipStream_t stream)
{
    const int*   labels = (const int*)  d_in[0];
    const float* vision = (const float*)d_in[1];
    const float* vpw    = (const float*)d_in[2];
    const float* vpb    = (const float*)d_in[3];
    const float* temb   = (const float*)d_in[4];
    const float* pemb   = (const float*)d_in[5];
    const float* saw    = (const float*)d_in[6];
    const float* sab    = (const float*)d_in[7];
    const float* saow   = (const float*)d_in[8];
    const float* saob   = (const float*)d_in[9];
    const float* caw    = (const float*)d_in[10];
    const float* cab    = (const float*)d_in[11];
    const float* caow   = (const float*)d_in[12];
    const float* caob   = (const float*)d_in[13];
    const float* ln1g   = (const float*)d_in[14];
    const float* ln1b   = (const float*)d_in[15];
    const float* ln2g   = (const float*)d_in[16];
    const float* ln2b   = (const float*)d_in[17];
    const float* ln3g   = (const float*)d_in[18];
    const float* ln3b   = (const float*)d_in[19];
    const float* f1w    = (const float*)d_in[20];
    const float* f1b    = (const float*)d_in[21];
    const float* f2w    = (const float*)d_in[22];
    const float* f2b    = (const float*)d_in[23];
    const float* ow     = (const float*)d_in[24];
    const float* ob     = (const float*)d_in[25];
    (void)in_sizes; (void)n_in; (void)out_size;

    // ---- workspace layout ----
    char* p = (char*)d_ws;
    auto alloc = [&](long elems, int esz) -> char* {
        char* r = p; p += ((long)elems * esz + 255) & ~255L; return r;
    };
    u16* wb_vp  = (u16*)alloc(768L*768, 2);
    u16* wb_sa  = (u16*)alloc(3L*2304*768, 2);
    u16* wb_sao = (u16*)alloc(3L*768*768, 2);
    u16* wb_ca  = (u16*)alloc(3L*2304*768, 2);
    u16* wb_cao = (u16*)alloc(3L*768*768, 2);
    u16* wb_f1  = (u16*)alloc(3L*1024*768, 2);
    u16* wb_f2  = (u16*)alloc(3L*768*1024, 2);
    u16* wb_ow  = (u16*)alloc(10000L*768, 2);
    u16* vis_b  = (u16*)alloc(3152L*768, 2);
    u16* mem_b  = (u16*)alloc(3152L*768, 2);
    u16* xb     = (u16*)alloc(8192L*768, 2);
    u16* qkv    = (u16*)alloc(8192L*2304, 2);   // reused: {qkv} | {q_bf,kv_bf} | {h_bf}
    u16* q_bf   = qkv;
    u16* kv_bf  = qkv + 8192L*768;
    u16* h_bf   = qkv;
    u16* scb    = (u16*)alloc(64L*512*512, 2);  // bf16 scores (SA 512 / CA 224 ld)
    u16* pr     = (u16*)alloc(64L*512*512, 2);  // probs (SA ld 512 / CA ld 256)
    u16* vt     = (u16*)alloc(64L*192*512, 2);  // V^T (SA Kp 512 / CA Kp 256)
    u16* attn   = (u16*)alloc(8192L*768, 2);
    u16* subb   = (u16*)alloc(8192L*768, 2);
    if ((size_t)(p - (char*)d_ws) > ws_size) return;   // clean fail if ws too small

    // ---- all f32->bf16 casts in ONE launch ----
    Cast9 c9;
    c9.s[0] = vpw;    c9.d[0] = wb_vp;  c9.n4[0] = 768L*768/4;
    c9.s[1] = saw;    c9.d[1] = wb_sa;  c9.n4[1] = 3L*2304*768/4;
    c9.s[2] = saow;   c9.d[2] = wb_sao; c9.n4[2] = 3L*768*768/4;
    c9.s[3] = caw;    c9.d[3] = wb_ca;  c9.n4[3] = 3L*2304*768/4;
    c9.s[4] = caow;   c9.d[4] = wb_cao; c9.n4[4] = 3L*768*768/4;
    c9.s[5] = f1w;    c9.d[5] = wb_f1;  c9.n4[5] = 3L*1024*768/4;
    c9.s[6] = f2w;    c9.d[6] = wb_f2;  c9.n4[6] = 3L*768*1024/4;
    c9.s[7] = ow;     c9.d[7] = wb_ow;  c9.n4[7] = 10000L*768/4;
    c9.s[8] = vision; c9.d[8] = vis_b;  c9.n4[8] = 3152L*768/4;
    cast9_kernel<<<dim3(512, 1, 9), dim3(256), 0, stream>>>(c9);

    embed_kernel<<<dim3(2048), dim3(256), 0, stream>>>(labels, temb, pemb, xb,
                                                       (float*)d_out + 81920000L);

    // mem = vision @ vis_proj_w^T + b   (16*197=3152 rows)
    g64_bf(stream, false, vis_b, 768, wb_vp, 768, vpb, mem_b, 768, 3152, 768, 768);

    const float scale = 0.07216878364870323f;  // 1/sqrt(192)

    for (int l = 0; l < 3; l++) {
        // ======== self-attention ========
        const u16* Wsa = wb_sa + (long)l*2304*768;
        g128_bf(stream, xb, 768, Wsa, 768, sab + l*2304, qkv, 2304, 8192, 2304, 768);
        transpose_pad<<<dim3(16,6,64), dim3(32,8), 0, stream>>>(
            qkv + 1536, 512L*2304, 192L, 2304, 4, vt, 192L*512, 512, 512);
        // scores = Q K^T (batched z = b*4+h)
        gbat(stream, qkv, 2304, 512L*2304, 192, qkv + 768, 2304, 512L*2304, 192,
             scb, 512, 4L*512*512, 512L*512, 512, 512, 192, 64, 4);
        softmax_kernel<<<dim3(64*512), dim3(256), 0, stream>>>(scb, pr, 512, 512, 512, scale, 1);
        // O = P @ V  (W = V^T, K=512)
        gbat(stream, pr, 512, 4L*512*512, 512L*512, vt, 512, 4L*192*512, 192L*512,
             attn, 768, 512L*768, 192, 512, 192, 512, 64, 4);
        g64_bf(stream, false, attn, 768, wb_sao + (long)l*768*768, 768,
               saob + l*768, subb, 768, 8192, 768, 768);
        ln_kernel<<<dim3(2048), dim3(256), 0, stream>>>(xb, subb, ln1g + l*768, ln1b + l*768, xb);

        // ======== cross-attention ========
        const u16* Wca = wb_ca + (long)l*2304*768;
        g64_bf(stream, false, xb, 768, Wca, 768, cab + l*2304, q_bf, 768, 8192, 768, 768);
        g64_bf(stream, false, mem_b, 768, Wca + 768L*768, 768, cab + l*2304 + 768,
               kv_bf, 1536, 3152, 1536, 768);
        transpose_pad<<<dim3(8,6,64), dim3(32,8), 0, stream>>>(
            kv_bf + 768, 197L*1536, 192L, 1536, 4, vt, 192L*256, 197, 256);
        // scores (N=197, ld 224)
        gbat(stream, q_bf, 768, 512L*768, 192, kv_bf, 1536, 197L*1536, 192,
             scb, 224, 4L*512*224, 512L*224, 512, 197, 192, 64, 4);
        softmax_kernel<<<dim3(64*512), dim3(256), 0, stream>>>(scb, pr, 512, 224, 256, scale, 0);
        // O = P @ V (K padded to 256 with zeros in pr/vt)
        gbat(stream, pr, 256, 4L*512*256, 512L*256, vt, 256, 4L*192*256, 192L*256,
             attn, 768, 512L*768, 192, 512, 192, 256, 64, 4);
        g64_bf(stream, false, attn, 768, wb_cao + (long)l*768*768, 768,
               caob + l*768, subb, 768, 8192, 768, 768);
        ln_kernel<<<dim3(2048), dim3(256), 0, stream>>>(xb, subb, ln2g + l*768, ln2b + l*768, xb);

        // ======== feed-forward ========
        g64_bf(stream, true, xb, 768, wb_f1 + (long)l*1024*768, 768,
               f1b + l*1024, h_bf, 1024, 8192, 1024, 768);
        g64_bf(stream, false, h_bf, 1024, wb_f2 + (long)l*768*1024, 1024,
               f2b + l*768, subb, 768, 8192, 768, 1024);
        ln_kernel<<<dim3(2048), dim3(256), 0, stream>>>(xb, subb, ln3g + l*768, ln3b + l*768, xb);
    }

    // vocab head -> d_out (FLOAT32 logits — d_out is float*)
    g128_f32(stream, xb, 768, wb_ow, 768, ob, (float*)d_out, 10000, 8192, 10000, 768);
}

// Round 8
// 1392.477 us; speedup vs baseline: 1.2119x; 1.0488x over previous
//
#include <hip/hip_runtime.h>
#include <hip/hip_fp8.h>

typedef unsigned short u16;
typedef __bf16 bf16x8 __attribute__((ext_vector_type(8)));
typedef float f32x4 __attribute__((ext_vector_type(4)));
typedef unsigned short u16x8 __attribute__((ext_vector_type(8)));
typedef unsigned short u16x4 __attribute__((ext_vector_type(4)));
typedef long i64;

typedef __attribute__((address_space(3))) u16 lds_u16_t;
typedef __attribute__((address_space(1))) const u16 glb_u16_t;
typedef __attribute__((address_space(3))) unsigned char lds_u8_t;
typedef __attribute__((address_space(1))) const unsigned char glb_u8_t;

__device__ __forceinline__ u16 f2bf(float f) {
    union { float f; unsigned u; } v; v.f = f;
    unsigned r = v.u + 0x7FFFu + ((v.u >> 16) & 1u);   // RNE
    return (u16)(r >> 16);
}
__device__ __forceinline__ float bf2f(u16 h) {
    union { unsigned u; float f; } v; v.u = ((unsigned)h) << 16; return v.f;
}
__device__ __forceinline__ unsigned char f2e4m3(float f) {
    __hip_fp8_e4m3 h(f);               // OCP e4m3fn, RNE+sat
    return (unsigned char)h.__x;
}

// ---------------- merged f32 -> bf16 cast: 8 segments in ONE launch ----------------
struct Cast8 { const float* s[8]; u16* d[8]; long n4[8]; };
__global__ __launch_bounds__(256) void cast8_kernel(Cast8 a) {
    int seg = blockIdx.z;
    const float* s = a.s[seg];
    u16* d = a.d[seg];
    long n4 = a.n4[seg];
    long i = (long)blockIdx.x * 256 + threadIdx.x;
    long stride = (long)gridDim.x * 256;
    for (; i < n4; i += stride) {
        float4 f = reinterpret_cast<const float4*>(s)[i];
        ushort4 o;
        o.x = f2bf(f.x); o.y = f2bf(f.y); o.z = f2bf(f.z); o.w = f2bf(f.w);
        reinterpret_cast<ushort4*>(d)[i] = o;
    }
}

// ---------------- f32 -> fp8 e4m3 with pre-scale (weights x256) ----------------
__global__ __launch_bounds__(256) void cast_f32_fp8(
    const float* __restrict__ src, unsigned char* __restrict__ dst, long n4, float mul)
{
    long i = (long)blockIdx.x * 256 + threadIdx.x;
    long stride = (long)gridDim.x * 256;
    for (; i < n4; i += stride) {
        float4 f = reinterpret_cast<const float4*>(src)[i];
        uchar4 o;
        o.x = f2e4m3(f.x * mul); o.y = f2e4m3(f.y * mul);
        o.z = f2e4m3(f.z * mul); o.w = f2e4m3(f.w * mul);
        reinterpret_cast<uchar4*>(dst)[i] = o;
    }
}

// ---------------- bf16 -> fp8 e4m3 (activations, no scale) ----------------
__global__ __launch_bounds__(256) void cast_bf16_fp8(
    const u16* __restrict__ src, unsigned char* __restrict__ dst, long n8)
{
    long i = (long)blockIdx.x * 256 + threadIdx.x;
    long stride = (long)gridDim.x * 256;
    for (; i < n8; i += stride) {
        u16x8 x = reinterpret_cast<const u16x8*>(src)[i];
        union { unsigned char b[8]; i64 v; } o;
#pragma unroll
        for (int j = 0; j < 8; j++) o.b[j] = f2e4m3(bf2f(x[j]));
        reinterpret_cast<i64*>(dst)[i] = o.v;
    }
}

// ---------------- token + positional embedding (wave-per-row) + labels[:,1:] out ----------------
__global__ __launch_bounds__(256) void embed_kernel(
    const int* __restrict__ labels, const float* __restrict__ tok_emb,
    const float* __restrict__ pos_emb, u16* __restrict__ xb, float* __restrict__ lab_out)
{
    int wid = threadIdx.x >> 6, lane = threadIdx.x & 63;
    int r = blockIdx.x * 4 + wid;       // 0..8191 = b*512+t
    int b = r >> 9, t = r & 511;
    int tok = labels[b * 513 + t];      // labels[:, :-1]
    if (lane == 0) lab_out[r] = (float)labels[b * 513 + t + 1];   // second output
    const float* te = tok_emb + (long)tok * 768;
    const float* pe = pos_emb + (long)t * 768;
    u16* xo = xb + (long)r * 768;
    int base = lane * 12;
#pragma unroll
    for (int c = 0; c < 3; c++) {
        float4 a = *reinterpret_cast<const float4*>(te + base + c * 4);
        float4 p = *reinterpret_cast<const float4*>(pe + base + c * 4);
        ushort4 o;
        o.x = f2bf(a.x + p.x); o.y = f2bf(a.y + p.y);
        o.z = f2bf(a.z + p.z); o.w = f2bf(a.w + p.w);
        *reinterpret_cast<ushort4*>(xo + base + c * 4) = o;
    }
}

// ================= BMx128 bf16 MFMA GEMM, 2-phase double-buffered, BATCHED =========
template<int OB, int RELU, int BM, int MW>
__global__ __launch_bounds__(256, MW) void gemmT(
    const u16* __restrict__ A, int lda, long sAb, long sAh,
    const u16* __restrict__ W, int ldw, long sWb, long sWh,
    const float* __restrict__ bias,
    void* __restrict__ C, int ldc, long sCb, long sCh,
    int M, int N, int K, int NH)
{
    constexpr int MREP = 4;
    constexpr int NREP = (BM == 128) ? 4 : 2;
    __shared__ __align__(16) u16 As0[BM * 32];
    __shared__ __align__(16) u16 As1[BM * 32];
    __shared__ __align__(16) u16 Bs0[128 * 32];
    __shared__ __align__(16) u16 Bs1[128 * 32];

    int z = blockIdx.z, zb = z / NH, zh = z % NH;
    const u16* Ap = A + (long)zb * sAb + (long)zh * sAh;
    const u16* Wp = W + (long)zb * sWb + (long)zh * sWh;
    long coff = (long)zb * sCb + (long)zh * sCh;

    // ---- bijective XCD swizzle (m204) + 8-col supertiles ----
    int gx = (int)gridDim.x, gy = (int)gridDim.y;
    int nwg = gx * gy;
    int orig = (int)(blockIdx.y * gridDim.x + blockIdx.x);
    int q = nwg >> 3, r = nwg & 7;
    int xcd = orig & 7, loc = orig >> 3;
    int wg = (xcd < r ? xcd * (q + 1) : r * (q + 1) + (xcd - r) * q) + loc;
    int full = 8 * gy;
    int nsc = (gx + 7) >> 3;
    int sc = wg / full; if (sc > nsc - 1) sc = nsc - 1;
    int rem = wg - sc * full;
    int wdt = gx - sc * 8; if (wdt > 8) wdt = 8;
    int by = rem / wdt, bx = sc * 8 + rem % wdt;

    int m0 = by * BM, n0 = bx * 128;
    int tid = threadIdx.x, wid = tid >> 6, lane = tid & 63;
    int wr = (BM == 128) ? (wid >> 1) * 64 : 0;
    int wc = (BM == 128) ? (wid & 1) * 64 : wid * 32;
    int fr = lane & 15, fk = (lane >> 4) * 8;

    int li0 = wid * 64 + lane;
    int li1 = li0 + 256;
    int r0 = li0 >> 2, c0 = (li0 & 3) * 8;
    int r1 = li1 >> 2, c1 = (li1 & 3) * 8;
    long aoff0 = (long)min(m0 + r0, M - 1) * lda + c0;
    long aoff1 = (BM == 128) ? ((long)min(m0 + r1, M - 1) * lda + c1) : 0;
    long woff0 = (long)min(n0 + r0, N - 1) * ldw + c0;
    long woff1 = (long)min(n0 + r1, N - 1) * ldw + c1;
    char* a0base = (char*)As0 + wid * 1024;
    char* a1base = (char*)As1 + wid * 1024;
    char* b0base = (char*)Bs0 + wid * 1024;
    char* b1base = (char*)Bs1 + wid * 1024;

    f32x4 acc[MREP][NREP] = {};

    auto stage = [&](char* ab, char* bb, int kt) {
        int k0 = kt * 32;
        __builtin_amdgcn_global_load_lds((glb_u16_t*)(Ap + aoff0 + k0), (lds_u16_t*)ab, 16, 0, 0);
        if (BM == 128)
            __builtin_amdgcn_global_load_lds((glb_u16_t*)(Ap + aoff1 + k0), (lds_u16_t*)(ab + 4096), 16, 0, 0);
        __builtin_amdgcn_global_load_lds((glb_u16_t*)(Wp + woff0 + k0), (lds_u16_t*)bb, 16, 0, 0);
        __builtin_amdgcn_global_load_lds((glb_u16_t*)(Wp + woff1 + k0), (lds_u16_t*)(bb + 4096), 16, 0, 0);
    };
    auto compute = [&](const u16* as, const u16* bs) {
        bf16x8 af[MREP], bw[NREP];
#pragma unroll
        for (int m = 0; m < MREP; m++)
            af[m] = *reinterpret_cast<const bf16x8*>(&as[(wr + m * 16 + fr) * 32 + fk]);
#pragma unroll
        for (int n = 0; n < NREP; n++)
            bw[n] = *reinterpret_cast<const bf16x8*>(&bs[(wc + n * 16 + fr) * 32 + fk]);
#pragma unroll
        for (int m = 0; m < MREP; m++)
#pragma unroll
            for (int n = 0; n < NREP; n++)
                acc[m][n] = __builtin_amdgcn_mfma_f32_16x16x32_bf16(af[m], bw[n], acc[m][n], 0, 0, 0);
    };

    int nt = K >> 5;
    stage(a0base, b0base, 0);
    __syncthreads();
    for (int t = 0; t < nt; t += 2) {
        stage(a1base, b1base, t + 1);
        compute(As0, Bs0);
        __syncthreads();
        if (t + 2 < nt) stage(a0base, b0base, t + 2);
        compute(As1, Bs1);
        __syncthreads();
    }

    int crow = (lane >> 4) * 4;
#pragma unroll
    for (int m = 0; m < MREP; m++) {
#pragma unroll
        for (int n = 0; n < NREP; n++) {
            int col = n0 + wc + n * 16 + fr;
            if (col >= N) continue;
            float bv = bias ? bias[col] : 0.f;
            int rbase = m0 + wr + m * 16 + crow;
#pragma unroll
            for (int rr = 0; rr < 4; rr++) {
                int row = rbase + rr;
                if (row >= M) continue;
                float v = acc[m][n][rr] + bv;
                if (RELU) v = fmaxf(v, 0.f);
                long idx = coff + (long)row * ldc + col;
                if (OB) ((u16*)C)[idx] = f2bf(v);
                else    ((float*)C)[idx] = v;
            }
        }
    }
}

// ================= 128x128 FP8 MFMA GEMM, BK=64, 2-phase (vocab head) =================
// C = A[M,K]*W[N,K]^T * outscale + bias, f32 out. 32 MFMA per K-step per wave (2x barrier amortization).
__global__ __launch_bounds__(256, 4) void gemm8(
    const unsigned char* __restrict__ A, int lda,
    const unsigned char* __restrict__ W, int ldw,
    const float* __restrict__ bias, float outscale,
    float* __restrict__ C, int ldc,
    int M, int N, int K)
{
    __shared__ __align__(16) unsigned char As0[128 * 64];
    __shared__ __align__(16) unsigned char As1[128 * 64];
    __shared__ __align__(16) unsigned char Bs0[128 * 64];
    __shared__ __align__(16) unsigned char Bs1[128 * 64];

    // ---- bijective XCD swizzle + 8-col supertiles ----
    int gx = (int)gridDim.x, gy = (int)gridDim.y;
    int nwg = gx * gy;
    int orig = (int)(blockIdx.y * gridDim.x + blockIdx.x);
    int q = nwg >> 3, r = nwg & 7;
    int xcd = orig & 7, loc = orig >> 3;
    int wg = (xcd < r ? xcd * (q + 1) : r * (q + 1) + (xcd - r) * q) + loc;
    int full = 8 * gy;
    int nsc = (gx + 7) >> 3;
    int sc = wg / full; if (sc > nsc - 1) sc = nsc - 1;
    int rem = wg - sc * full;
    int wdt = gx - sc * 8; if (wdt > 8) wdt = 8;
    int by = rem / wdt, bx = sc * 8 + rem % wdt;

    int m0 = by * 128, n0 = bx * 128;
    int tid = threadIdx.x, wid = tid >> 6, lane = tid & 63;
    int wr = (wid >> 1) * 64, wc = (wid & 1) * 64;
    int fr = lane & 15, g8 = (lane >> 4) * 8;

    // staging: tile 128x64 fp8 = 8 KB = 512 x 16B chunks; thread li stages (li, li+256)
    int li0 = wid * 64 + lane;
    int li1 = li0 + 256;
    int r0 = li0 >> 2, c0 = (li0 & 3) * 16;
    int r1 = li1 >> 2, c1 = (li1 & 3) * 16;
    long aoff0 = (long)min(m0 + r0, M - 1) * lda + c0;
    long aoff1 = (long)min(m0 + r1, M - 1) * lda + c1;
    long woff0 = (long)min(n0 + r0, N - 1) * ldw + c0;
    long woff1 = (long)min(n0 + r1, N - 1) * ldw + c1;
    char* a0base = (char*)As0 + wid * 1024;
    char* a1base = (char*)As1 + wid * 1024;
    char* b0base = (char*)Bs0 + wid * 1024;
    char* b1base = (char*)Bs1 + wid * 1024;

    f32x4 acc[4][4] = {};

    auto stage = [&](char* ab, char* bb, int kt) {
        int k0 = kt * 64;
        __builtin_amdgcn_global_load_lds((glb_u8_t*)(A + aoff0 + k0), (lds_u8_t*)ab, 16, 0, 0);
        __builtin_amdgcn_global_load_lds((glb_u8_t*)(A + aoff1 + k0), (lds_u8_t*)(ab + 4096), 16, 0, 0);
        __builtin_amdgcn_global_load_lds((glb_u8_t*)(W + woff0 + k0), (lds_u8_t*)bb, 16, 0, 0);
        __builtin_amdgcn_global_load_lds((glb_u8_t*)(W + woff1 + k0), (lds_u8_t*)(bb + 4096), 16, 0, 0);
    };
    auto compute = [&](const unsigned char* as, const unsigned char* bs) {
        // A frag (16x16x32 fp8): row = lane&15, k = (lane>>4)*8 + j; ks subtile at +32
        i64 af[4][2], bw[4][2];
#pragma unroll
        for (int m = 0; m < 4; m++) {
            int row = wr + m * 16 + fr;
            af[m][0] = *reinterpret_cast<const i64*>(as + row * 64 + g8);
            af[m][1] = *reinterpret_cast<const i64*>(as + row * 64 + g8 + 32);
        }
#pragma unroll
        for (int n = 0; n < 4; n++) {
            int row = wc + n * 16 + fr;
            bw[n][0] = *reinterpret_cast<const i64*>(bs + row * 64 + g8);
            bw[n][1] = *reinterpret_cast<const i64*>(bs + row * 64 + g8 + 32);
        }
#pragma unroll
        for (int ks = 0; ks < 2; ks++)
#pragma unroll
            for (int m = 0; m < 4; m++)
#pragma unroll
                for (int n = 0; n < 4; n++)
                    acc[m][n] = __builtin_amdgcn_mfma_f32_16x16x32_fp8_fp8(
                        af[m][ks], bw[n][ks], acc[m][n], 0, 0, 0);
    };

    int nt = K >> 6;                      // K=768 -> 12 (even)
    stage(a0base, b0base, 0);
    __syncthreads();
    for (int t = 0; t < nt; t += 2) {
        stage(a1base, b1base, t + 1);
        compute(As0, Bs0);
        __syncthreads();
        if (t + 2 < nt) stage(a0base, b0base, t + 2);
        compute(As1, Bs1);
        __syncthreads();
    }

    int crow = (lane >> 4) * 4;
#pragma unroll
    for (int m = 0; m < 4; m++) {
#pragma unroll
        for (int n = 0; n < 4; n++) {
            int col = n0 + wc + n * 16 + fr;
            if (col >= N) continue;
            float bv = bias ? bias[col] : 0.f;
            int rbase = m0 + wr + m * 16 + crow;
#pragma unroll
            for (int rr = 0; rr < 4; rr++) {
                int row = rbase + rr;
                if (row >= M) continue;
                C[(long)row * ldc + col] = acc[m][n][rr] * outscale + bv;
            }
        }
    }
}

// ---------------- V transpose with zero-pad: VT[z][d][k] = V[k][d], k>=rowsIn -> 0 ----------------
__global__ __launch_bounds__(256) void transpose_pad(
    const u16* __restrict__ V, long sVb, long sVh, int ldv, int NH,
    u16* __restrict__ VT, long sVT, int rowsIn, int Kp)
{
    __shared__ u16 tile[32][33];
    int z = blockIdx.z, zb = z / NH, zh = z % NH;
    const u16* Vp = V + (long)zb * sVb + (long)zh * sVh;
    int k0 = blockIdx.x * 32, d0 = blockIdx.y * 32;
#pragma unroll
    for (int i = 0; i < 4; i++) {
        int k = k0 + threadIdx.y + i * 8;
        int d = d0 + threadIdx.x;
        tile[threadIdx.y + i * 8][threadIdx.x] = (k < rowsIn) ? Vp[(long)k * ldv + d] : (u16)0;
    }
    __syncthreads();
    u16* Op = VT + (long)z * sVT;
#pragma unroll
    for (int i = 0; i < 4; i++) {
        int d = d0 + threadIdx.y + i * 8;
        int k = k0 + threadIdx.x;
        Op[(long)d * Kp + k] = tile[threadIdx.x][threadIdx.y + i * 8];
    }
}

// ---------------- wave-per-row softmax, vectorized (G13); explicit valid count ----------------
// CPL = cols per lane (8: 512 cols; 4: 256 cols). Rows r = z*512 + q. Zeros written to [valid, ld_out).
template<int CPL, int CAUSAL>
__global__ __launch_bounds__(256) void softmax2(
    const u16* __restrict__ S, u16* __restrict__ P,
    int ld_in, int valid_in, int ld_out, float scale)
{
    int wid = threadIdx.x >> 6, lane = threadIdx.x & 63;
    long r = (long)blockIdx.x * 4 + wid;
    int q = (int)(r & 511);
    int valid = CAUSAL ? (q + 1) : valid_in;
    const u16* srow = S + r * (long)ld_in;
    u16* prow = P + r * (long)ld_out;
    int base = lane * CPL;
    float v[CPL];
    if constexpr (CPL == 8) {
        u16x8 x = *reinterpret_cast<const u16x8*>(srow + base);
#pragma unroll
        for (int j = 0; j < 8; j++) v[j] = bf2f(x[j]);
    } else {
        u16x4 x = *reinterpret_cast<const u16x4*>(srow + base);
#pragma unroll
        for (int j = 0; j < 4; j++) v[j] = bf2f(x[j]);
    }
    float mx = -3e38f;
#pragma unroll
    for (int j = 0; j < CPL; j++) {
        v[j] *= scale;
        if (base + j < valid) mx = fmaxf(mx, v[j]);
    }
#pragma unroll
    for (int o = 32; o; o >>= 1) mx = fmaxf(mx, __shfl_xor(mx, o, 64));
    float e[CPL], s = 0.f;
#pragma unroll
    for (int j = 0; j < CPL; j++) {
        e[j] = (base + j < valid) ? __expf(v[j] - mx) : 0.f;
        s += e[j];
    }
#pragma unroll
    for (int o = 32; o; o >>= 1) s += __shfl_xor(s, o, 64);
    float inv = 1.f / s;
    if constexpr (CPL == 8) {
        u16x8 o8;
#pragma unroll
        for (int j = 0; j < 8; j++) o8[j] = f2bf(e[j] * inv);
        *reinterpret_cast<u16x8*>(prow + base) = o8;
    } else {
        u16x4 o4;
#pragma unroll
        for (int j = 0; j < 4; j++) o4[j] = f2bf(e[j] * inv);
        *reinterpret_cast<u16x4*>(prow + base) = o4;
    }
}

// ---------------- fused residual add + LayerNorm (bf16 in/out, wave-per-row) ----------------
__global__ __launch_bounds__(256) void ln_kernel(
    const u16* __restrict__ xin, const u16* __restrict__ subb,
    const float* __restrict__ g, const float* __restrict__ bta,
    u16* __restrict__ xout)
{
    int wid = threadIdx.x >> 6, lane = threadIdx.x & 63;
    long r = (long)blockIdx.x * 4 + wid;
    const u16* a = xin + r * 768;
    const u16* s = subb + r * 768;
    int base = lane * 12;
    float v[12];
    float sum = 0.f;
#pragma unroll
    for (int c = 0; c < 3; c++) {
        ushort4 av = *reinterpret_cast<const ushort4*>(a + base + c * 4);
        ushort4 sv = *reinterpret_cast<const ushort4*>(s + base + c * 4);
        v[c*4+0] = bf2f(av.x) + bf2f(sv.x);
        v[c*4+1] = bf2f(av.y) + bf2f(sv.y);
        v[c*4+2] = bf2f(av.z) + bf2f(sv.z);
        v[c*4+3] = bf2f(av.w) + bf2f(sv.w);
        sum += v[c*4+0] + v[c*4+1] + v[c*4+2] + v[c*4+3];
    }
#pragma unroll
    for (int o = 32; o; o >>= 1) sum += __shfl_xor(sum, o, 64);
    float mean = sum * (1.f / 768.f);
    float vs = 0.f;
#pragma unroll
    for (int j = 0; j < 12; j++) { float t = v[j] - mean; vs += t * t; }
#pragma unroll
    for (int o = 32; o; o >>= 1) vs += __shfl_xor(vs, o, 64);
    float rstd = rsqrtf(vs * (1.f / 768.f) + 1e-5f);
    u16* xo = xout + r * 768;
#pragma unroll
    for (int c = 0; c < 3; c++) {
        float4 gv = *reinterpret_cast<const float4*>(g + base + c * 4);
        float4 bv = *reinterpret_cast<const float4*>(bta + base + c * 4);
        ushort4 o;
        o.x = f2bf((v[c*4+0] - mean) * rstd * gv.x + bv.x);
        o.y = f2bf((v[c*4+1] - mean) * rstd * gv.y + bv.y);
        o.z = f2bf((v[c*4+2] - mean) * rstd * gv.z + bv.z);
        o.w = f2bf((v[c*4+3] - mean) * rstd * gv.w + bv.w);
        *reinterpret_cast<ushort4*>(xo + base + c * 4) = o;
    }
}

// ---------------- host helpers ----------------
static void g128_bf(hipStream_t st, const u16* A, int lda, const u16* W, int ldw,
                    const float* bias, void* C, int ldc, int M, int N, int K) {
    dim3 g((N + 127) / 128, (M + 127) / 128, 1), b(256, 1, 1);
    gemmT<1,0,128,4><<<g,b,0,st>>>(A,lda,0,0,W,ldw,0,0,bias,C,ldc,0,0,M,N,K,1);
}
static void g64_bf(hipStream_t st, bool relu, const u16* A, int lda, const u16* W, int ldw,
                   const float* bias, void* C, int ldc, int M, int N, int K) {
    dim3 g((N + 127) / 128, (M + 63) / 64, 1), b(256, 1, 1);
    if (relu) gemmT<1,1,64,4><<<g,b,0,st>>>(A,lda,0,0,W,ldw,0,0,bias,C,ldc,0,0,M,N,K,1);
    else      gemmT<1,0,64,4><<<g,b,0,st>>>(A,lda,0,0,W,ldw,0,0,bias,C,ldc,0,0,M,N,K,1);
}
static void gbat(hipStream_t st,
    const u16* A, int lda, long sAb, long sAh,
    const u16* W, int ldw, long sWb, long sWh,
    void* C, int ldc, long sCb, long sCh,
    int M, int N, int K, int Z, int NH) {
    dim3 g((N + 127) / 128, (M + 127) / 128, Z), b(256, 1, 1);
    gemmT<1,0,128,4><<<g,b,0,st>>>(A,lda,sAb,sAh,W,ldw,sWb,sWh,nullptr,C,ldc,sCb,sCh,M,N,K,NH);
}

extern "C" void kernel_launch(void* const* d_in, const int* in_sizes, int n_in,
                              void* d_out, int out_size, void* d_ws, size_t ws_size,
                              hipStream_t stream)
{
    const int*   labels = (const int*)  d_in[0];
    const float* vision = (const float*)d_in[1];
    const float* vpw    = (const float*)d_in[2];
    const float* vpb    = (const float*)d_in[3];
    const float* temb   = (const float*)d_in[4];
    const float* pemb   = (const float*)d_in[5];
    const float* saw    = (const float*)d_in[6];
    const float* sab    = (const float*)d_in[7];
    const float* saow   = (const float*)d_in[8];
    const float* saob   = (const float*)d_in[9];
    const float* caw    = (const float*)d_in[10];
    const float* cab    = (const float*)d_in[11];
    const float* caow   = (const float*)d_in[12];
    const float* caob   = (const float*)d_in[13];
    const float* ln1g   = (const float*)d_in[14];
    const float* ln1b   = (const float*)d_in[15];
    const float* ln2g   = (const float*)d_in[16];
    const float* ln2b   = (const float*)d_in[17];
    const float* ln3g   = (const float*)d_in[18];
    const float* ln3b   = (const float*)d_in[19];
    const float* f1w    = (const float*)d_in[20];
    const float* f1b    = (const float*)d_in[21];
    const float* f2w    = (const float*)d_in[22];
    const float* f2b    = (const float*)d_in[23];
    const float* ow     = (const float*)d_in[24];
    const float* ob     = (const float*)d_in[25];
    (void)in_sizes; (void)n_in; (void)out_size;

    // ---- workspace layout ----
    char* p = (char*)d_ws;
    auto alloc = [&](long elems, int esz) -> char* {
        char* r = p; p += ((long)elems * esz + 255) & ~255L; return r;
    };
    u16* wb_vp  = (u16*)alloc(768L*768, 2);
    u16* wb_sa  = (u16*)alloc(3L*2304*768, 2);
    u16* wb_sao = (u16*)alloc(3L*768*768, 2);
    u16* wb_ca  = (u16*)alloc(3L*2304*768, 2);
    u16* wb_cao = (u16*)alloc(3L*768*768, 2);
    u16* wb_f1  = (u16*)alloc(3L*1024*768, 2);
    u16* wb_f2  = (u16*)alloc(3L*768*1024, 2);
    unsigned char* w8_ow = (unsigned char*)alloc(10000L*768, 1);  // fp8 vocab weights (x256)
    unsigned char* xq    = (unsigned char*)alloc(8192L*768, 1);   // fp8 activations for vocab
    u16* vis_b  = (u16*)alloc(3152L*768, 2);
    u16* mem_b  = (u16*)alloc(3152L*768, 2);
    u16* xb     = (u16*)alloc(8192L*768, 2);
    u16* qkv    = (u16*)alloc(8192L*2304, 2);   // reused: {qkv} | {q_bf,kv_bf} | {h_bf}
    u16* q_bf   = qkv;
    u16* kv_bf  = qkv + 8192L*768;
    u16* h_bf   = qkv;
    u16* scb    = (u16*)alloc(64L*512*512, 2);  // bf16 scores (SA ld 512 / CA ld 224)
    u16* pr     = (u16*)alloc(64L*512*512, 2);  // probs (SA ld 512 / CA ld 256)
    u16* vt     = (u16*)alloc(64L*192*512, 2);  // V^T (SA Kp 512 / CA Kp 256)
    u16* attn   = (u16*)alloc(8192L*768, 2);
    u16* subb   = (u16*)alloc(8192L*768, 2);
    if ((size_t)(p - (char*)d_ws) > ws_size) return;

    // ---- weight casts ----
    Cast8 c8;
    c8.s[0] = vpw;    c8.d[0] = wb_vp;  c8.n4[0] = 768L*768/4;
    c8.s[1] = saw;    c8.d[1] = wb_sa;  c8.n4[1] = 3L*2304*768/4;
    c8.s[2] = saow;   c8.d[2] = wb_sao; c8.n4[2] = 3L*768*768/4;
    c8.s[3] = caw;    c8.d[3] = wb_ca;  c8.n4[3] = 3L*2304*768/4;
    c8.s[4] = caow;   c8.d[4] = wb_cao; c8.n4[4] = 3L*768*768/4;
    c8.s[5] = f1w;    c8.d[5] = wb_f1;  c8.n4[5] = 3L*1024*768/4;
    c8.s[6] = f2w;    c8.d[6] = wb_f2;  c8.n4[6] = 3L*768*1024/4;
    c8.s[7] = vision; c8.d[7] = vis_b;  c8.n4[7] = 3152L*768/4;
    cast8_kernel<<<dim3(512, 1, 8), dim3(256), 0, stream>>>(c8);
    cast_f32_fp8<<<dim3(2048), dim3(256), 0, stream>>>(ow, w8_ow, 10000L*768/4, 256.f);

    embed_kernel<<<dim3(2048), dim3(256), 0, stream>>>(labels, temb, pemb, xb,
                                                       (float*)d_out + 81920000L);

    // mem = vision @ vis_proj_w^T + b
    g64_bf(stream, false, vis_b, 768, wb_vp, 768, vpb, mem_b, 768, 3152, 768, 768);

    const float scale = 0.07216878364870323f;  // 1/sqrt(192)

    for (int l = 0; l < 3; l++) {
        // ======== self-attention ========
        const u16* Wsa = wb_sa + (long)l*2304*768;
        g128_bf(stream, xb, 768, Wsa, 768, sab + l*2304, qkv, 2304, 8192, 2304, 768);
        transpose_pad<<<dim3(16,6,64), dim3(32,8), 0, stream>>>(
            qkv + 1536, 512L*2304, 192L, 2304, 4, vt, 192L*512, 512, 512);
        gbat(stream, qkv, 2304, 512L*2304, 192, qkv + 768, 2304, 512L*2304, 192,
             scb, 512, 4L*512*512, 512L*512, 512, 512, 192, 64, 4);
        softmax2<8,1><<<dim3(8192), dim3(256), 0, stream>>>(scb, pr, 512, 512, 512, scale);
        gbat(stream, pr, 512, 4L*512*512, 512L*512, vt, 512, 4L*192*512, 192L*512,
             attn, 768, 512L*768, 192, 512, 192, 512, 64, 4);
        g64_bf(stream, false, attn, 768, wb_sao + (long)l*768*768, 768,
               saob + l*768, subb, 768, 8192, 768, 768);
        ln_kernel<<<dim3(2048), dim3(256), 0, stream>>>(xb, subb, ln1g + l*768, ln1b + l*768, xb);

        // ======== cross-attention ========
        const u16* Wca = wb_ca + (long)l*2304*768;
        g64_bf(stream, false, xb, 768, Wca, 768, cab + l*2304, q_bf, 768, 8192, 768, 768);
        g64_bf(stream, false, mem_b, 768, Wca + 768L*768, 768, cab + l*2304 + 768,
               kv_bf, 1536, 3152, 1536, 768);
        transpose_pad<<<dim3(8,6,64), dim3(32,8), 0, stream>>>(
            kv_bf + 768, 197L*1536, 192L, 1536, 4, vt, 192L*256, 197, 256);
        gbat(stream, q_bf, 768, 512L*768, 192, kv_bf, 1536, 197L*1536, 192,
             scb, 224, 4L*512*224, 512L*224, 512, 197, 192, 64, 4);
        softmax2<4,0><<<dim3(8192), dim3(256), 0, stream>>>(scb, pr, 224, 197, 256, scale);
        gbat(stream, pr, 256, 4L*512*256, 512L*256, vt, 256, 4L*192*256, 192L*256,
             attn, 768, 512L*768, 192, 512, 192, 256, 64, 4);
        g64_bf(stream, false, attn, 768, wb_cao + (long)l*768*768, 768,
               caob + l*768, subb, 768, 8192, 768, 768);
        ln_kernel<<<dim3(2048), dim3(256), 0, stream>>>(xb, subb, ln2g + l*768, ln2b + l*768, xb);

        // ======== feed-forward ========
        g64_bf(stream, true, xb, 768, wb_f1 + (long)l*1024*768, 768,
               f1b + l*1024, h_bf, 1024, 8192, 1024, 768);
        g64_bf(stream, false, h_bf, 1024, wb_f2 + (long)l*768*1024, 1024,
               f2b + l*768, subb, 768, 8192, 768, 1024);
        ln_kernel<<<dim3(2048), dim3(256), 0, stream>>>(xb, subb, ln3g + l*768, ln3b + l*768, xb);
    }

    // vocab head (fp8, BK=64) -> d_out f32 logits
    cast_bf16_fp8<<<dim3(3072), dim3(256), 0, stream>>>(xb, xq, 8192L*768/8);
    {
        dim3 g((10000 + 127) / 128, 8192 / 128, 1), b(256, 1, 1);
        gemm8<<<g, b, 0, stream>>>(xq, 768, w8_ow, 768, ob, 1.f/256.f,
                                   (float*)d_out, 10000, 8192, 10000, 768);
    }
}

// Round 9
// 1275.748 us; speedup vs baseline: 1.3228x; 1.0915x over previous
//
#include <hip/hip_runtime.h>
#include <hip/hip_fp8.h>

typedef unsigned short u16;
typedef __bf16 bf16x8 __attribute__((ext_vector_type(8)));
typedef float f32x4 __attribute__((ext_vector_type(4)));
typedef unsigned short u16x8 __attribute__((ext_vector_type(8)));
typedef unsigned short u16x4 __attribute__((ext_vector_type(4)));
typedef long i64;

typedef __attribute__((address_space(3))) u16 lds_u16_t;
typedef __attribute__((address_space(1))) const u16 glb_u16_t;
typedef __attribute__((address_space(3))) unsigned char lds_u8_t;
typedef __attribute__((address_space(1))) const unsigned char glb_u8_t;

__device__ __forceinline__ u16 f2bf(float f) {
    union { float f; unsigned u; } v; v.f = f;
    unsigned r = v.u + 0x7FFFu + ((v.u >> 16) & 1u);   // RNE
    return (u16)(r >> 16);
}
__device__ __forceinline__ float bf2f(u16 h) {
    union { unsigned u; float f; } v; v.u = ((unsigned)h) << 16; return v.f;
}
__device__ __forceinline__ unsigned char f2e4m3(float f) {
    __hip_fp8_e4m3 h(f);               // OCP e4m3fn, RNE+sat
    return (unsigned char)h.__x;
}

// ---------------- merged f32 -> bf16 cast: 5 segments ----------------
struct Cast5 { const float* s[5]; u16* d[5]; long n4[5]; };
__global__ __launch_bounds__(256) void cast5_kernel(Cast5 a) {
    int seg = blockIdx.z;
    const float* s = a.s[seg];
    u16* d = a.d[seg];
    long n4 = a.n4[seg];
    long i = (long)blockIdx.x * 256 + threadIdx.x;
    long stride = (long)gridDim.x * 256;
    for (; i < n4; i += stride) {
        float4 f = reinterpret_cast<const float4*>(s)[i];
        ushort4 o;
        o.x = f2bf(f.x); o.y = f2bf(f.y); o.z = f2bf(f.z); o.w = f2bf(f.w);
        reinterpret_cast<ushort4*>(d)[i] = o;
    }
}
// ---------------- merged f32 -> fp8 (x256) cast: 4 segments ----------------
struct CastQ { const float* s[4]; unsigned char* d[4]; long n4[4]; };
__global__ __launch_bounds__(256) void castq_kernel(CastQ a) {
    int seg = blockIdx.z;
    const float* s = a.s[seg];
    unsigned char* d = a.d[seg];
    long n4 = a.n4[seg];
    long i = (long)blockIdx.x * 256 + threadIdx.x;
    long stride = (long)gridDim.x * 256;
    for (; i < n4; i += stride) {
        float4 f = reinterpret_cast<const float4*>(s)[i];
        uchar4 o;
        o.x = f2e4m3(f.x * 256.f); o.y = f2e4m3(f.y * 256.f);
        o.z = f2e4m3(f.z * 256.f); o.w = f2e4m3(f.w * 256.f);
        reinterpret_cast<uchar4*>(d)[i] = o;
    }
}

// ---------------- token + positional embedding (wave-per-row), bf16 + fp8 out + labels ----------------
__global__ __launch_bounds__(256) void embed_kernel(
    const int* __restrict__ labels, const float* __restrict__ tok_emb,
    const float* __restrict__ pos_emb, u16* __restrict__ xb,
    unsigned char* __restrict__ xq, float* __restrict__ lab_out)
{
    int wid = threadIdx.x >> 6, lane = threadIdx.x & 63;
    int r = blockIdx.x * 4 + wid;       // 0..8191 = b*512+t
    int b = r >> 9, t = r & 511;
    int tok = labels[b * 513 + t];      // labels[:, :-1]
    if (lane == 0) lab_out[r] = (float)labels[b * 513 + t + 1];
    const float* te = tok_emb + (long)tok * 768;
    const float* pe = pos_emb + (long)t * 768;
    u16* xo = xb + (long)r * 768;
    unsigned char* qo = xq + (long)r * 768;
    int base = lane * 12;
#pragma unroll
    for (int c = 0; c < 3; c++) {
        float4 a = *reinterpret_cast<const float4*>(te + base + c * 4);
        float4 p = *reinterpret_cast<const float4*>(pe + base + c * 4);
        float v0 = a.x + p.x, v1 = a.y + p.y, v2 = a.z + p.z, v3 = a.w + p.w;
        ushort4 o; o.x = f2bf(v0); o.y = f2bf(v1); o.z = f2bf(v2); o.w = f2bf(v3);
        *reinterpret_cast<ushort4*>(xo + base + c * 4) = o;
        uchar4 q; q.x = f2e4m3(v0); q.y = f2e4m3(v1); q.z = f2e4m3(v2); q.w = f2e4m3(v3);
        *reinterpret_cast<uchar4*>(qo + base + c * 4) = q;
    }
}

// ================= BMx128 bf16 MFMA GEMM, 2-phase double-buffered, BATCHED =========
template<int OB, int RELU, int BM, int MW>
__global__ __launch_bounds__(256, MW) void gemmT(
    const u16* __restrict__ A, int lda, long sAb, long sAh,
    const u16* __restrict__ W, int ldw, long sWb, long sWh,
    const float* __restrict__ bias,
    void* __restrict__ C, int ldc, long sCb, long sCh,
    int M, int N, int K, int NH)
{
    constexpr int MREP = 4;
    constexpr int NREP = (BM == 128) ? 4 : 2;
    __shared__ __align__(16) u16 As0[BM * 32];
    __shared__ __align__(16) u16 As1[BM * 32];
    __shared__ __align__(16) u16 Bs0[128 * 32];
    __shared__ __align__(16) u16 Bs1[128 * 32];

    int z = blockIdx.z, zb = z / NH, zh = z % NH;
    const u16* Ap = A + (long)zb * sAb + (long)zh * sAh;
    const u16* Wp = W + (long)zb * sWb + (long)zh * sWh;
    long coff = (long)zb * sCb + (long)zh * sCh;

    int gx = (int)gridDim.x, gy = (int)gridDim.y;
    int nwg = gx * gy;
    int orig = (int)(blockIdx.y * gridDim.x + blockIdx.x);
    int q = nwg >> 3, r = nwg & 7;
    int xcd = orig & 7, loc = orig >> 3;
    int wg = (xcd < r ? xcd * (q + 1) : r * (q + 1) + (xcd - r) * q) + loc;
    int full = 8 * gy;
    int nsc = (gx + 7) >> 3;
    int sc = wg / full; if (sc > nsc - 1) sc = nsc - 1;
    int rem = wg - sc * full;
    int wdt = gx - sc * 8; if (wdt > 8) wdt = 8;
    int by = rem / wdt, bx = sc * 8 + rem % wdt;

    int m0 = by * BM, n0 = bx * 128;
    int tid = threadIdx.x, wid = tid >> 6, lane = tid & 63;
    int wr = (BM == 128) ? (wid >> 1) * 64 : 0;
    int wc = (BM == 128) ? (wid & 1) * 64 : wid * 32;
    int fr = lane & 15, fk = (lane >> 4) * 8;

    int li0 = wid * 64 + lane;
    int li1 = li0 + 256;
    int r0 = li0 >> 2, c0 = (li0 & 3) * 8;
    int r1 = li1 >> 2, c1 = (li1 & 3) * 8;
    long aoff0 = (long)min(m0 + r0, M - 1) * lda + c0;
    long aoff1 = (BM == 128) ? ((long)min(m0 + r1, M - 1) * lda + c1) : 0;
    long woff0 = (long)min(n0 + r0, N - 1) * ldw + c0;
    long woff1 = (long)min(n0 + r1, N - 1) * ldw + c1;
    char* a0base = (char*)As0 + wid * 1024;
    char* a1base = (char*)As1 + wid * 1024;
    char* b0base = (char*)Bs0 + wid * 1024;
    char* b1base = (char*)Bs1 + wid * 1024;

    f32x4 acc[MREP][NREP] = {};

    auto stage = [&](char* ab, char* bb, int kt) {
        int k0 = kt * 32;
        __builtin_amdgcn_global_load_lds((glb_u16_t*)(Ap + aoff0 + k0), (lds_u16_t*)ab, 16, 0, 0);
        if (BM == 128)
            __builtin_amdgcn_global_load_lds((glb_u16_t*)(Ap + aoff1 + k0), (lds_u16_t*)(ab + 4096), 16, 0, 0);
        __builtin_amdgcn_global_load_lds((glb_u16_t*)(Wp + woff0 + k0), (lds_u16_t*)bb, 16, 0, 0);
        __builtin_amdgcn_global_load_lds((glb_u16_t*)(Wp + woff1 + k0), (lds_u16_t*)(bb + 4096), 16, 0, 0);
    };
    auto compute = [&](const u16* as, const u16* bs) {
        bf16x8 af[MREP], bw[NREP];
#pragma unroll
        for (int m = 0; m < MREP; m++)
            af[m] = *reinterpret_cast<const bf16x8*>(&as[(wr + m * 16 + fr) * 32 + fk]);
#pragma unroll
        for (int n = 0; n < NREP; n++)
            bw[n] = *reinterpret_cast<const bf16x8*>(&bs[(wc + n * 16 + fr) * 32 + fk]);
#pragma unroll
        for (int m = 0; m < MREP; m++)
#pragma unroll
            for (int n = 0; n < NREP; n++)
                acc[m][n] = __builtin_amdgcn_mfma_f32_16x16x32_bf16(af[m], bw[n], acc[m][n], 0, 0, 0);
    };

    int nt = K >> 5;
    stage(a0base, b0base, 0);
    __syncthreads();
    for (int t = 0; t < nt; t += 2) {
        stage(a1base, b1base, t + 1);
        compute(As0, Bs0);
        __syncthreads();
        if (t + 2 < nt) stage(a0base, b0base, t + 2);
        compute(As1, Bs1);
        __syncthreads();
    }

    int crow = (lane >> 4) * 4;
#pragma unroll
    for (int m = 0; m < MREP; m++) {
#pragma unroll
        for (int n = 0; n < NREP; n++) {
            int col = n0 + wc + n * 16 + fr;
            if (col >= N) continue;
            float bv = bias ? bias[col] : 0.f;
            int rbase = m0 + wr + m * 16 + crow;
#pragma unroll
            for (int rr = 0; rr < 4; rr++) {
                int row = rbase + rr;
                if (row >= M) continue;
                float v = acc[m][n][rr] + bv;
                if (RELU) v = fmaxf(v, 0.f);
                long idx = coff + (long)row * ldc + col;
                if (OB) ((u16*)C)[idx] = f2bf(v);
                else    ((float*)C)[idx] = v;
            }
        }
    }
}

// ================= 128x128 FP8 MFMA GEMM, BK=64, 2-phase, SWIZZLED LDS =================
// LDS tile = two 4KB halves (k 0..31, 32..63); 32-B rows; 16-B chunk slot = chunk ^ ((row>>2)&1).
// Applied on BOTH the global source (stage) and the read -> 2-way residual conflicts (free, m136).
// OUT: 0=f32, 1=bf16, 2=fp8.  C = (A.W^T)*outscale + bias  [RELU].
template<int OUT, int RELU>
__global__ __launch_bounds__(256, 4) void gemm8(
    const unsigned char* __restrict__ A, int lda,
    const unsigned char* __restrict__ W, int ldw,
    const float* __restrict__ bias, float outscale,
    void* __restrict__ C, int ldc,
    int M, int N, int K)
{
    __shared__ __align__(16) unsigned char As0[128 * 64];
    __shared__ __align__(16) unsigned char As1[128 * 64];
    __shared__ __align__(16) unsigned char Bs0[128 * 64];
    __shared__ __align__(16) unsigned char Bs1[128 * 64];

    int gx = (int)gridDim.x, gy = (int)gridDim.y;
    int nwg = gx * gy;
    int orig = (int)(blockIdx.y * gridDim.x + blockIdx.x);
    int q = nwg >> 3, r = nwg & 7;
    int xcd = orig & 7, loc = orig >> 3;
    int wg = (xcd < r ? xcd * (q + 1) : r * (q + 1) + (xcd - r) * q) + loc;
    int full = 8 * gy;
    int nsc = (gx + 7) >> 3;
    int sc = wg / full; if (sc > nsc - 1) sc = nsc - 1;
    int rem = wg - sc * full;
    int wdt = gx - sc * 8; if (wdt > 8) wdt = 8;
    int by = rem / wdt, bx = sc * 8 + rem % wdt;

    int m0 = by * 128, n0 = bx * 128;
    int tid = threadIdx.x, wid = tid >> 6, lane = tid & 63;
    int wr = (wid >> 1) * 64, wc = (wid & 1) * 64;
    int fr = lane & 15, g8 = (lane >> 4) * 8;

    // ---- staging geometry: slot li0 = (row, chunk); holds global chunk (chunk ^ ((row>>2)&1)) ----
    int li0 = wid * 64 + lane;          // [0,256): half0; li0+256: half1 (same row/chunk)
    int rs = li0 >> 1;                  // tile-local row 0..127
    int cs = li0 & 1;
    int kc = ((cs ^ (rs >> 2)) & 1) << 4;   // swizzled byte-within-half-row (0 or 16)
    long aoff = (long)min(m0 + rs, M - 1) * lda + kc;
    long woff = (long)min(n0 + rs, N - 1) * ldw + kc;
    char* a0base = (char*)As0 + wid * 1024;
    char* a1base = (char*)As1 + wid * 1024;
    char* b0base = (char*)Bs0 + wid * 1024;
    char* b1base = (char*)Bs1 + wid * 1024;

    f32x4 acc[4][4] = {};

    auto stage = [&](char* ab, char* bb, int kt) {
        int k0 = kt * 64;
        __builtin_amdgcn_global_load_lds((glb_u8_t*)(A + aoff + k0), (lds_u8_t*)ab, 16, 0, 0);
        __builtin_amdgcn_global_load_lds((glb_u8_t*)(A + aoff + k0 + 32), (lds_u8_t*)(ab + 4096), 16, 0, 0);
        __builtin_amdgcn_global_load_lds((glb_u8_t*)(W + woff + k0), (lds_u8_t*)bb, 16, 0, 0);
        __builtin_amdgcn_global_load_lds((glb_u8_t*)(W + woff + k0 + 32), (lds_u8_t*)(bb + 4096), 16, 0, 0);
    };
    int cg = g8 >> 4, go = g8 & 15;     // global chunk within half-row, byte within chunk
    auto compute = [&](const unsigned char* as, const unsigned char* bs) {
        i64 af[4][2], bw[4][2];
#pragma unroll
        for (int m = 0; m < 4; m++) {
            int rr2 = wr + m * 16 + fr;
            int off = rr2 * 32 + (((cg ^ (rr2 >> 2)) & 1) << 4) + go;
            af[m][0] = *reinterpret_cast<const i64*>(as + off);
            af[m][1] = *reinterpret_cast<const i64*>(as + 4096 + off);
        }
#pragma unroll
        for (int n = 0; n < 4; n++) {
            int rr2 = wc + n * 16 + fr;
            int off = rr2 * 32 + (((cg ^ (rr2 >> 2)) & 1) << 4) + go;
            bw[n][0] = *reinterpret_cast<const i64*>(bs + off);
            bw[n][1] = *reinterpret_cast<const i64*>(bs + 4096 + off);
        }
#pragma unroll
        for (int ks = 0; ks < 2; ks++)
#pragma unroll
            for (int m = 0; m < 4; m++)
#pragma unroll
                for (int n = 0; n < 4; n++)
                    acc[m][n] = __builtin_amdgcn_mfma_f32_16x16x32_fp8_fp8(
                        af[m][ks], bw[n][ks], acc[m][n], 0, 0, 0);
    };

    int nt = K >> 6;                      // 12 (K=768) / 16 (K=1024), even
    stage(a0base, b0base, 0);
    __syncthreads();
    for (int t = 0; t < nt; t += 2) {
        stage(a1base, b1base, t + 1);
        compute(As0, Bs0);
        __syncthreads();
        if (t + 2 < nt) stage(a0base, b0base, t + 2);
        compute(As1, Bs1);
        __syncthreads();
    }

    int crow = (lane >> 4) * 4;
#pragma unroll
    for (int m = 0; m < 4; m++) {
#pragma unroll
        for (int n = 0; n < 4; n++) {
            int col = n0 + wc + n * 16 + fr;
            if (col >= N) continue;
            float bv = bias ? bias[col] : 0.f;
            int rbase = m0 + wr + m * 16 + crow;
#pragma unroll
            for (int rr = 0; rr < 4; rr++) {
                int row = rbase + rr;
                if (row >= M) continue;
                float v = acc[m][n][rr] * outscale + bv;
                if (RELU) v = fmaxf(v, 0.f);
                long idx = (long)row * ldc + col;
                if (OUT == 0)      ((float*)C)[idx] = v;
                else if (OUT == 1) ((u16*)C)[idx] = f2bf(v);
                else               ((unsigned char*)C)[idx] = f2e4m3(v);
            }
        }
    }
}

// ---------------- V transpose with zero-pad ----------------
__global__ __launch_bounds__(256) void transpose_pad(
    const u16* __restrict__ V, long sVb, long sVh, int ldv, int NH,
    u16* __restrict__ VT, long sVT, int rowsIn, int Kp)
{
    __shared__ u16 tile[32][33];
    int z = blockIdx.z, zb = z / NH, zh = z % NH;
    const u16* Vp = V + (long)zb * sVb + (long)zh * sVh;
    int k0 = blockIdx.x * 32, d0 = blockIdx.y * 32;
#pragma unroll
    for (int i = 0; i < 4; i++) {
        int k = k0 + threadIdx.y + i * 8;
        int d = d0 + threadIdx.x;
        tile[threadIdx.y + i * 8][threadIdx.x] = (k < rowsIn) ? Vp[(long)k * ldv + d] : (u16)0;
    }
    __syncthreads();
    u16* Op = VT + (long)z * sVT;
#pragma unroll
    for (int i = 0; i < 4; i++) {
        int d = d0 + threadIdx.y + i * 8;
        int k = k0 + threadIdx.x;
        Op[(long)d * Kp + k] = tile[threadIdx.x][threadIdx.y + i * 8];
    }
}

// ---------------- wave-per-row softmax, vectorized; explicit valid count ----------------
template<int CPL, int CAUSAL>
__global__ __launch_bounds__(256) void softmax2(
    const u16* __restrict__ S, u16* __restrict__ P,
    int ld_in, int valid_in, int ld_out, float scale)
{
    int wid = threadIdx.x >> 6, lane = threadIdx.x & 63;
    long r = (long)blockIdx.x * 4 + wid;
    int q = (int)(r & 511);
    int valid = CAUSAL ? (q + 1) : valid_in;
    const u16* srow = S + r * (long)ld_in;
    u16* prow = P + r * (long)ld_out;
    int base = lane * CPL;
    float v[CPL];
    if constexpr (CPL == 8) {
        u16x8 x = *reinterpret_cast<const u16x8*>(srow + base);
#pragma unroll
        for (int j = 0; j < 8; j++) v[j] = bf2f(x[j]);
    } else {
        u16x4 x = *reinterpret_cast<const u16x4*>(srow + base);
#pragma unroll
        for (int j = 0; j < 4; j++) v[j] = bf2f(x[j]);
    }
    float mx = -3e38f;
#pragma unroll
    for (int j = 0; j < CPL; j++) {
        v[j] *= scale;
        if (base + j < valid) mx = fmaxf(mx, v[j]);
    }
#pragma unroll
    for (int o = 32; o; o >>= 1) mx = fmaxf(mx, __shfl_xor(mx, o, 64));
    float e[CPL], s = 0.f;
#pragma unroll
    for (int j = 0; j < CPL; j++) {
        e[j] = (base + j < valid) ? __expf(v[j] - mx) : 0.f;
        s += e[j];
    }
#pragma unroll
    for (int o = 32; o; o >>= 1) s += __shfl_xor(s, o, 64);
    float inv = 1.f / s;
    if constexpr (CPL == 8) {
        u16x8 o8;
#pragma unroll
        for (int j = 0; j < 8; j++) o8[j] = f2bf(e[j] * inv);
        *reinterpret_cast<u16x8*>(prow + base) = o8;
    } else {
        u16x4 o4;
#pragma unroll
        for (int j = 0; j < 4; j++) o4[j] = f2bf(e[j] * inv);
        *reinterpret_cast<u16x4*>(prow + base) = o4;
    }
}

// ---------------- fused residual add + LayerNorm (bf16 in/out, optional fp8 out) ----------------
__global__ __launch_bounds__(256) void ln_kernel(
    const u16* __restrict__ xin, const u16* __restrict__ subb,
    const float* __restrict__ g, const float* __restrict__ bta,
    u16* __restrict__ xout, unsigned char* __restrict__ q8)
{
    int wid = threadIdx.x >> 6, lane = threadIdx.x & 63;
    long r = (long)blockIdx.x * 4 + wid;
    const u16* a = xin + r * 768;
    const u16* s = subb + r * 768;
    int base = lane * 12;
    float v[12];
    float sum = 0.f;
#pragma unroll
    for (int c = 0; c < 3; c++) {
        ushort4 av = *reinterpret_cast<const ushort4*>(a + base + c * 4);
        ushort4 sv = *reinterpret_cast<const ushort4*>(s + base + c * 4);
        v[c*4+0] = bf2f(av.x) + bf2f(sv.x);
        v[c*4+1] = bf2f(av.y) + bf2f(sv.y);
        v[c*4+2] = bf2f(av.z) + bf2f(sv.z);
        v[c*4+3] = bf2f(av.w) + bf2f(sv.w);
        sum += v[c*4+0] + v[c*4+1] + v[c*4+2] + v[c*4+3];
    }
#pragma unroll
    for (int o = 32; o; o >>= 1) sum += __shfl_xor(sum, o, 64);
    float mean = sum * (1.f / 768.f);
    float vs = 0.f;
#pragma unroll
    for (int j = 0; j < 12; j++) { float t = v[j] - mean; vs += t * t; }
#pragma unroll
    for (int o = 32; o; o >>= 1) vs += __shfl_xor(vs, o, 64);
    float rstd = rsqrtf(vs * (1.f / 768.f) + 1e-5f);
    u16* xo = xout + r * 768;
    unsigned char* qo = q8 ? q8 + r * 768 : nullptr;
#pragma unroll
    for (int c = 0; c < 3; c++) {
        float4 gv = *reinterpret_cast<const float4*>(g + base + c * 4);
        float4 bv = *reinterpret_cast<const float4*>(bta + base + c * 4);
        float y0 = (v[c*4+0] - mean) * rstd * gv.x + bv.x;
        float y1 = (v[c*4+1] - mean) * rstd * gv.y + bv.y;
        float y2 = (v[c*4+2] - mean) * rstd * gv.z + bv.z;
        float y3 = (v[c*4+3] - mean) * rstd * gv.w + bv.w;
        ushort4 o; o.x = f2bf(y0); o.y = f2bf(y1); o.z = f2bf(y2); o.w = f2bf(y3);
        *reinterpret_cast<ushort4*>(xo + base + c * 4) = o;
        if (qo) {
            uchar4 qb; qb.x = f2e4m3(y0); qb.y = f2e4m3(y1); qb.z = f2e4m3(y2); qb.w = f2e4m3(y3);
            *reinterpret_cast<uchar4*>(qo + base + c * 4) = qb;
        }
    }
}

// ---------------- host helpers ----------------
static void g128_bf(hipStream_t st, const u16* A, int lda, const u16* W, int ldw,
                    const float* bias, void* C, int ldc, int M, int N, int K) {
    dim3 g((N + 127) / 128, (M + 127) / 128, 1), b(256, 1, 1);
    gemmT<1,0,128,4><<<g,b,0,st>>>(A,lda,0,0,W,ldw,0,0,bias,C,ldc,0,0,M,N,K,1);
}
static void g64_bf(hipStream_t st, bool relu, const u16* A, int lda, const u16* W, int ldw,
                   const float* bias, void* C, int ldc, int M, int N, int K) {
    dim3 g((N + 127) / 128, (M + 63) / 64, 1), b(256, 1, 1);
    if (relu) gemmT<1,1,64,4><<<g,b,0,st>>>(A,lda,0,0,W,ldw,0,0,bias,C,ldc,0,0,M,N,K,1);
    else      gemmT<1,0,64,4><<<g,b,0,st>>>(A,lda,0,0,W,ldw,0,0,bias,C,ldc,0,0,M,N,K,1);
}
static void gbat(hipStream_t st,
    const u16* A, int lda, long sAb, long sAh,
    const u16* W, int ldw, long sWb, long sWh,
    void* C, int ldc, long sCb, long sCh,
    int M, int N, int K, int Z, int NH) {
    dim3 g((N + 127) / 128, (M + 127) / 128, Z), b(256, 1, 1);
    gemmT<1,0,128,4><<<g,b,0,st>>>(A,lda,sAb,sAh,W,ldw,sWb,sWh,nullptr,C,ldc,sCb,sCh,M,N,K,NH);
}
template<int OUT, int RELU>
static void g8(hipStream_t st, const unsigned char* A, int lda, const unsigned char* W, int ldw,
               const float* bias, void* C, int ldc, int M, int N, int K) {
    dim3 g((N + 127) / 128, (M + 127) / 128, 1), b(256, 1, 1);
    gemm8<OUT,RELU><<<g,b,0,st>>>(A,lda,W,ldw,bias,1.f/256.f,C,ldc,M,N,K);
}

extern "C" void kernel_launch(void* const* d_in, const int* in_sizes, int n_in,
                              void* d_out, int out_size, void* d_ws, size_t ws_size,
                              hipStream_t stream)
{
    const int*   labels = (const int*)  d_in[0];
    const float* vision = (const float*)d_in[1];
    const float* vpw    = (const float*)d_in[2];
    const float* vpb    = (const float*)d_in[3];
    const float* temb   = (const float*)d_in[4];
    const float* pemb   = (const float*)d_in[5];
    const float* saw    = (const float*)d_in[6];
    const float* sab    = (const float*)d_in[7];
    const float* saow   = (const float*)d_in[8];
    const float* saob   = (const float*)d_in[9];
    const float* caw    = (const float*)d_in[10];
    const float* cab    = (const float*)d_in[11];
    const float* caow   = (const float*)d_in[12];
    const float* caob   = (const float*)d_in[13];
    const float* ln1g   = (const float*)d_in[14];
    const float* ln1b   = (const float*)d_in[15];
    const float* ln2g   = (const float*)d_in[16];
    const float* ln2b   = (const float*)d_in[17];
    const float* ln3g   = (const float*)d_in[18];
    const float* ln3b   = (const float*)d_in[19];
    const float* f1w    = (const float*)d_in[20];
    const float* f1b    = (const float*)d_in[21];
    const float* f2w    = (const float*)d_in[22];
    const float* f2b    = (const float*)d_in[23];
    const float* ow     = (const float*)d_in[24];
    const float* ob     = (const float*)d_in[25];
    (void)in_sizes; (void)n_in; (void)out_size;

    // ---- workspace layout ----
    char* p = (char*)d_ws;
    auto alloc = [&](long elems, int esz) -> char* {
        char* r = p; p += ((long)elems * esz + 255) & ~255L; return r;
    };
    u16* wb_vp  = (u16*)alloc(768L*768, 2);
    u16* wb_sao = (u16*)alloc(3L*768*768, 2);
    u16* wb_ca  = (u16*)alloc(3L*2304*768, 2);
    u16* wb_cao = (u16*)alloc(3L*768*768, 2);
    unsigned char* w8_sa = (unsigned char*)alloc(3L*2304*768, 1);  // fp8 x256
    unsigned char* w8_f1 = (unsigned char*)alloc(3L*1024*768, 1);
    unsigned char* w8_f2 = (unsigned char*)alloc(3L*768*1024, 1);
    unsigned char* w8_ow = (unsigned char*)alloc(10000L*768, 1);
    unsigned char* xq    = (unsigned char*)alloc(8192L*768, 1);    // fp8 activations
    unsigned char* h8    = (unsigned char*)alloc(8192L*1024, 1);   // fp8 FF hidden
    u16* vis_b  = (u16*)alloc(3152L*768, 2);
    u16* mem_b  = (u16*)alloc(3152L*768, 2);
    u16* xb     = (u16*)alloc(8192L*768, 2);
    u16* qkv    = (u16*)alloc(8192L*2304, 2);   // reused: {qkv} | {q_bf,kv_bf}
    u16* q_bf   = qkv;
    u16* kv_bf  = qkv + 8192L*768;
    u16* scb    = (u16*)alloc(64L*512*512, 2);
    u16* pr     = (u16*)alloc(64L*512*512, 2);
    u16* vt     = (u16*)alloc(64L*192*512, 2);
    u16* attn   = (u16*)alloc(8192L*768, 2);
    u16* subb   = (u16*)alloc(8192L*768, 2);
    if ((size_t)(p - (char*)d_ws) > ws_size) return;

    // ---- weight casts: 5 bf16 segments + 4 fp8 segments ----
    Cast5 c5;
    c5.s[0] = vpw;    c5.d[0] = wb_vp;  c5.n4[0] = 768L*768/4;
    c5.s[1] = saow;   c5.d[1] = wb_sao; c5.n4[1] = 3L*768*768/4;
    c5.s[2] = caw;    c5.d[2] = wb_ca;  c5.n4[2] = 3L*2304*768/4;
    c5.s[3] = caow;   c5.d[3] = wb_cao; c5.n4[3] = 3L*768*768/4;
    c5.s[4] = vision; c5.d[4] = vis_b;  c5.n4[4] = 3152L*768/4;
    cast5_kernel<<<dim3(512, 1, 5), dim3(256), 0, stream>>>(c5);
    CastQ cq;
    cq.s[0] = saw; cq.d[0] = w8_sa; cq.n4[0] = 3L*2304*768/4;
    cq.s[1] = f1w; cq.d[1] = w8_f1; cq.n4[1] = 3L*1024*768/4;
    cq.s[2] = f2w; cq.d[2] = w8_f2; cq.n4[2] = 3L*768*1024/4;
    cq.s[3] = ow;  cq.d[3] = w8_ow; cq.n4[3] = 10000L*768/4;
    castq_kernel<<<dim3(512, 1, 4), dim3(256), 0, stream>>>(cq);

    embed_kernel<<<dim3(2048), dim3(256), 0, stream>>>(labels, temb, pemb, xb, xq,
                                                       (float*)d_out + 81920000L);

    // mem = vision @ vis_proj_w^T + b
    g64_bf(stream, false, vis_b, 768, wb_vp, 768, vpb, mem_b, 768, 3152, 768, 768);

    const float scale = 0.07216878364870323f;  // 1/sqrt(192)

    for (int l = 0; l < 3; l++) {
        // ======== self-attention ========
        // QKV in fp8: A = xq (embed or prev LN3), W = w8_sa, out bf16
        g8<1,0>(stream, xq, 768, w8_sa + (long)l*2304*768, 768, sab + l*2304,
                qkv, 2304, 8192, 2304, 768);
        transpose_pad<<<dim3(16,6,64), dim3(32,8), 0, stream>>>(
            qkv + 1536, 512L*2304, 192L, 2304, 4, vt, 192L*512, 512, 512);
        gbat(stream, qkv, 2304, 512L*2304, 192, qkv + 768, 2304, 512L*2304, 192,
             scb, 512, 4L*512*512, 512L*512, 512, 512, 192, 64, 4);
        softmax2<8,1><<<dim3(8192), dim3(256), 0, stream>>>(scb, pr, 512, 512, 512, scale);
        gbat(stream, pr, 512, 4L*512*512, 512L*512, vt, 512, 4L*192*512, 192L*512,
             attn, 768, 512L*768, 192, 512, 192, 512, 64, 4);
        g64_bf(stream, false, attn, 768, wb_sao + (long)l*768*768, 768,
               saob + l*768, subb, 768, 8192, 768, 768);
        ln_kernel<<<dim3(2048), dim3(256), 0, stream>>>(xb, subb, ln1g + l*768, ln1b + l*768,
                                                        xb, nullptr);

        // ======== cross-attention ========
        const u16* Wca = wb_ca + (long)l*2304*768;
        g64_bf(stream, false, xb, 768, Wca, 768, cab + l*2304, q_bf, 768, 8192, 768, 768);
        g64_bf(stream, false, mem_b, 768, Wca + 768L*768, 768, cab + l*2304 + 768,
               kv_bf, 1536, 3152, 1536, 768);
        transpose_pad<<<dim3(8,6,64), dim3(32,8), 0, stream>>>(
            kv_bf + 768, 197L*1536, 192L, 1536, 4, vt, 192L*256, 197, 256);
        gbat(stream, q_bf, 768, 512L*768, 192, kv_bf, 1536, 197L*1536, 192,
             scb, 224, 4L*512*224, 512L*224, 512, 197, 192, 64, 4);
        softmax2<4,0><<<dim3(8192), dim3(256), 0, stream>>>(scb, pr, 224, 197, 256, scale);
        gbat(stream, pr, 256, 4L*512*256, 512L*256, vt, 256, 4L*192*256, 192L*256,
             attn, 768, 512L*768, 192, 512, 192, 256, 64, 4);
        g64_bf(stream, false, attn, 768, wb_cao + (long)l*768*768, 768,
               caob + l*768, subb, 768, 8192, 768, 768);
        // LN2 -> xb + xq (FF input)
        ln_kernel<<<dim3(2048), dim3(256), 0, stream>>>(xb, subb, ln2g + l*768, ln2b + l*768,
                                                        xb, xq);

        // ======== feed-forward (fp8) ========
        g8<2,1>(stream, xq, 768, w8_f1 + (long)l*1024*768, 768, f1b + l*1024,
                h8, 1024, 8192, 1024, 768);
        g8<1,0>(stream, h8, 1024, w8_f2 + (long)l*768*1024, 1024, f2b + l*768,
                subb, 768, 8192, 768, 1024);
        // LN3 -> xb + xq (next QKV / vocab input)
        ln_kernel<<<dim3(2048), dim3(256), 0, stream>>>(xb, subb, ln3g + l*768, ln3b + l*768,
                                                        xb, xq);
    }

    // vocab head (fp8, swizzled) -> d_out f32 logits
    g8<0,0>(stream, xq, 768, w8_ow, 768, ob, (float*)d_out, 10000, 8192, 10000, 768);
}

// Round 10
// 1108.752 us; speedup vs baseline: 1.5221x; 1.1506x over previous
//
#include <hip/hip_runtime.h>
#include <hip/hip_fp8.h>

typedef unsigned short u16;
typedef __bf16 bf16x8 __attribute__((ext_vector_type(8)));
typedef float f32x4 __attribute__((ext_vector_type(4)));
typedef unsigned short u16x8 __attribute__((ext_vector_type(8)));
typedef unsigned short u16x4 __attribute__((ext_vector_type(4)));
typedef long i64;

typedef __attribute__((address_space(3))) u16 lds_u16_t;
typedef __attribute__((address_space(1))) const u16 glb_u16_t;
typedef __attribute__((address_space(3))) unsigned char lds_u8_t;
typedef __attribute__((address_space(1))) const unsigned char glb_u8_t;

__device__ __forceinline__ u16 f2bf(float f) {
    union { float f; unsigned u; } v; v.f = f;
    unsigned r = v.u + 0x7FFFu + ((v.u >> 16) & 1u);   // RNE
    return (u16)(r >> 16);
}
__device__ __forceinline__ float bf2f(u16 h) {
    union { unsigned u; float f; } v; v.u = ((unsigned)h) << 16; return v.f;
}
__device__ __forceinline__ unsigned char f2e4m3(float f) {
    __hip_fp8_e4m3 h(f);               // OCP e4m3fn, RNE+sat
    return (unsigned char)h.__x;
}

// ---------------- merged f32 -> fp8 cast: 9 segments, per-segment scale ----------------
struct CastQ { const float* s[9]; unsigned char* d[9]; long n4[9]; float mul[9]; };
__global__ __launch_bounds__(256) void castq_kernel(CastQ a) {
    int seg = blockIdx.z;
    const float* s = a.s[seg];
    unsigned char* d = a.d[seg];
    long n4 = a.n4[seg];
    float mul = a.mul[seg];
    long i = (long)blockIdx.x * 256 + threadIdx.x;
    long stride = (long)gridDim.x * 256;
    for (; i < n4; i += stride) {
        float4 f = reinterpret_cast<const float4*>(s)[i];
        uchar4 o;
        o.x = f2e4m3(f.x * mul); o.y = f2e4m3(f.y * mul);
        o.z = f2e4m3(f.z * mul); o.w = f2e4m3(f.w * mul);
        reinterpret_cast<uchar4*>(d)[i] = o;
    }
}

// ---------------- token + positional embedding (wave-per-row), bf16 + fp8 out + labels ----------------
__global__ __launch_bounds__(256) void embed_kernel(
    const int* __restrict__ labels, const float* __restrict__ tok_emb,
    const float* __restrict__ pos_emb, u16* __restrict__ xb,
    unsigned char* __restrict__ xq, float* __restrict__ lab_out)
{
    int wid = threadIdx.x >> 6, lane = threadIdx.x & 63;
    int r = blockIdx.x * 4 + wid;       // 0..8191 = b*512+t
    int b = r >> 9, t = r & 511;
    int tok = labels[b * 513 + t];      // labels[:, :-1]
    if (lane == 0) lab_out[r] = (float)labels[b * 513 + t + 1];
    const float* te = tok_emb + (long)tok * 768;
    const float* pe = pos_emb + (long)t * 768;
    u16* xo = xb + (long)r * 768;
    unsigned char* qo = xq + (long)r * 768;
    int base = lane * 12;
#pragma unroll
    for (int c = 0; c < 3; c++) {
        float4 a = *reinterpret_cast<const float4*>(te + base + c * 4);
        float4 p = *reinterpret_cast<const float4*>(pe + base + c * 4);
        float v0 = a.x + p.x, v1 = a.y + p.y, v2 = a.z + p.z, v3 = a.w + p.w;
        ushort4 o; o.x = f2bf(v0); o.y = f2bf(v1); o.z = f2bf(v2); o.w = f2bf(v3);
        *reinterpret_cast<ushort4*>(xo + base + c * 4) = o;
        uchar4 q; q.x = f2e4m3(v0); q.y = f2e4m3(v1); q.z = f2e4m3(v2); q.w = f2e4m3(v3);
        *reinterpret_cast<uchar4*>(qo + base + c * 4) = q;
    }
}

// ================= 128x128 bf16 MFMA GEMM, 2-phase, BATCHED (attention) =========
// OUT: 1=bf16, 2=fp8.
template<int OUT>
__global__ __launch_bounds__(256, 4) void gemmT(
    const u16* __restrict__ A, int lda, long sAb, long sAh,
    const u16* __restrict__ W, int ldw, long sWb, long sWh,
    void* __restrict__ C, int ldc, long sCb, long sCh,
    int M, int N, int K, int NH)
{
    __shared__ __align__(16) u16 As0[128 * 32];
    __shared__ __align__(16) u16 As1[128 * 32];
    __shared__ __align__(16) u16 Bs0[128 * 32];
    __shared__ __align__(16) u16 Bs1[128 * 32];

    int z = blockIdx.z, zb = z / NH, zh = z % NH;
    const u16* Ap = A + (long)zb * sAb + (long)zh * sAh;
    const u16* Wp = W + (long)zb * sWb + (long)zh * sWh;
    long coff = (long)zb * sCb + (long)zh * sCh;

    int gx = (int)gridDim.x, gy = (int)gridDim.y;
    int nwg = gx * gy;
    int orig = (int)(blockIdx.y * gridDim.x + blockIdx.x);
    int q = nwg >> 3, r = nwg & 7;
    int xcd = orig & 7, loc = orig >> 3;
    int wg = (xcd < r ? xcd * (q + 1) : r * (q + 1) + (xcd - r) * q) + loc;
    int full = 8 * gy;
    int nsc = (gx + 7) >> 3;
    int sc = wg / full; if (sc > nsc - 1) sc = nsc - 1;
    int rem = wg - sc * full;
    int wdt = gx - sc * 8; if (wdt > 8) wdt = 8;
    int by = rem / wdt, bx = sc * 8 + rem % wdt;

    int m0 = by * 128, n0 = bx * 128;
    int tid = threadIdx.x, wid = tid >> 6, lane = tid & 63;
    int wr = (wid >> 1) * 64, wc = (wid & 1) * 64;
    int fr = lane & 15, fk = (lane >> 4) * 8;

    int li0 = wid * 64 + lane;
    int li1 = li0 + 256;
    int r0 = li0 >> 2, c0 = (li0 & 3) * 8;
    int r1 = li1 >> 2, c1 = (li1 & 3) * 8;
    long aoff0 = (long)min(m0 + r0, M - 1) * lda + c0;
    long aoff1 = (long)min(m0 + r1, M - 1) * lda + c1;
    long woff0 = (long)min(n0 + r0, N - 1) * ldw + c0;
    long woff1 = (long)min(n0 + r1, N - 1) * ldw + c1;
    char* a0base = (char*)As0 + wid * 1024;
    char* a1base = (char*)As1 + wid * 1024;
    char* b0base = (char*)Bs0 + wid * 1024;
    char* b1base = (char*)Bs1 + wid * 1024;

    f32x4 acc[4][4] = {};

    auto stage = [&](char* ab, char* bb, int kt) {
        int k0 = kt * 32;
        __builtin_amdgcn_global_load_lds((glb_u16_t*)(Ap + aoff0 + k0), (lds_u16_t*)ab, 16, 0, 0);
        __builtin_amdgcn_global_load_lds((glb_u16_t*)(Ap + aoff1 + k0), (lds_u16_t*)(ab + 4096), 16, 0, 0);
        __builtin_amdgcn_global_load_lds((glb_u16_t*)(Wp + woff0 + k0), (lds_u16_t*)bb, 16, 0, 0);
        __builtin_amdgcn_global_load_lds((glb_u16_t*)(Wp + woff1 + k0), (lds_u16_t*)(bb + 4096), 16, 0, 0);
    };
    auto compute = [&](const u16* as, const u16* bs) {
        bf16x8 af[4], bw[4];
#pragma unroll
        for (int m = 0; m < 4; m++)
            af[m] = *reinterpret_cast<const bf16x8*>(&as[(wr + m * 16 + fr) * 32 + fk]);
#pragma unroll
        for (int n = 0; n < 4; n++)
            bw[n] = *reinterpret_cast<const bf16x8*>(&bs[(wc + n * 16 + fr) * 32 + fk]);
#pragma unroll
        for (int m = 0; m < 4; m++)
#pragma unroll
            for (int n = 0; n < 4; n++)
                acc[m][n] = __builtin_amdgcn_mfma_f32_16x16x32_bf16(af[m], bw[n], acc[m][n], 0, 0, 0);
    };

    int nt = K >> 5;
    stage(a0base, b0base, 0);
    __syncthreads();
    for (int t = 0; t < nt; t += 2) {
        stage(a1base, b1base, t + 1);
        compute(As0, Bs0);
        __syncthreads();
        if (t + 2 < nt) stage(a0base, b0base, t + 2);
        compute(As1, Bs1);
        __syncthreads();
    }

    int crow = (lane >> 4) * 4;
#pragma unroll
    for (int m = 0; m < 4; m++) {
#pragma unroll
        for (int n = 0; n < 4; n++) {
            int col = n0 + wc + n * 16 + fr;
            if (col >= N) continue;
            int rbase = m0 + wr + m * 16 + crow;
#pragma unroll
            for (int rr = 0; rr < 4; rr++) {
                int row = rbase + rr;
                if (row >= M) continue;
                float v = acc[m][n][rr];
                long idx = coff + (long)row * ldc + col;
                if (OUT == 1) ((u16*)C)[idx] = f2bf(v);
                else          ((unsigned char*)C)[idx] = f2e4m3(v);
            }
        }
    }
}

// ================= BMx128 FP8 MFMA GEMM, BK=64, 2-phase, swizzled LDS =================
// LDS per matrix: halves (k 0..31 / 32..63), 32-B rows, 16-B chunk ^= (row>>2)&1 on BOTH sides.
// OUT: 0=f32, 1=bf16, 2=fp8. FUSEVT: also scatter V^T (cols>=1536, QKV only).
template<int OUT, int RELU, int BM, int FUSEVT>
__global__ __launch_bounds__(256, 4) void gemm8(
    const unsigned char* __restrict__ A, int lda,
    const unsigned char* __restrict__ W, int ldw,
    const float* __restrict__ bias, float outscale,
    void* __restrict__ C, int ldc, u16* __restrict__ vt,
    int M, int N, int K)
{
    constexpr int NREP = (BM == 128) ? 4 : 2;
    constexpr int AHALF = (BM == 128) ? 4096 : 2048;
    __shared__ __align__(16) unsigned char As0[BM * 64];
    __shared__ __align__(16) unsigned char As1[BM * 64];
    __shared__ __align__(16) unsigned char Bs0[128 * 64];
    __shared__ __align__(16) unsigned char Bs1[128 * 64];

    int gx = (int)gridDim.x, gy = (int)gridDim.y;
    int nwg = gx * gy;
    int orig = (int)(blockIdx.y * gridDim.x + blockIdx.x);
    int q = nwg >> 3, r = nwg & 7;
    int xcd = orig & 7, loc = orig >> 3;
    int wg = (xcd < r ? xcd * (q + 1) : r * (q + 1) + (xcd - r) * q) + loc;
    int full = 8 * gy;
    int nsc = (gx + 7) >> 3;
    int sc = wg / full; if (sc > nsc - 1) sc = nsc - 1;
    int rem = wg - sc * full;
    int wdt = gx - sc * 8; if (wdt > 8) wdt = 8;
    int by = rem / wdt, bx = sc * 8 + rem % wdt;

    int m0 = by * BM, n0 = bx * 128;
    int tid = threadIdx.x, wid = tid >> 6, lane = tid & 63;
    int wr = (BM == 128) ? (wid >> 1) * 64 : 0;
    int wc = (BM == 128) ? (wid & 1) * 64 : wid * 32;
    int fr = lane & 15, gk = (lane >> 4) * 8;

    // ---- staging geometry (validated swizzle: chunk ^= (row>>2)&1) ----
    int li0 = wid * 64 + lane;
    int rsW = li0 >> 1, csW = li0 & 1;
    int kcW = ((csW ^ (rsW >> 2)) & 1) << 4;
    long woff = (long)min(n0 + rsW, N - 1) * ldw + kcW;
    long aoff;
    if constexpr (BM == 128) {
        aoff = (long)min(m0 + rsW, M - 1) * lda + kcW;
    } else {
        int halfA = li0 >> 7;
        int rsA = (li0 >> 1) & 63, csA = li0 & 1;
        int kcA = ((csA ^ (rsA >> 2)) & 1) << 4;
        aoff = (long)min(m0 + rsA, M - 1) * lda + halfA * 32 + kcA;
    }
    char* a0base = (char*)As0 + wid * 1024;
    char* a1base = (char*)As1 + wid * 1024;
    char* b0base = (char*)Bs0 + wid * 1024;
    char* b1base = (char*)Bs1 + wid * 1024;

    f32x4 acc[4][NREP] = {};

    auto stage = [&](char* ab, char* bb, int kt) {
        int k0 = kt * 64;
        if constexpr (BM == 128) {
            __builtin_amdgcn_global_load_lds((glb_u8_t*)(A + aoff + k0), (lds_u8_t*)ab, 16, 0, 0);
            __builtin_amdgcn_global_load_lds((glb_u8_t*)(A + aoff + k0 + 32), (lds_u8_t*)(ab + 4096), 16, 0, 0);
        } else {
            __builtin_amdgcn_global_load_lds((glb_u8_t*)(A + aoff + k0), (lds_u8_t*)ab, 16, 0, 0);
        }
        __builtin_amdgcn_global_load_lds((glb_u8_t*)(W + woff + k0), (lds_u8_t*)bb, 16, 0, 0);
        __builtin_amdgcn_global_load_lds((glb_u8_t*)(W + woff + k0 + 32), (lds_u8_t*)(bb + 4096), 16, 0, 0);
    };
    int cg = gk >> 4, go = gk & 15;
    auto compute = [&](const unsigned char* as, const unsigned char* bs) {
        i64 af[4][2], bw[NREP][2];
#pragma unroll
        for (int m = 0; m < 4; m++) {
            int rr2 = wr + m * 16 + fr;
            int off = rr2 * 32 + (((cg ^ (rr2 >> 2)) & 1) << 4) + go;
            af[m][0] = *reinterpret_cast<const i64*>(as + off);
            af[m][1] = *reinterpret_cast<const i64*>(as + AHALF + off);
        }
#pragma unroll
        for (int n = 0; n < NREP; n++) {
            int rr2 = wc + n * 16 + fr;
            int off = rr2 * 32 + (((cg ^ (rr2 >> 2)) & 1) << 4) + go;
            bw[n][0] = *reinterpret_cast<const i64*>(bs + off);
            bw[n][1] = *reinterpret_cast<const i64*>(bs + 4096 + off);
        }
#pragma unroll
        for (int ks = 0; ks < 2; ks++)
#pragma unroll
            for (int m = 0; m < 4; m++)
#pragma unroll
                for (int n = 0; n < NREP; n++)
                    acc[m][n] = __builtin_amdgcn_mfma_f32_16x16x32_fp8_fp8(
                        af[m][ks], bw[n][ks], acc[m][n], 0, 0, 0);
    };

    int nt = K >> 6;                      // even for K in {768, 1024}
    stage(a0base, b0base, 0);
    __syncthreads();
    for (int t = 0; t < nt; t += 2) {
        stage(a1base, b1base, t + 1);
        compute(As0, Bs0);
        __syncthreads();
        if (t + 2 < nt) stage(a0base, b0base, t + 2);
        compute(As1, Bs1);
        __syncthreads();
    }

    int crow = (lane >> 4) * 4;
#pragma unroll
    for (int m = 0; m < 4; m++) {
#pragma unroll
        for (int n = 0; n < NREP; n++) {
            int col = n0 + wc + n * 16 + fr;
            if (col >= N) continue;
            float bv = bias ? bias[col] : 0.f;
            int rbase = m0 + wr + m * 16 + crow;
            float vv[4];
#pragma unroll
            for (int rr = 0; rr < 4; rr++) {
                int row = rbase + rr;
                if (row >= M) continue;
                float v = acc[m][n][rr] * outscale + bv;
                if (RELU) v = fmaxf(v, 0.f);
                vv[rr] = v;
                long idx = (long)row * ldc + col;
                if (OUT == 0)      ((float*)C)[idx] = v;
                else if (OUT == 1) ((u16*)C)[idx] = f2bf(v);
                else               ((unsigned char*)C)[idx] = f2e4m3(v);
            }
            if constexpr (FUSEVT) {
                // QKV: cols 1536.. are V; scatter V^T[z=b*4+h][d][k] (M=8192, no edges)
                if (col >= 1536) {
                    int tt = col - 1536;
                    int h = tt / 192, d = tt - h * 192;
                    int b = rbase >> 9, k0 = rbase & 511;
                    ushort4 o;
                    o.x = f2bf(vv[0]); o.y = f2bf(vv[1]); o.z = f2bf(vv[2]); o.w = f2bf(vv[3]);
                    *reinterpret_cast<ushort4*>(vt + ((long)((b << 2) + h) * 192 + d) * 512 + k0) = o;
                }
            }
        }
    }
}

// ---------------- V transpose with zero-pad (CA only) ----------------
__global__ __launch_bounds__(256) void transpose_pad(
    const u16* __restrict__ V, long sVb, long sVh, int ldv, int NH,
    u16* __restrict__ VT, long sVT, int rowsIn, int Kp)
{
    __shared__ u16 tile[32][33];
    int z = blockIdx.z, zb = z / NH, zh = z % NH;
    const u16* Vp = V + (long)zb * sVb + (long)zh * sVh;
    int k0 = blockIdx.x * 32, d0 = blockIdx.y * 32;
#pragma unroll
    for (int i = 0; i < 4; i++) {
        int k = k0 + threadIdx.y + i * 8;
        int d = d0 + threadIdx.x;
        tile[threadIdx.y + i * 8][threadIdx.x] = (k < rowsIn) ? Vp[(long)k * ldv + d] : (u16)0;
    }
    __syncthreads();
    u16* Op = VT + (long)z * sVT;
#pragma unroll
    for (int i = 0; i < 4; i++) {
        int d = d0 + threadIdx.y + i * 8;
        int k = k0 + threadIdx.x;
        Op[(long)d * Kp + k] = tile[threadIdx.x][threadIdx.y + i * 8];
    }
}

// ---------------- wave-per-row softmax, vectorized; explicit valid count ----------------
template<int CPL, int CAUSAL>
__global__ __launch_bounds__(256) void softmax2(
    const u16* __restrict__ S, u16* __restrict__ P,
    int ld_in, int valid_in, int ld_out, float scale)
{
    int wid = threadIdx.x >> 6, lane = threadIdx.x & 63;
    long r = (long)blockIdx.x * 4 + wid;
    int q = (int)(r & 511);
    int valid = CAUSAL ? (q + 1) : valid_in;
    const u16* srow = S + r * (long)ld_in;
    u16* prow = P + r * (long)ld_out;
    int base = lane * CPL;
    float v[CPL];
    if constexpr (CPL == 8) {
        u16x8 x = *reinterpret_cast<const u16x8*>(srow + base);
#pragma unroll
        for (int j = 0; j < 8; j++) v[j] = bf2f(x[j]);
    } else {
        u16x4 x = *reinterpret_cast<const u16x4*>(srow + base);
#pragma unroll
        for (int j = 0; j < 4; j++) v[j] = bf2f(x[j]);
    }
    float mx = -3e38f;
#pragma unroll
    for (int j = 0; j < CPL; j++) {
        v[j] *= scale;
        if (base + j < valid) mx = fmaxf(mx, v[j]);
    }
#pragma unroll
    for (int o = 32; o; o >>= 1) mx = fmaxf(mx, __shfl_xor(mx, o, 64));
    float e[CPL], s = 0.f;
#pragma unroll
    for (int j = 0; j < CPL; j++) {
        e[j] = (base + j < valid) ? __expf(v[j] - mx) : 0.f;
        s += e[j];
    }
#pragma unroll
    for (int o = 32; o; o >>= 1) s += __shfl_xor(s, o, 64);
    float inv = 1.f / s;
    if constexpr (CPL == 8) {
        u16x8 o8;
#pragma unroll
        for (int j = 0; j < 8; j++) o8[j] = f2bf(e[j] * inv);
        *reinterpret_cast<u16x8*>(prow + base) = o8;
    } else {
        u16x4 o4;
#pragma unroll
        for (int j = 0; j < 4; j++) o4[j] = f2bf(e[j] * inv);
        *reinterpret_cast<u16x4*>(prow + base) = o4;
    }
}

// ---------------- fused residual add + LayerNorm (bf16 in/out + fp8 out) ----------------
__global__ __launch_bounds__(256) void ln_kernel(
    const u16* __restrict__ xin, const u16* __restrict__ subb,
    const float* __restrict__ g, const float* __restrict__ bta,
    u16* __restrict__ xout, unsigned char* __restrict__ q8)
{
    int wid = threadIdx.x >> 6, lane = threadIdx.x & 63;
    long r = (long)blockIdx.x * 4 + wid;
    const u16* a = xin + r * 768;
    const u16* s = subb + r * 768;
    int base = lane * 12;
    float v[12];
    float sum = 0.f;
#pragma unroll
    for (int c = 0; c < 3; c++) {
        ushort4 av = *reinterpret_cast<const ushort4*>(a + base + c * 4);
        ushort4 sv = *reinterpret_cast<const ushort4*>(s + base + c * 4);
        v[c*4+0] = bf2f(av.x) + bf2f(sv.x);
        v[c*4+1] = bf2f(av.y) + bf2f(sv.y);
        v[c*4+2] = bf2f(av.z) + bf2f(sv.z);
        v[c*4+3] = bf2f(av.w) + bf2f(sv.w);
        sum += v[c*4+0] + v[c*4+1] + v[c*4+2] + v[c*4+3];
    }
#pragma unroll
    for (int o = 32; o; o >>= 1) sum += __shfl_xor(sum, o, 64);
    float mean = sum * (1.f / 768.f);
    float vs = 0.f;
#pragma unroll
    for (int j = 0; j < 12; j++) { float t = v[j] - mean; vs += t * t; }
#pragma unroll
    for (int o = 32; o; o >>= 1) vs += __shfl_xor(vs, o, 64);
    float rstd = rsqrtf(vs * (1.f / 768.f) + 1e-5f);
    u16* xo = xout + r * 768;
    unsigned char* qo = q8 + r * 768;
#pragma unroll
    for (int c = 0; c < 3; c++) {
        float4 gv = *reinterpret_cast<const float4*>(g + base + c * 4);
        float4 bv = *reinterpret_cast<const float4*>(bta + base + c * 4);
        float y0 = (v[c*4+0] - mean) * rstd * gv.x + bv.x;
        float y1 = (v[c*4+1] - mean) * rstd * gv.y + bv.y;
        float y2 = (v[c*4+2] - mean) * rstd * gv.z + bv.z;
        float y3 = (v[c*4+3] - mean) * rstd * gv.w + bv.w;
        ushort4 o; o.x = f2bf(y0); o.y = f2bf(y1); o.z = f2bf(y2); o.w = f2bf(y3);
        *reinterpret_cast<ushort4*>(xo + base + c * 4) = o;
        uchar4 qb; qb.x = f2e4m3(y0); qb.y = f2e4m3(y1); qb.z = f2e4m3(y2); qb.w = f2e4m3(y3);
        *reinterpret_cast<uchar4*>(qo + base + c * 4) = qb;
    }
}

// ---------------- host helpers ----------------
template<int OUT>
static void gbat(hipStream_t st,
    const u16* A, int lda, long sAb, long sAh,
    const u16* W, int ldw, long sWb, long sWh,
    void* C, int ldc, long sCb, long sCh,
    int M, int N, int K, int Z, int NH) {
    dim3 g((N + 127) / 128, (M + 127) / 128, Z), b(256, 1, 1);
    gemmT<OUT><<<g,b,0,st>>>(A,lda,sAb,sAh,W,ldw,sWb,sWh,C,ldc,sCb,sCh,M,N,K,NH);
}
template<int OUT, int RELU, int BM>
static void g8(hipStream_t st, const unsigned char* A, int lda, const unsigned char* W, int ldw,
               const float* bias, void* C, int ldc, int M, int N, int K) {
    dim3 g((N + 127) / 128, (M + BM - 1) / BM, 1), b(256, 1, 1);
    gemm8<OUT,RELU,BM,0><<<g,b,0,st>>>(A,lda,W,ldw,bias,1.f/256.f,C,ldc,nullptr,M,N,K);
}
static void g8qkv(hipStream_t st, const unsigned char* A, const unsigned char* W,
                  const float* bias, u16* C, u16* vt) {
    dim3 g(18, 64, 1), b(256, 1, 1);
    gemm8<1,0,128,1><<<g,b,0,st>>>(A,768,W,768,bias,1.f/256.f,C,2304,vt,8192,2304,768);
}

extern "C" void kernel_launch(void* const* d_in, const int* in_sizes, int n_in,
                              void* d_out, int out_size, void* d_ws, size_t ws_size,
                              hipStream_t stream)
{
    const int*   labels = (const int*)  d_in[0];
    const float* vision = (const float*)d_in[1];
    const float* vpw    = (const float*)d_in[2];
    const float* vpb    = (const float*)d_in[3];
    const float* temb   = (const float*)d_in[4];
    const float* pemb   = (const float*)d_in[5];
    const float* saw    = (const float*)d_in[6];
    const float* sab    = (const float*)d_in[7];
    const float* saow   = (const float*)d_in[8];
    const float* saob   = (const float*)d_in[9];
    const float* caw    = (const float*)d_in[10];
    const float* cab    = (const float*)d_in[11];
    const float* caow   = (const float*)d_in[12];
    const float* caob   = (const float*)d_in[13];
    const float* ln1g   = (const float*)d_in[14];
    const float* ln1b   = (const float*)d_in[15];
    const float* ln2g   = (const float*)d_in[16];
    const float* ln2b   = (const float*)d_in[17];
    const float* ln3g   = (const float*)d_in[18];
    const float* ln3b   = (const float*)d_in[19];
    const float* f1w    = (const float*)d_in[20];
    const float* f1b    = (const float*)d_in[21];
    const float* f2w    = (const float*)d_in[22];
    const float* f2b    = (const float*)d_in[23];
    const float* ow     = (const float*)d_in[24];
    const float* ob     = (const float*)d_in[25];
    (void)in_sizes; (void)n_in; (void)out_size;

    // ---- workspace layout ----
    char* p = (char*)d_ws;
    auto alloc = [&](long elems, int esz) -> char* {
        char* r = p; p += ((long)elems * esz + 255) & ~255L; return r;
    };
    unsigned char* w8_sa  = (unsigned char*)alloc(3L*2304*768, 1);  // fp8 weights x256
    unsigned char* w8_ca  = (unsigned char*)alloc(3L*2304*768, 1);
    unsigned char* w8_sao = (unsigned char*)alloc(3L*768*768, 1);
    unsigned char* w8_cao = (unsigned char*)alloc(3L*768*768, 1);
    unsigned char* w8_f1  = (unsigned char*)alloc(3L*1024*768, 1);
    unsigned char* w8_f2  = (unsigned char*)alloc(3L*768*1024, 1);
    unsigned char* w8_ow  = (unsigned char*)alloc(10000L*768, 1);
    unsigned char* w8_vp  = (unsigned char*)alloc(768L*768, 1);
    unsigned char* vis8   = (unsigned char*)alloc(3152L*768, 1);    // fp8 activations (x1)
    unsigned char* mem8   = (unsigned char*)alloc(3152L*768, 1);
    unsigned char* xq     = (unsigned char*)alloc(8192L*768, 1);
    unsigned char* h8     = (unsigned char*)alloc(8192L*1024, 1);
    unsigned char* attn8  = (unsigned char*)alloc(8192L*768, 1);
    u16* xb   = (u16*)alloc(8192L*768, 2);
    u16* qkv  = (u16*)alloc(8192L*2304, 2);   // reused: {qkv} | {q_bf, kv_bf}
    u16* q_bf = qkv;
    u16* kv_bf = qkv + 8192L*768;
    u16* scb  = (u16*)alloc(64L*512*512, 2);
    u16* pr   = (u16*)alloc(64L*512*512, 2);
    u16* vt   = (u16*)alloc(64L*192*512, 2);
    u16* subb = (u16*)alloc(8192L*768, 2);
    if ((size_t)(p - (char*)d_ws) > ws_size) return;

    // ---- all casts -> fp8 in one launch (weights x256, vision x1) ----
    CastQ cq;
    cq.s[0] = saw;    cq.d[0] = w8_sa;  cq.n4[0] = 3L*2304*768/4;  cq.mul[0] = 256.f;
    cq.s[1] = caw;    cq.d[1] = w8_ca;  cq.n4[1] = 3L*2304*768/4;  cq.mul[1] = 256.f;
    cq.s[2] = saow;   cq.d[2] = w8_sao; cq.n4[2] = 3L*768*768/4;   cq.mul[2] = 256.f;
    cq.s[3] = caow;   cq.d[3] = w8_cao; cq.n4[3] = 3L*768*768/4;   cq.mul[3] = 256.f;
    cq.s[4] = f1w;    cq.d[4] = w8_f1;  cq.n4[4] = 3L*1024*768/4;  cq.mul[4] = 256.f;
    cq.s[5] = f2w;    cq.d[5] = w8_f2;  cq.n4[5] = 3L*768*1024/4;  cq.mul[5] = 256.f;
    cq.s[6] = ow;     cq.d[6] = w8_ow;  cq.n4[6] = 10000L*768/4;   cq.mul[6] = 256.f;
    cq.s[7] = vpw;    cq.d[7] = w8_vp;  cq.n4[7] = 768L*768/4;     cq.mul[7] = 256.f;
    cq.s[8] = vision; cq.d[8] = vis8;   cq.n4[8] = 3152L*768/4;    cq.mul[8] = 1.f;
    castq_kernel<<<dim3(512, 1, 9), dim3(256), 0, stream>>>(cq);

    embed_kernel<<<dim3(2048), dim3(256), 0, stream>>>(labels, temb, pemb, xb, xq,
                                                       (float*)d_out + 81920000L);

    // mem = vision @ vis_proj_w^T + b  -> fp8
    g8<2,0,64>(stream, vis8, 768, w8_vp, 768, vpb, mem8, 768, 3152, 768, 768);

    const float scale = 0.07216878364870323f;  // 1/sqrt(192)

    for (int l = 0; l < 3; l++) {
        // ======== self-attention ========
        g8qkv(stream, xq, w8_sa + (long)l*2304*768, sab + l*2304, qkv, vt);  // + fused V^T
        gbat<1>(stream, qkv, 2304, 512L*2304, 192, qkv + 768, 2304, 512L*2304, 192,
                scb, 512, 4L*512*512, 512L*512, 512, 512, 192, 64, 4);
        softmax2<8,1><<<dim3(8192), dim3(256), 0, stream>>>(scb, pr, 512, 512, 512, scale);
        gbat<2>(stream, pr, 512, 4L*512*512, 512L*512, vt, 512, 4L*192*512, 192L*512,
                attn8, 768, 512L*768, 192, 512, 192, 512, 64, 4);
        g8<1,0,64>(stream, attn8, 768, w8_sao + (long)l*768*768, 768,
                   saob + l*768, subb, 768, 8192, 768, 768);
        ln_kernel<<<dim3(2048), dim3(256), 0, stream>>>(xb, subb, ln1g + l*768, ln1b + l*768,
                                                        xb, xq);

        // ======== cross-attention ========
        g8<1,0,64>(stream, xq, 768, w8_ca + (long)l*2304*768, 768,
                   cab + l*2304, q_bf, 768, 8192, 768, 768);
        g8<1,0,64>(stream, mem8, 768, w8_ca + (long)l*2304*768 + 768L*768, 768,
                   cab + l*2304 + 768, kv_bf, 1536, 3152, 1536, 768);
        transpose_pad<<<dim3(8,6,64), dim3(32,8), 0, stream>>>(
            kv_bf + 768, 197L*1536, 192L, 1536, 4, vt, 192L*256, 197, 256);
        gbat<1>(stream, q_bf, 768, 512L*768, 192, kv_bf, 1536, 197L*1536, 192,
                scb, 224, 4L*512*224, 512L*224, 512, 197, 192, 64, 4);
        softmax2<4,0><<<dim3(8192), dim3(256), 0, stream>>>(scb, pr, 224, 197, 256, scale);
        gbat<2>(stream, pr, 256, 4L*512*256, 512L*256, vt, 256, 4L*192*256, 192L*256,
                attn8, 768, 512L*768, 192, 512, 192, 256, 64, 4);
        g8<1,0,64>(stream, attn8, 768, w8_cao + (long)l*768*768, 768,
                   caob + l*768, subb, 768, 8192, 768, 768);
        ln_kernel<<<dim3(2048), dim3(256), 0, stream>>>(xb, subb, ln2g + l*768, ln2b + l*768,
                                                        xb, xq);

        // ======== feed-forward (fp8) ========
        g8<2,1,128>(stream, xq, 768, w8_f1 + (long)l*1024*768, 768, f1b + l*1024,
                    h8, 1024, 8192, 1024, 768);
        g8<1,0,64>(stream, h8, 1024, w8_f2 + (long)l*768*1024, 1024, f2b + l*768,
                   subb, 768, 8192, 768, 1024);
        ln_kernel<<<dim3(2048), dim3(256), 0, stream>>>(xb, subb, ln3g + l*768, ln3b + l*768,
                                                        xb, xq);
    }

    // vocab head (fp8, BM=128) -> d_out f32 logits
    g8<0,0,128>(stream, xq, 768, w8_ow, 768, ob, (float*)d_out, 10000, 8192, 10000, 768);
}

// Round 11
// 1067.277 us; speedup vs baseline: 1.5812x; 1.0389x over previous
//
#include <hip/hip_runtime.h>
#include <hip/hip_fp8.h>

typedef unsigned short u16;
typedef float f32x4 __attribute__((ext_vector_type(4)));
typedef unsigned short u16x8 __attribute__((ext_vector_type(8)));
typedef unsigned short u16x4 __attribute__((ext_vector_type(4)));
typedef long i64;

typedef __attribute__((address_space(3))) unsigned char lds_u8_t;
typedef __attribute__((address_space(1))) const unsigned char glb_u8_t;

__device__ __forceinline__ u16 f2bf(float f) {
    union { float f; unsigned u; } v; v.f = f;
    unsigned r = v.u + 0x7FFFu + ((v.u >> 16) & 1u);   // RNE
    return (u16)(r >> 16);
}
__device__ __forceinline__ float bf2f(u16 h) {
    union { unsigned u; float f; } v; v.u = ((unsigned)h) << 16; return v.f;
}
__device__ __forceinline__ unsigned char f2e4m3(float f) {
    __hip_fp8_e4m3 h(f);               // OCP e4m3fn, RNE+sat
    return (unsigned char)h.__x;
}

// ---------------- merged f32 -> fp8 cast: 9 segments, per-segment scale ----------------
struct CastQ { const float* s[9]; unsigned char* d[9]; long n4[9]; float mul[9]; };
__global__ __launch_bounds__(256) void castq_kernel(CastQ a) {
    int seg = blockIdx.z;
    const float* s = a.s[seg];
    unsigned char* d = a.d[seg];
    long n4 = a.n4[seg];
    float mul = a.mul[seg];
    long i = (long)blockIdx.x * 256 + threadIdx.x;
    long stride = (long)gridDim.x * 256;
    for (; i < n4; i += stride) {
        float4 f = reinterpret_cast<const float4*>(s)[i];
        uchar4 o;
        o.x = f2e4m3(f.x * mul); o.y = f2e4m3(f.y * mul);
        o.z = f2e4m3(f.z * mul); o.w = f2e4m3(f.w * mul);
        reinterpret_cast<uchar4*>(d)[i] = o;
    }
}

// ---------------- token + positional embedding (wave-per-row), bf16 + fp8 out + labels ----------------
__global__ __launch_bounds__(256) void embed_kernel(
    const int* __restrict__ labels, const float* __restrict__ tok_emb,
    const float* __restrict__ pos_emb, u16* __restrict__ xb,
    unsigned char* __restrict__ xq, float* __restrict__ lab_out)
{
    int wid = threadIdx.x >> 6, lane = threadIdx.x & 63;
    int r = blockIdx.x * 4 + wid;       // 0..8191 = b*512+t
    int b = r >> 9, t = r & 511;
    int tok = labels[b * 513 + t];      // labels[:, :-1]
    if (lane == 0) lab_out[r] = (float)labels[b * 513 + t + 1];
    const float* te = tok_emb + (long)tok * 768;
    const float* pe = pos_emb + (long)t * 768;
    u16* xo = xb + (long)r * 768;
    unsigned char* qo = xq + (long)r * 768;
    int base = lane * 12;
#pragma unroll
    for (int c = 0; c < 3; c++) {
        float4 a = *reinterpret_cast<const float4*>(te + base + c * 4);
        float4 p = *reinterpret_cast<const float4*>(pe + base + c * 4);
        float v0 = a.x + p.x, v1 = a.y + p.y, v2 = a.z + p.z, v3 = a.w + p.w;
        ushort4 o; o.x = f2bf(v0); o.y = f2bf(v1); o.z = f2bf(v2); o.w = f2bf(v3);
        *reinterpret_cast<ushort4*>(xo + base + c * 4) = o;
        uchar4 q; q.x = f2e4m3(v0); q.y = f2e4m3(v1); q.z = f2e4m3(v2); q.w = f2e4m3(v3);
        *reinterpret_cast<uchar4*>(qo + base + c * 4) = q;
    }
}

// ================= BMx128 FP8 MFMA GEMM, BK=64, 2-phase, swizzled LDS, BATCHED =================
// LDS per matrix: halves (k 0..31 / 32..63), 32-B rows, 16-B chunk ^= (row>>2)&1 on BOTH sides.
// OUT: 0=f32, 1=bf16, 2=fp8. QKV: cols<1536 -> fp8 C (ld 1536); cols>=1536 -> fp8 V^T scatter.
// Guarded 2-phase loop handles odd nt (K=192). Batch z = zb*NH + zh.
template<int OUT, int RELU, int BM, int QKV>
__global__ __launch_bounds__(256, 4) void gemm8(
    const unsigned char* __restrict__ A, int lda, long sAb, long sAh,
    const unsigned char* __restrict__ W, int ldw, long sWb, long sWh,
    const float* __restrict__ bias, float outscale,
    void* __restrict__ C, int ldc, long sCb, long sCh,
    unsigned char* __restrict__ vt8,
    int M, int N, int K, int NH)
{
    constexpr int NREP = (BM == 128) ? 4 : 2;
    constexpr int AHALF = (BM == 128) ? 4096 : 2048;
    __shared__ __align__(16) unsigned char As0[BM * 64];
    __shared__ __align__(16) unsigned char As1[BM * 64];
    __shared__ __align__(16) unsigned char Bs0[128 * 64];
    __shared__ __align__(16) unsigned char Bs1[128 * 64];

    int z = blockIdx.z, zb = z / NH, zh = z % NH;
    const unsigned char* Ap = A + (long)zb * sAb + (long)zh * sAh;
    const unsigned char* Wp = W + (long)zb * sWb + (long)zh * sWh;
    long coff = (long)zb * sCb + (long)zh * sCh;

    int gx = (int)gridDim.x, gy = (int)gridDim.y;
    int nwg = gx * gy;
    int orig = (int)(blockIdx.y * gridDim.x + blockIdx.x);
    int q = nwg >> 3, r = nwg & 7;
    int xcd = orig & 7, loc = orig >> 3;
    int wg = (xcd < r ? xcd * (q + 1) : r * (q + 1) + (xcd - r) * q) + loc;
    int full = 8 * gy;
    int nsc = (gx + 7) >> 3;
    int sc = wg / full; if (sc > nsc - 1) sc = nsc - 1;
    int rem = wg - sc * full;
    int wdt = gx - sc * 8; if (wdt > 8) wdt = 8;
    int by = rem / wdt, bx = sc * 8 + rem % wdt;

    int m0 = by * BM, n0 = bx * 128;
    int tid = threadIdx.x, wid = tid >> 6, lane = tid & 63;
    int wr = (BM == 128) ? (wid >> 1) * 64 : 0;
    int wc = (BM == 128) ? (wid & 1) * 64 : wid * 32;
    int fr = lane & 15, gk = (lane >> 4) * 8;

    // ---- staging geometry (validated swizzle: chunk ^= (row>>2)&1) ----
    int li0 = wid * 64 + lane;
    int rsW = li0 >> 1, csW = li0 & 1;
    int kcW = ((csW ^ (rsW >> 2)) & 1) << 4;
    long woff = (long)min(n0 + rsW, N - 1) * ldw + kcW;
    long aoff;
    if constexpr (BM == 128) {
        aoff = (long)min(m0 + rsW, M - 1) * lda + kcW;
    } else {
        int halfA = li0 >> 7;
        int rsA = (li0 >> 1) & 63, csA = li0 & 1;
        int kcA = ((csA ^ (rsA >> 2)) & 1) << 4;
        aoff = (long)min(m0 + rsA, M - 1) * lda + halfA * 32 + kcA;
    }
    char* a0base = (char*)As0 + wid * 1024;
    char* a1base = (char*)As1 + wid * 1024;
    char* b0base = (char*)Bs0 + wid * 1024;
    char* b1base = (char*)Bs1 + wid * 1024;

    f32x4 acc[4][NREP] = {};

    auto stage = [&](char* ab, char* bb, int kt) {
        int k0 = kt * 64;
        if constexpr (BM == 128) {
            __builtin_amdgcn_global_load_lds((glb_u8_t*)(Ap + aoff + k0), (lds_u8_t*)ab, 16, 0, 0);
            __builtin_amdgcn_global_load_lds((glb_u8_t*)(Ap + aoff + k0 + 32), (lds_u8_t*)(ab + 4096), 16, 0, 0);
        } else {
            __builtin_amdgcn_global_load_lds((glb_u8_t*)(Ap + aoff + k0), (lds_u8_t*)ab, 16, 0, 0);
        }
        __builtin_amdgcn_global_load_lds((glb_u8_t*)(Wp + woff + k0), (lds_u8_t*)bb, 16, 0, 0);
        __builtin_amdgcn_global_load_lds((glb_u8_t*)(Wp + woff + k0 + 32), (lds_u8_t*)(bb + 4096), 16, 0, 0);
    };
    int cg = gk >> 4, go = gk & 15;
    auto compute = [&](const unsigned char* as, const unsigned char* bs) {
        i64 af[4][2], bw[NREP][2];
#pragma unroll
        for (int m = 0; m < 4; m++) {
            int rr2 = wr + m * 16 + fr;
            int off = rr2 * 32 + (((cg ^ (rr2 >> 2)) & 1) << 4) + go;
            af[m][0] = *reinterpret_cast<const i64*>(as + off);
            af[m][1] = *reinterpret_cast<const i64*>(as + AHALF + off);
        }
#pragma unroll
        for (int n = 0; n < NREP; n++) {
            int rr2 = wc + n * 16 + fr;
            int off = rr2 * 32 + (((cg ^ (rr2 >> 2)) & 1) << 4) + go;
            bw[n][0] = *reinterpret_cast<const i64*>(bs + off);
            bw[n][1] = *reinterpret_cast<const i64*>(bs + 4096 + off);
        }
#pragma unroll
        for (int ks = 0; ks < 2; ks++)
#pragma unroll
            for (int m = 0; m < 4; m++)
#pragma unroll
                for (int n = 0; n < NREP; n++)
                    acc[m][n] = __builtin_amdgcn_mfma_f32_16x16x32_fp8_fp8(
                        af[m][ks], bw[n][ks], acc[m][n], 0, 0, 0);
    };

    // guarded 2-phase loop: correct for any nt >= 1 (nt=3 for K=192)
    int nt = K >> 6;
    stage(a0base, b0base, 0);
    __syncthreads();
    for (int t = 0; t < nt; t += 2) {
        if (t + 1 < nt) stage(a1base, b1base, t + 1);
        compute(As0, Bs0);
        __syncthreads();
        if (t + 1 < nt) {
            if (t + 2 < nt) stage(a0base, b0base, t + 2);
            compute(As1, Bs1);
            __syncthreads();
        }
    }

    int crow = (lane >> 4) * 4;
#pragma unroll
    for (int m = 0; m < 4; m++) {
#pragma unroll
        for (int n = 0; n < NREP; n++) {
            int col = n0 + wc + n * 16 + fr;
            if (col >= N) continue;
            float bv = bias ? bias[col] : 0.f;
            int rbase = m0 + wr + m * 16 + crow;
            float vv[4];
#pragma unroll
            for (int rr = 0; rr < 4; rr++) {
                float v = acc[m][n][rr] * outscale + bv;
                if (RELU) v = fmaxf(v, 0.f);
                vv[rr] = v;
            }
            if constexpr (QKV) {
                // M=8192, N=2304 exact: no edge checks. cols<1536 -> q8k8; else V^T fp8 scatter.
                if (col < 1536) {
#pragma unroll
                    for (int rr = 0; rr < 4; rr++)
                        ((unsigned char*)C)[coff + (long)(rbase + rr) * ldc + col] = f2e4m3(vv[rr]);
                } else {
                    int tt = col - 1536;
                    int h = tt / 192, d = tt - h * 192;
                    int b = rbase >> 9, k0 = rbase & 511;
                    uchar4 o;
                    o.x = f2e4m3(vv[0]); o.y = f2e4m3(vv[1]);
                    o.z = f2e4m3(vv[2]); o.w = f2e4m3(vv[3]);
                    *reinterpret_cast<uchar4*>(vt8 + ((long)((b << 2) + h) * 192 + d) * 512 + k0) = o;
                }
            } else {
#pragma unroll
                for (int rr = 0; rr < 4; rr++) {
                    int row = rbase + rr;
                    if (row >= M) continue;
                    long idx = coff + (long)row * ldc + col;
                    if (OUT == 0)      ((float*)C)[idx] = vv[rr];
                    else if (OUT == 1) ((u16*)C)[idx] = f2bf(vv[rr]);
                    else               ((unsigned char*)C)[idx] = f2e4m3(vv[rr]);
                }
            }
        }
    }
}

// ---------------- fp8 V transpose with zero-pad (CA only) ----------------
__global__ __launch_bounds__(256) void transpose_pad8(
    const unsigned char* __restrict__ V, long sVb, long sVh, int ldv, int NH,
    unsigned char* __restrict__ VT, long sVT, int rowsIn, int Kp)
{
    __shared__ unsigned char tile[32][33];
    int z = blockIdx.z, zb = z / NH, zh = z % NH;
    const unsigned char* Vp = V + (long)zb * sVb + (long)zh * sVh;
    int k0 = blockIdx.x * 32, d0 = blockIdx.y * 32;
#pragma unroll
    for (int i = 0; i < 4; i++) {
        int k = k0 + threadIdx.y + i * 8;
        int d = d0 + threadIdx.x;
        tile[threadIdx.y + i * 8][threadIdx.x] = (k < rowsIn) ? Vp[(long)k * ldv + d] : (unsigned char)0;
    }
    __syncthreads();
    unsigned char* Op = VT + (long)z * sVT;
#pragma unroll
    for (int i = 0; i < 4; i++) {
        int d = d0 + threadIdx.y + i * 8;
        int k = k0 + threadIdx.x;
        Op[(long)d * Kp + k] = tile[threadIdx.x][threadIdx.y + i * 8];
    }
}

// ---------------- wave-per-row softmax: bf16 scores -> fp8 probs x64 ----------------
template<int CPL, int CAUSAL>
__global__ __launch_bounds__(256) void softmax2(
    const u16* __restrict__ S, unsigned char* __restrict__ P,
    int ld_in, int valid_in, int ld_out, float scale)
{
    int wid = threadIdx.x >> 6, lane = threadIdx.x & 63;
    long r = (long)blockIdx.x * 4 + wid;
    int q = (int)(r & 511);
    int valid = CAUSAL ? (q + 1) : valid_in;
    const u16* srow = S + r * (long)ld_in;
    unsigned char* prow = P + r * (long)ld_out;
    int base = lane * CPL;
    float v[CPL];
    if constexpr (CPL == 8) {
        u16x8 x = *reinterpret_cast<const u16x8*>(srow + base);
#pragma unroll
        for (int j = 0; j < 8; j++) v[j] = bf2f(x[j]);
    } else {
        u16x4 x = *reinterpret_cast<const u16x4*>(srow + base);
#pragma unroll
        for (int j = 0; j < 4; j++) v[j] = bf2f(x[j]);
    }
    float mx = -3e38f;
#pragma unroll
    for (int j = 0; j < CPL; j++) {
        v[j] *= scale;
        if (base + j < valid) mx = fmaxf(mx, v[j]);
    }
#pragma unroll
    for (int o = 32; o; o >>= 1) mx = fmaxf(mx, __shfl_xor(mx, o, 64));
    float e[CPL], s = 0.f;
#pragma unroll
    for (int j = 0; j < CPL; j++) {
        e[j] = (base + j < valid) ? __expf(v[j] - mx) : 0.f;
        s += e[j];
    }
#pragma unroll
    for (int o = 32; o; o >>= 1) s += __shfl_xor(s, o, 64);
    float inv = 64.f / s;                 // probs x64 (PV outscale 1/64)
    if constexpr (CPL == 8) {
        union { unsigned char b[8]; i64 v8; } o;
#pragma unroll
        for (int j = 0; j < 8; j++) o.b[j] = f2e4m3(e[j] * inv);
        *reinterpret_cast<i64*>(prow + base) = o.v8;
    } else {
        uchar4 o4;
        o4.x = f2e4m3(e[0] * inv); o4.y = f2e4m3(e[1] * inv);
        o4.z = f2e4m3(e[2] * inv); o4.w = f2e4m3(e[3] * inv);
        *reinterpret_cast<uchar4*>(prow + base) = o4;
    }
}

// ---------------- fused residual add + LayerNorm (bf16 in/out + fp8 out) ----------------
__global__ __launch_bounds__(256) void ln_kernel(
    const u16* __restrict__ xin, const u16* __restrict__ subb,
    const float* __restrict__ g, const float* __restrict__ bta,
    u16* __restrict__ xout, unsigned char* __restrict__ q8)
{
    int wid = threadIdx.x >> 6, lane = threadIdx.x & 63;
    long r = (long)blockIdx.x * 4 + wid;
    const u16* a = xin + r * 768;
    const u16* s = subb + r * 768;
    int base = lane * 12;
    float v[12];
    float sum = 0.f;
#pragma unroll
    for (int c = 0; c < 3; c++) {
        ushort4 av = *reinterpret_cast<const ushort4*>(a + base + c * 4);
        ushort4 sv = *reinterpret_cast<const ushort4*>(s + base + c * 4);
        v[c*4+0] = bf2f(av.x) + bf2f(sv.x);
        v[c*4+1] = bf2f(av.y) + bf2f(sv.y);
        v[c*4+2] = bf2f(av.z) + bf2f(sv.z);
        v[c*4+3] = bf2f(av.w) + bf2f(sv.w);
        sum += v[c*4+0] + v[c*4+1] + v[c*4+2] + v[c*4+3];
    }
#pragma unroll
    for (int o = 32; o; o >>= 1) sum += __shfl_xor(sum, o, 64);
    float mean = sum * (1.f / 768.f);
    float vs = 0.f;
#pragma unroll
    for (int j = 0; j < 12; j++) { float t = v[j] - mean; vs += t * t; }
#pragma unroll
    for (int o = 32; o; o >>= 1) vs += __shfl_xor(vs, o, 64);
    float rstd = rsqrtf(vs * (1.f / 768.f) + 1e-5f);
    u16* xo = xout + r * 768;
    unsigned char* qo = q8 + r * 768;
#pragma unroll
    for (int c = 0; c < 3; c++) {
        float4 gv = *reinterpret_cast<const float4*>(g + base + c * 4);
        float4 bv = *reinterpret_cast<const float4*>(bta + base + c * 4);
        float y0 = (v[c*4+0] - mean) * rstd * gv.x + bv.x;
        float y1 = (v[c*4+1] - mean) * rstd * gv.y + bv.y;
        float y2 = (v[c*4+2] - mean) * rstd * gv.z + bv.z;
        float y3 = (v[c*4+3] - mean) * rstd * gv.w + bv.w;
        ushort4 o; o.x = f2bf(y0); o.y = f2bf(y1); o.z = f2bf(y2); o.w = f2bf(y3);
        *reinterpret_cast<ushort4*>(xo + base + c * 4) = o;
        uchar4 qb; qb.x = f2e4m3(y0); qb.y = f2e4m3(y1); qb.z = f2e4m3(y2); qb.w = f2e4m3(y3);
        *reinterpret_cast<uchar4*>(qo + base + c * 4) = qb;
    }
}

// ---------------- host helpers ----------------
template<int OUT, int RELU, int BM>
static void g8(hipStream_t st, const unsigned char* A, int lda, const unsigned char* W, int ldw,
               const float* bias, void* C, int ldc, int M, int N, int K) {
    dim3 g((N + 127) / 128, (M + BM - 1) / BM, 1), b(256, 1, 1);
    gemm8<OUT,RELU,BM,0><<<g,b,0,st>>>(A,lda,0,0,W,ldw,0,0,bias,1.f/256.f,C,ldc,0,0,nullptr,M,N,K,1);
}
template<int OUT>
static void g8bat(hipStream_t st,
    const unsigned char* A, int lda, long sAb, long sAh,
    const unsigned char* W, int ldw, long sWb, long sWh,
    float outscale, void* C, int ldc, long sCb, long sCh,
    int M, int N, int K, int Z, int NH) {
    dim3 g((N + 127) / 128, (M + 127) / 128, Z), b(256, 1, 1);
    gemm8<OUT,0,128,0><<<g,b,0,st>>>(A,lda,sAb,sAh,W,ldw,sWb,sWh,nullptr,outscale,
                                     C,ldc,sCb,sCh,nullptr,M,N,K,NH);
}
static void g8qkv(hipStream_t st, const unsigned char* A, const unsigned char* W,
                  const float* bias, unsigned char* q8k8, unsigned char* vt8) {
    dim3 g(18, 64, 1), b(256, 1, 1);
    gemm8<2,0,128,1><<<g,b,0,st>>>(A,768,0,0,W,768,0,0,bias,1.f/256.f,
                                   q8k8,1536,0,0,vt8,8192,2304,768,1);
}

extern "C" void kernel_launch(void* const* d_in, const int* in_sizes, int n_in,
                              void* d_out, int out_size, void* d_ws, size_t ws_size,
                              hipStream_t stream)
{
    const int*   labels = (const int*)  d_in[0];
    const float* vision = (const float*)d_in[1];
    const float* vpw    = (const float*)d_in[2];
    const float* vpb    = (const float*)d_in[3];
    const float* temb   = (const float*)d_in[4];
    const float* pemb   = (const float*)d_in[5];
    const float* saw    = (const float*)d_in[6];
    const float* sab    = (const float*)d_in[7];
    const float* saow   = (const float*)d_in[8];
    const float* saob   = (const float*)d_in[9];
    const float* caw    = (const float*)d_in[10];
    const float* cab    = (const float*)d_in[11];
    const float* caow   = (const float*)d_in[12];
    const float* caob   = (const float*)d_in[13];
    const float* ln1g   = (const float*)d_in[14];
    const float* ln1b   = (const float*)d_in[15];
    const float* ln2g   = (const float*)d_in[16];
    const float* ln2b   = (const float*)d_in[17];
    const float* ln3g   = (const float*)d_in[18];
    const float* ln3b   = (const float*)d_in[19];
    const float* f1w    = (const float*)d_in[20];
    const float* f1b    = (const float*)d_in[21];
    const float* f2w    = (const float*)d_in[22];
    const float* f2b    = (const float*)d_in[23];
    const float* ow     = (const float*)d_in[24];
    const float* ob     = (const float*)d_in[25];
    (void)in_sizes; (void)n_in; (void)out_size;

    // ---- workspace layout ----
    char* p = (char*)d_ws;
    auto alloc = [&](long elems, int esz) -> char* {
        char* r = p; p += ((long)elems * esz + 255) & ~255L; return r;
    };
    unsigned char* w8_sa  = (unsigned char*)alloc(3L*2304*768, 1);  // fp8 weights x256
    unsigned char* w8_ca  = (unsigned char*)alloc(3L*2304*768, 1);
    unsigned char* w8_sao = (unsigned char*)alloc(3L*768*768, 1);
    unsigned char* w8_cao = (unsigned char*)alloc(3L*768*768, 1);
    unsigned char* w8_f1  = (unsigned char*)alloc(3L*1024*768, 1);
    unsigned char* w8_f2  = (unsigned char*)alloc(3L*768*1024, 1);
    unsigned char* w8_ow  = (unsigned char*)alloc(10000L*768, 1);
    unsigned char* w8_vp  = (unsigned char*)alloc(768L*768, 1);
    unsigned char* vis8   = (unsigned char*)alloc(3152L*768, 1);    // fp8 activations (x1)
    unsigned char* mem8   = (unsigned char*)alloc(3152L*768, 1);
    unsigned char* xq     = (unsigned char*)alloc(8192L*768, 1);
    unsigned char* h8     = (unsigned char*)alloc(8192L*1024, 1);
    unsigned char* attn8  = (unsigned char*)alloc(8192L*768, 1);
    unsigned char* q8k8   = (unsigned char*)alloc(8192L*1536, 1);   // SA Q|K fp8
    unsigned char* q8ca   = (unsigned char*)alloc(8192L*768, 1);    // CA Q fp8
    unsigned char* kv8    = (unsigned char*)alloc(3152L*1536, 1);   // CA K|V fp8
    unsigned char* vt8    = (unsigned char*)alloc(64L*192*512, 1);  // V^T fp8 (SA Kp512 / CA Kp256)
    unsigned char* pr8    = (unsigned char*)alloc(64L*512*512, 1);  // probs fp8 x64
    u16* xb   = (u16*)alloc(8192L*768, 2);
    u16* scb  = (u16*)alloc(64L*512*512, 2);                        // bf16 scores
    u16* subb = (u16*)alloc(8192L*768, 2);
    if ((size_t)(p - (char*)d_ws) > ws_size) return;

    // ---- all casts -> fp8 in one launch (weights x256, vision x1) ----
    CastQ cq;
    cq.s[0] = saw;    cq.d[0] = w8_sa;  cq.n4[0] = 3L*2304*768/4;  cq.mul[0] = 256.f;
    cq.s[1] = caw;    cq.d[1] = w8_ca;  cq.n4[1] = 3L*2304*768/4;  cq.mul[1] = 256.f;
    cq.s[2] = saow;   cq.d[2] = w8_sao; cq.n4[2] = 3L*768*768/4;   cq.mul[2] = 256.f;
    cq.s[3] = caow;   cq.d[3] = w8_cao; cq.n4[3] = 3L*768*768/4;   cq.mul[3] = 256.f;
    cq.s[4] = f1w;    cq.d[4] = w8_f1;  cq.n4[4] = 3L*1024*768/4;  cq.mul[4] = 256.f;
    cq.s[5] = f2w;    cq.d[5] = w8_f2;  cq.n4[5] = 3L*768*1024/4;  cq.mul[5] = 256.f;
    cq.s[6] = ow;     cq.d[6] = w8_ow;  cq.n4[6] = 10000L*768/4;   cq.mul[6] = 256.f;
    cq.s[7] = vpw;    cq.d[7] = w8_vp;  cq.n4[7] = 768L*768/4;     cq.mul[7] = 256.f;
    cq.s[8] = vision; cq.d[8] = vis8;   cq.n4[8] = 3152L*768/4;    cq.mul[8] = 1.f;
    castq_kernel<<<dim3(512, 1, 9), dim3(256), 0, stream>>>(cq);

    embed_kernel<<<dim3(2048), dim3(256), 0, stream>>>(labels, temb, pemb, xb, xq,
                                                       (float*)d_out + 81920000L);

    // mem = vision @ vis_proj_w^T + b  -> fp8
    g8<2,0,64>(stream, vis8, 768, w8_vp, 768, vpb, mem8, 768, 3152, 768, 768);

    const float scale = 0.07216878364870323f;  // 1/sqrt(192)
    const float PSCALE_INV = 1.f / 64.f;

    for (int l = 0; l < 3; l++) {
        // ======== self-attention (all fp8) ========
        g8qkv(stream, xq, w8_sa + (long)l*2304*768, sab + l*2304, q8k8, vt8);
        // scores = Q K^T : fp8 x fp8 (x1 scales), K=192 (nt=3 guarded), out bf16 scb
        g8bat<1>(stream, q8k8, 1536, 512L*1536, 192, q8k8 + 768, 1536, 512L*1536, 192,
                 1.f, scb, 512, 4L*512*512, 512L*512, 512, 512, 192, 64, 4);
        softmax2<8,1><<<dim3(8192), dim3(256), 0, stream>>>(scb, pr8, 512, 512, 512, scale);
        // O = P(x64) @ V^T : outscale 1/64, out fp8 attn8
        g8bat<2>(stream, pr8, 512, 4L*512*512, 512L*512, vt8, 512, 4L*192*512, 192L*512,
                 PSCALE_INV, attn8, 768, 512L*768, 192, 512, 192, 512, 64, 4);
        g8<1,0,64>(stream, attn8, 768, w8_sao + (long)l*768*768, 768,
                   saob + l*768, subb, 768, 8192, 768, 768);
        ln_kernel<<<dim3(2048), dim3(256), 0, stream>>>(xb, subb, ln1g + l*768, ln1b + l*768,
                                                        xb, xq);

        // ======== cross-attention (all fp8) ========
        g8<2,0,64>(stream, xq, 768, w8_ca + (long)l*2304*768, 768,
                   cab + l*2304, q8ca, 768, 8192, 768, 768);
        g8<2,0,64>(stream, mem8, 768, w8_ca + (long)l*2304*768 + 768L*768, 768,
                   cab + l*2304 + 768, kv8, 1536, 3152, 1536, 768);
        transpose_pad8<<<dim3(8,6,64), dim3(32,8), 0, stream>>>(
            kv8 + 768, 197L*1536, 192L, 1536, 4, vt8, 192L*256, 197, 256);
        g8bat<1>(stream, q8ca, 768, 512L*768, 192, kv8, 1536, 197L*1536, 192,
                 1.f, scb, 224, 4L*512*224, 512L*224, 512, 197, 192, 64, 4);
        softmax2<4,0><<<dim3(8192), dim3(256), 0, stream>>>(scb, pr8, 224, 197, 256, scale);
        g8bat<2>(stream, pr8, 256, 4L*512*256, 512L*256, vt8, 256, 4L*192*256, 192L*256,
                 PSCALE_INV, attn8, 768, 512L*768, 192, 512, 192, 256, 64, 4);
        g8<1,0,64>(stream, attn8, 768, w8_cao + (long)l*768*768, 768,
                   caob + l*768, subb, 768, 8192, 768, 768);
        ln_kernel<<<dim3(2048), dim3(256), 0, stream>>>(xb, subb, ln2g + l*768, ln2b + l*768,
                                                        xb, xq);

        // ======== feed-forward (fp8) ========
        g8<2,1,128>(stream, xq, 768, w8_f1 + (long)l*1024*768, 768, f1b + l*1024,
                    h8, 1024, 8192, 1024, 768);
        g8<1,0,64>(stream, h8, 1024, w8_f2 + (long)l*768*1024, 1024, f2b + l*768,
                   subb, 768, 8192, 768, 1024);
        ln_kernel<<<dim3(2048), dim3(256), 0, stream>>>(xb, subb, ln3g + l*768, ln3b + l*768,
                                                        xb, xq);
    }

    // vocab head (fp8, BM=128) -> d_out f32 logits
    g8<0,0,128>(stream, xq, 768, w8_ow, 768, ob, (float*)d_out, 10000, 8192, 10000, 768);
}